// Round 6
// baseline (445.816 us; speedup 1.0000x reference)
//
#include <hip/hip_runtime.h>
#include <hip/hip_bf16.h>
#include <math.h>

// Problem constants (B=2, S=1024, E=1024, H=16, D=64)
#define S_LEN 1024
#define E_DIM 1024
#define NH 16
#define HD 64
#define M_ROWS 2048   // B*S
#define BH_CNT 32     // B*NH

static constexpr float LR_C = 0.01f;
static constexpr float SC_C = 0.125f;                // 1/sqrt(64)
static constexpr float C2_C = 0.125f * 1.44269504f;  // SC * log2(e): log2-domain softmax

typedef unsigned short ushort_t;
typedef __attribute__((ext_vector_type(8))) __bf16 bf16x8;
typedef __attribute__((ext_vector_type(4))) float f32x4;

static __device__ inline ushort_t f2bu(float f) {
  __hip_bfloat16 h = __float2bfloat16(f);
  return *(ushort_t*)&h;
}
static __device__ inline bf16x8 ldg8(const ushort_t* p) { return *(const bf16x8*)p; }

// async global->LDS, 16B per lane; LDS dest = wave-uniform base + lane*16
static __device__ inline void async_cp16(const ushort_t* g, __bf16* lds_wave_base) {
  __builtin_amdgcn_global_load_lds((const __attribute__((address_space(1))) void*)g,
                                   (__attribute__((address_space(3))) void*)lds_wave_base,
                                   16, 0, 0);
}

// ---- 64x64 bf16 tile in unpadded LDS with per-row chunk rotation ----
// element (r,c) lives at ushort offset r*64 + (((c>>3)+r)&7)*8 + (c&7).
// Staged via global_load_lds: wave w, issue t fills slab s=w*2+t (rows 8s..8s+7, 1 KB,
// wave-uniform dest); lane l supplies source chunk c=((l&7)-(l>>3))&7 of row 8s+(l>>3)
// (pre-rotated SOURCE address = m173's swizzle-the-global-side pattern).
// b128 fragment reads hit bank-quad (chunk+row)&7 — same distribution as the old +8 pad.
static __device__ inline void stage_tile(const ushort_t* src, size_t src_stride,
                                         ushort_t* lds, int lane, int wave) {
  int rl = lane >> 3;
  int c = ((lane & 7) - rl) & 7;
  #pragma unroll
  for (int t = 0; t < 2; t++) {
    int s = wave * 2 + t;
    async_cp16(src + (size_t)(s * 8 + rl) * src_stride + c * 8,
               (__bf16*)(lds + s * 512));
  }
}
static __device__ inline const bf16x8* tile_at(const ushort_t* lds, int r, int cchunk) {
  return (const bf16x8*)(lds + r * 64 + (((cchunk + r) & 7) * 8));
}

// ---------------- weight prep: bf16 cast + bf16 transpose, 64x64 tiles ----------------
__global__ __launch_bounds__(256) void prep_w(const float* __restrict__ W,
                                              ushort_t* __restrict__ Wb,
                                              ushort_t* __restrict__ WTb) {
  __shared__ float ts[64][65];
  int bx = blockIdx.x * 64, by = blockIdx.y * 64;
  int t = threadIdx.x;
  int rr = t >> 6, cc = t & 63;
  #pragma unroll
  for (int p = 0; p < 16; p++) {
    int r = p * 4 + rr;
    float v = W[(size_t)(by + r) * E_DIM + bx + cc];
    ts[r][cc] = v;
    Wb[(size_t)(by + r) * E_DIM + bx + cc] = f2bu(v);
  }
  __syncthreads();
  #pragma unroll
  for (int p = 0; p < 16; p++) {
    int r = p * 4 + rr;
    WTb[(size_t)(bx + r) * E_DIM + by + cc] = f2bu(ts[cc][r]);
  }
}

// ---------------- fp32 -> bf16 cast (float4-wide) ----------------
__global__ __launch_bounds__(256) void k_cast(const float* __restrict__ in,
                                              ushort_t* __restrict__ out, int n4) {
  int i = blockIdx.x * 256 + threadIdx.x;
  if (i < n4) {
    float4 v = ((const float4*)in)[i];
    ushort_t p[4] = {f2bu(v.x), f2bu(v.y), f2bu(v.z), f2bu(v.w)};
    *(uint2*)(out + (size_t)i * 4) = *(uint2*)p;
  }
}

// ---------------- N = 3LR*I - 3LR^2*M + LR^3*M2  (bf16 out) ----------------
__global__ __launch_bounds__(256) void k_formN(const float* __restrict__ Mf,
                                               const float* __restrict__ M2f,
                                               ushort_t* __restrict__ Nb) {
  int idx = blockIdx.x * 256 + threadIdx.x;   // 1M elements
  int i = idx >> 10, j = idx & 1023;
  float v = -3.f * LR_C * LR_C * Mf[idx] + LR_C * LR_C * LR_C * M2f[idx];
  if (i == j) v += 3.f * LR_C;
  Nb[idx] = f2bu(v);
}

// ---------------- iter-1 shortcut: suffix scan S[j] = sum_{i>=j} Xs[i]/(i+1) ----------------
// x=0 => Q=K=V=0 => P is exactly causal-uniform, dQ=dK=0, dV = P0^T(-Xs).
// x1 = LR * (P0^T Xs) * Wv. Two-pass chunked scan over the sequence dim.
__global__ __launch_bounds__(256) void k_scan1(const float* __restrict__ Xs,
                                               float* __restrict__ Sf,
                                               float* __restrict__ tot) {
  int e = blockIdx.x * 256 + threadIdx.x;  // column 0..1023
  int b = blockIdx.y;                      // batch
  int z = blockIdx.z;                      // chunk 0..15 (64 rows each)
  float acc = 0.f;
  for (int i = z * 64 + 63; i >= z * 64; i--) {
    size_t idx = ((size_t)b * S_LEN + i) * E_DIM + e;
    acc = fmaf(Xs[idx], 1.0f / (float)(i + 1), acc);
    Sf[idx] = acc;
  }
  tot[((size_t)b * 16 + z) * E_DIM + e] = acc;
}

__global__ __launch_bounds__(256) void k_scan2(const float* __restrict__ Sf,
                                               const float* __restrict__ tot,
                                               ushort_t* __restrict__ Sb) {
  int e = blockIdx.x * 256 + threadIdx.x;
  int b = blockIdx.y;
  int z = blockIdx.z;
  float off = 0.f;
  for (int c = z + 1; c < 16; c++) off += tot[((size_t)b * 16 + c) * E_DIM + e];
  for (int i = z * 64; i < z * 64 + 64; i++) {
    size_t idx = ((size_t)b * S_LEN + i) * E_DIM + e;
    Sb[idx] = f2bu(Sf[idx] + off);
  }
}

// ---------------- bf16 MFMA GEMM, 64x64 tile, BK=64, ASYNC global_load_lds staging ----------
// Four 4KB half-buffers (16KB LDS); 16 barrier-drains per K=1024.
// k-halves accumulated h0 then h1 = identical order to BK=32 -> bit-identical results.
// MODE 0: Cb_z = bf16(acc) + Ct_z per-head transposed [bh][d][token], Qt/Kt pre-scaled by SC
// MODE 2: Cf += alpha*acc (fp32) and Cb0 = bf16(Cf), NSEG K-segments
// MODE 3: Cf = acc (fp32 only)
// MODE 4: Cf = acc and Cb0 = bf16(acc)
// MODE 5: Cb0 = bf16(acc)
// MODE 6: Cf = alpha*acc (overwrite) and Cb0 = bf16(alpha*acc)
template <int MODE, int NSEG>
__global__ __launch_bounds__(256) void gemm_mf(
    const ushort_t* __restrict__ A0, const ushort_t* __restrict__ A1, const ushort_t* __restrict__ A2,
    const ushort_t* __restrict__ B0, const ushort_t* __restrict__ B1, const ushort_t* __restrict__ B2,
    float* __restrict__ Cf,
    ushort_t* __restrict__ Cb0, ushort_t* __restrict__ Cb1, ushort_t* __restrict__ Cb2,
    ushort_t* __restrict__ Ct0, ushort_t* __restrict__ Ct1, ushort_t* __restrict__ Ct2,
    float alpha) {
  const int K = 1024;
  __shared__ __bf16 As0[64][32];
  __shared__ __bf16 As1[64][32];
  __shared__ __bf16 Bs0[64][32];
  __shared__ __bf16 Bs1[64][32];
  int tid = threadIdx.x;
  int m0 = blockIdx.y * 64, n0 = blockIdx.x * 64;

  const ushort_t* Bsel = B0;
  ushort_t* Cbz = Cb0;
  ushort_t* Ctz = Ct0;
  float tsc = 1.0f;
  if (MODE == 0) {
    int z = blockIdx.z;
    Bsel = (z == 0) ? B0 : (z == 1) ? B1 : B2;
    Cbz = (z == 0) ? Cb0 : (z == 1) ? Cb1 : Cb2;
    Ctz = (z == 0) ? Ct0 : (z == 1) ? Ct1 : Ct2;
    tsc = (z == 2) ? 1.0f : SC_C;   // Qt/Kt carry the 1/sqrt(d) factor
  }

  int lane = tid & 63, wave = tid >> 6;
  int wrow = wave >> 1, wcol = wave & 1;
  int fr = lane & 15, q = lane >> 4;

  int srow = wave * 16 + (lane >> 2);
  int scg = ((lane & 3) + (srow >> 1)) & 3;
  int scol = scg * 8;
  __bf16* ldsA0 = &As0[wave * 16][0];
  __bf16* ldsA1 = &As1[wave * 16][0];
  __bf16* ldsB0 = &Bs0[wave * 16][0];
  __bf16* ldsB1 = &Bs1[wave * 16][0];

  int rA0 = wrow * 32 + fr, rA1r = rA0 + 16;
  int rB0 = wcol * 32 + fr, rB1r = rB0 + 16;
  int cA0 = ((q - (rA0 >> 1)) & 3) * 8;
  int cA1 = ((q - (rA1r >> 1)) & 3) * 8;
  int cB0 = ((q - (rB0 >> 1)) & 3) * 8;
  int cB1 = ((q - (rB1r >> 1)) & 3) * 8;
  const bf16x8* pa0h0 = (const bf16x8*)&As0[rA0][cA0];
  const bf16x8* pa0h1 = (const bf16x8*)&As1[rA0][cA0];
  const bf16x8* pa1h0 = (const bf16x8*)&As0[rA1r][cA1];
  const bf16x8* pa1h1 = (const bf16x8*)&As1[rA1r][cA1];
  const bf16x8* pb0h0 = (const bf16x8*)&Bs0[rB0][cB0];
  const bf16x8* pb0h1 = (const bf16x8*)&Bs1[rB0][cB0];
  const bf16x8* pb1h0 = (const bf16x8*)&Bs0[rB1r][cB1];
  const bf16x8* pb1h1 = (const bf16x8*)&Bs1[rB1r][cB1];

  f32x4 acc[2][2] = {};

  #pragma unroll 1
  for (int seg = 0; seg < NSEG; seg++) {
    const ushort_t* Aseg = (seg == 0) ? A0 : (seg == 1) ? A1 : A2;
    const ushort_t* Bseg = (MODE == 0) ? Bsel : ((seg == 0) ? B0 : (seg == 1) ? B1 : B2);
    const ushort_t* ga = Aseg + (size_t)(m0 + srow) * K + scol;
    const ushort_t* gb = Bseg + (size_t)(n0 + srow) * K + scol;
    #pragma unroll 1
    for (int k0 = 0; k0 < K; k0 += 64) {
      __syncthreads();
      async_cp16(ga + k0, ldsA0);
      async_cp16(ga + k0 + 32, ldsA1);
      async_cp16(gb + k0, ldsB0);
      async_cp16(gb + k0 + 32, ldsB1);
      __syncthreads();
      bf16x8 a00 = *pa0h0, a01 = *pa0h1, a10 = *pa1h0, a11 = *pa1h1;
      bf16x8 b00 = *pb0h0, b01 = *pb0h1, b10 = *pb1h0, b11 = *pb1h1;
      acc[0][0] = __builtin_amdgcn_mfma_f32_16x16x32_bf16(a00, b00, acc[0][0], 0, 0, 0);
      acc[0][1] = __builtin_amdgcn_mfma_f32_16x16x32_bf16(a00, b10, acc[0][1], 0, 0, 0);
      acc[1][0] = __builtin_amdgcn_mfma_f32_16x16x32_bf16(a10, b00, acc[1][0], 0, 0, 0);
      acc[1][1] = __builtin_amdgcn_mfma_f32_16x16x32_bf16(a10, b10, acc[1][1], 0, 0, 0);
      acc[0][0] = __builtin_amdgcn_mfma_f32_16x16x32_bf16(a01, b01, acc[0][0], 0, 0, 0);
      acc[0][1] = __builtin_amdgcn_mfma_f32_16x16x32_bf16(a01, b11, acc[0][1], 0, 0, 0);
      acc[1][0] = __builtin_amdgcn_mfma_f32_16x16x32_bf16(a11, b01, acc[1][0], 0, 0, 0);
      acc[1][1] = __builtin_amdgcn_mfma_f32_16x16x32_bf16(a11, b11, acc[1][1], 0, 0, 0);
    }
  }

  // C/D layout: col = lane&15, row = (lane>>4)*4 + reg
  #pragma unroll
  for (int mi = 0; mi < 2; mi++)
    #pragma unroll
    for (int ni = 0; ni < 2; ni++) {
      int col = n0 + wcol * 32 + ni * 16 + fr;
      int row0 = m0 + wrow * 32 + mi * 16 + q * 4;
      ushort_t pk[4];
      #pragma unroll
      for (int r = 0; r < 4; r++) {
        size_t idx = (size_t)(row0 + r) * E_DIM + col;
        float v = acc[mi][ni][r];
        if (MODE == 0) {
          Cbz[idx] = f2bu(v);
          pk[r] = f2bu(v * tsc);
        } else if (MODE == 2) {
          float nv = Cf[idx] + alpha * v;
          Cf[idx] = nv;
          Cb0[idx] = f2bu(nv);
        } else if (MODE == 3) {
          Cf[idx] = v;
        } else if (MODE == 4) {
          Cf[idx] = v;
          Cb0[idx] = f2bu(v);
        } else if (MODE == 6) {
          float nv = alpha * v;
          Cf[idx] = nv;
          Cb0[idx] = f2bu(nv);
        } else {  // MODE 5
          Cb0[idx] = f2bu(v);
        }
      }
      if (MODE == 0) {
        int hh = col >> 6, dd = col & 63;
        int bb = row0 >> 10, ss = row0 & 1023;
        *(uint2*)(Ctz + ((size_t)((bb * NH + hh) * HD + dd)) * S_LEN + ss) = *(uint2*)pk;
      }
    }
}

// ====================== MFMA attention, LDS-staged ======================

// ---- fused fwd: single-pass flash, log2-domain online softmax; emits m' = m + log2(l),
//      g=O-Xs (bf16 + transposed), Dv. grid (bh=32, y=16), balanced pairing.
//      K/V tiles staged via global_load_lds into chunk-rotated unpadded LDS
//      (no VGPR round-trip; staging VALU removed). ----
__global__ __launch_bounds__(256) void fwd_fused(const ushort_t* __restrict__ Qg,
                                                 const ushort_t* __restrict__ Kg,
                                                 const ushort_t* __restrict__ Vt,
                                                 const float* __restrict__ Xs,
                                                 float* __restrict__ mbuf,
                                                 ushort_t* __restrict__ Gb,
                                                 ushort_t* __restrict__ Gt,
                                                 float* __restrict__ Dv) {
  int bh = blockIdx.x, y = blockIdx.y;
  int it = (y < 8) ? (15 - y) : (y - 8);
  int b = bh >> 4, h = bh & 15;
  int tid = threadIdx.x, lane = tid & 63, wv = tid >> 6;
  int fr = lane & 15, q = lane >> 4;
  int i0 = it * 64, band = wv * 16;
  __shared__ ushort_t Ks[4096];     // [j][d] chunk-rotated
  __shared__ ushort_t Vs[4096];     // [d][j] chunk-rotated
  __shared__ ushort_t Ps[64][72];   // [i][j] wave-private bands (lane-written)

  const ushort_t* Kbase = Kg + (size_t)(b * S_LEN) * E_DIM + h * HD;
  const ushort_t* Vbase = Vt + (size_t)(bh * HD) * S_LEN;

  const ushort_t* Qrow = Qg + (size_t)(b * S_LEN + i0 + band + fr) * E_DIM + h * HD;
  bf16x8 aq0 = ldg8(Qrow + q * 8);
  bf16x8 aq1 = ldg8(Qrow + 32 + q * 8);

  float m[4], l[4];
  #pragma unroll
  for (int r = 0; r < 4; r++) { m[r] = -1e30f; l[r] = 0.f; }
  f32x4 oacc[4] = {};

  #pragma unroll 1
  for (int jt = 0; jt <= it; jt++) {
    int j0 = jt * 64;
    __syncthreads();
    stage_tile(Kbase + (size_t)j0 * E_DIM, E_DIM, Ks, lane, wv);
    stage_tile(Vbase + j0, S_LEN, Vs, lane, wv);
    __syncthreads();
    f32x4 sA[4];
    #pragma unroll
    for (int nc = 0; nc < 4; nc++) {
      bf16x8 bk0 = *tile_at(Ks, nc * 16 + fr, q);
      bf16x8 bk1 = *tile_at(Ks, nc * 16 + fr, q + 4);
      f32x4 z = {};
      z = __builtin_amdgcn_mfma_f32_16x16x32_bf16(aq0, bk0, z, 0, 0, 0);
      sA[nc] = __builtin_amdgcn_mfma_f32_16x16x32_bf16(aq1, bk1, z, 0, 0, 0);
    }
    float sv[4][4];
    #pragma unroll
    for (int nc = 0; nc < 4; nc++)
      #pragma unroll
      for (int r = 0; r < 4; r++) {
        int row = i0 + band + q * 4 + r;
        int col = j0 + nc * 16 + fr;
        sv[nc][r] = (col <= row) ? sA[nc][r] * C2_C : -1e30f;  // log2 domain
      }
    #pragma unroll
    for (int r = 0; r < 4; r++) {
      float mx = fmaxf(fmaxf(sv[0][r], sv[1][r]), fmaxf(sv[2][r], sv[3][r]));
      #pragma unroll
      for (int off = 1; off < 16; off <<= 1) mx = fmaxf(mx, __shfl_xor(mx, off, 64));
      float mn = fmaxf(m[r], mx);
      float alpha = exp2f(m[r] - mn);
      float ps = 0.f;
      #pragma unroll
      for (int nc = 0; nc < 4; nc++) {
        float p = exp2f(sv[nc][r] - mn);
        Ps[band + q * 4 + r][nc * 16 + fr] = f2bu(p);
        ps += p;
      }
      #pragma unroll
      for (int off = 1; off < 16; off <<= 1) ps += __shfl_xor(ps, off, 64);
      l[r] = l[r] * alpha + ps;
      m[r] = mn;
      #pragma unroll
      for (int nc = 0; nc < 4; nc++) oacc[nc][r] *= alpha;
    }
    bf16x8 ap0 = *(const bf16x8*)&Ps[band + fr][q * 8];
    bf16x8 ap1 = *(const bf16x8*)&Ps[band + fr][32 + q * 8];
    #pragma unroll
    for (int nc = 0; nc < 4; nc++) {
      bf16x8 bv0 = *tile_at(Vs, nc * 16 + fr, q);
      bf16x8 bv1 = *tile_at(Vs, nc * 16 + fr, q + 4);
      oacc[nc] = __builtin_amdgcn_mfma_f32_16x16x32_bf16(ap0, bv0, oacc[nc], 0, 0, 0);
      oacc[nc] = __builtin_amdgcn_mfma_f32_16x16x32_bf16(ap1, bv1, oacc[nc], 0, 0, 0);
    }
  }
  // epilogue: g = O - Xs (bf16 normal + transposed), Dv partials
  float linv[4];
  #pragma unroll
  for (int r = 0; r < 4; r++) linv[r] = 1.0f / l[r];
  float dpart[4] = {};
  #pragma unroll
  for (int nc = 0; nc < 4; nc++) {
    ushort_t pg[4];
    #pragma unroll
    for (int r = 0; r < 4; r++) {
      int row = i0 + band + q * 4 + r;
      size_t gi = (size_t)(b * S_LEN + row) * E_DIM + h * HD + nc * 16 + fr;
      float o = oacc[nc][r] * linv[r];
      float g = o - Xs[gi];
      ushort_t bu = f2bu(g);
      Gb[gi] = bu;
      pg[r] = bu;
      dpart[r] += g * o;
    }
    int d = nc * 16 + fr;
    int s0 = i0 + band + q * 4;
    *(uint2*)(Gt + ((size_t)bh * HD + d) * S_LEN + s0) = *(uint2*)pg;
  }
  #pragma unroll
  for (int r = 0; r < 4; r++) {
    #pragma unroll
    for (int off = 1; off < 16; off <<= 1) dpart[r] += __shfl_xor(dpart[r], off, 64);
  }
  if (fr == 0) {
    #pragma unroll
    for (int r = 0; r < 4; r++) {
      size_t sid = (size_t)bh * S_LEN + i0 + band + q * 4 + r;
      mbuf[sid] = m[r] + log2f(l[r]);   // m' folds 1/l into the exponent
      Dv[sid] = dpart[r];
    }
  }
}

// ---- merged backward: block (bh, y): dq for i-tile y (y+1 units) then dk/dv for
//      j-tile y (16-y units) = 17 units/block (perfect balance; round-3 showed splitting
//      costs 5.5x HBM). All staged tiles now global_load_lds into chunk-rotated LDS. ----
__global__ __launch_bounds__(256) void bwd_fused(const ushort_t* __restrict__ Qg,
                                                 const ushort_t* __restrict__ Kg,
                                                 const ushort_t* __restrict__ Vg,
                                                 const ushort_t* __restrict__ Gg,
                                                 const ushort_t* __restrict__ Qt,
                                                 const ushort_t* __restrict__ Kt,
                                                 const ushort_t* __restrict__ Gt,
                                                 const float* __restrict__ mbuf,
                                                 const float* __restrict__ Dv,
                                                 ushort_t* __restrict__ GQ,
                                                 ushort_t* __restrict__ GK,
                                                 ushort_t* __restrict__ GV) {
  int bh = blockIdx.x, y = blockIdx.y;
  int b = bh >> 4, h = bh & 15;
  int tid = threadIdx.x, lane = tid & 63, wv = tid >> 6;
  int fr = lane & 15, q = lane >> 4;
  int band = wv * 16;
  __shared__ ushort_t tA[4][4096];    // staged tiles (chunk-rotated, global_load_lds)
  __shared__ ushort_t tP[2][64][72];  // lane-written P/dS (padded)

  // ================= phase A: dq for i-tile y =================
  {
    ushort_t* Ks = tA[0];           // [j][d]
    ushort_t* Vs = tA[1];           // [j][d]
    ushort_t* Ts = tA[2];           // [d][j] Kt (pre-scaled by SC)
    ushort_t (*dSs)[72] = tP[0];
    int it = y, i0 = it * 64;

    const ushort_t* KbaseA = Kg + (size_t)(b * S_LEN) * E_DIM + h * HD;
    const ushort_t* VbaseA = Vg + (size_t)(b * S_LEN) * E_DIM + h * HD;
    const ushort_t* TbaseA = Kt + (size_t)(bh * HD) * S_LEN;

    const ushort_t* Qrow = Qg + (size_t)(b * S_LEN + i0 + band + fr) * E_DIM + h * HD;
    const ushort_t* Grow = Gg + (size_t)(b * S_LEN + i0 + band + fr) * E_DIM + h * HD;
    bf16x8 aq0 = ldg8(Qrow + q * 8), aq1 = ldg8(Qrow + 32 + q * 8);
    bf16x8 ag0 = ldg8(Grow + q * 8), ag1 = ldg8(Grow + 32 + q * 8);

    float mrow[4], Dr[4];
    #pragma unroll
    for (int r = 0; r < 4; r++) {
      size_t sid = (size_t)bh * S_LEN + i0 + band + q * 4 + r;
      mrow[r] = mbuf[sid]; Dr[r] = Dv[sid];
    }
    f32x4 dqacc[4] = {};

    #pragma unroll 1
    for (int jt = 0; jt <= it; jt++) {
      int j0 = jt * 64;
      __syncthreads();
      stage_tile(KbaseA + (size_t)j0 * E_DIM, E_DIM, Ks, lane, wv);
      stage_tile(VbaseA + (size_t)j0 * E_DIM, E_DIM, Vs, lane, wv);
      stage_tile(TbaseA + j0, S_LEN, Ts, lane, wv);
      __syncthreads();
      f32x4 sA[4], dpA[4];
      #pragma unroll
      for (int nc = 0; nc < 4; nc++) {
        bf16x8 bk0 = *tile_at(Ks, nc * 16 + fr, q);
        bf16x8 bk1 = *tile_at(Ks, nc * 16 + fr, q + 4);
        bf16x8 bv0 = *tile_at(Vs, nc * 16 + fr, q);
        bf16x8 bv1 = *tile_at(Vs, nc * 16 + fr, q + 4);
        f32x4 z = {};
        z = __builtin_amdgcn_mfma_f32_16x16x32_bf16(aq0, bk0, z, 0, 0, 0);
        sA[nc] = __builtin_amdgcn_mfma_f32_16x16x32_bf16(aq1, bk1, z, 0, 0, 0);
        f32x4 z2 = {};
        z2 = __builtin_amdgcn_mfma_f32_16x16x32_bf16(ag0, bv0, z2, 0, 0, 0);
        dpA[nc] = __builtin_amdgcn_mfma_f32_16x16x32_bf16(ag1, bv1, z2, 0, 0, 0);
      }
      #pragma unroll
      for (int nc = 0; nc < 4; nc++)
        #pragma unroll
        for (int r = 0; r < 4; r++) {
          int row = i0 + band + q * 4 + r;
          int col = j0 + nc * 16 + fr;
          float ds = 0.f;
          if (col <= row) {
            float P = exp2f(fmaf(sA[nc][r], C2_C, -mrow[r]));
            ds = P * (dpA[nc][r] - Dr[r]);   // SC lives in Kt
          }
          dSs[band + q * 4 + r][nc * 16 + fr] = f2bu(ds);  // wave-private
        }
      bf16x8 ad0 = *(const bf16x8*)&dSs[band + fr][q * 8];
      bf16x8 ad1 = *(const bf16x8*)&dSs[band + fr][32 + q * 8];
      #pragma unroll
      for (int nc = 0; nc < 4; nc++) {
        bf16x8 bt0 = *tile_at(Ts, nc * 16 + fr, q);
        bf16x8 bt1 = *tile_at(Ts, nc * 16 + fr, q + 4);
        dqacc[nc] = __builtin_amdgcn_mfma_f32_16x16x32_bf16(ad0, bt0, dqacc[nc], 0, 0, 0);
        dqacc[nc] = __builtin_amdgcn_mfma_f32_16x16x32_bf16(ad1, bt1, dqacc[nc], 0, 0, 0);
      }
    }
    #pragma unroll
    for (int nc = 0; nc < 4; nc++)
      #pragma unroll
      for (int r = 0; r < 4; r++) {
        int row = i0 + band + q * 4 + r;
        size_t gi = (size_t)(b * S_LEN + row) * E_DIM + h * HD + nc * 16 + fr;
        GQ[gi] = f2bu(dqacc[nc][r]);
      }
  }

  // ================= phase B: dk/dv for j-tile y =================
  {
    ushort_t* Qs  = tA[0];          // [i][d]
    ushort_t* Gs  = tA[1];          // [i][d]
    ushort_t* Qts = tA[2];          // [d][i] (pre-scaled by SC)
    ushort_t* Gts = tA[3];          // [d][i]
    ushort_t (*PT)[72]  = tP[0];    // [j][i]
    ushort_t (*dST)[72] = tP[1];    // [j][i]
    int jt = y, j0 = jt * 64;

    const ushort_t* QbaseB = Qg + (size_t)(b * S_LEN) * E_DIM + h * HD;
    const ushort_t* GbaseB = Gg + (size_t)(b * S_LEN) * E_DIM + h * HD;
    const ushort_t* QtbaseB = Qt + (size_t)(bh * HD) * S_LEN;
    const ushort_t* GtbaseB = Gt + (size_t)(bh * HD) * S_LEN;

    const ushort_t* Krow = Kg + (size_t)(b * S_LEN + j0 + band + fr) * E_DIM + h * HD;
    const ushort_t* Vrow = Vg + (size_t)(b * S_LEN + j0 + band + fr) * E_DIM + h * HD;
    bf16x8 ak0 = ldg8(Krow + q * 8), ak1 = ldg8(Krow + 32 + q * 8);
    bf16x8 av0 = ldg8(Vrow + q * 8), av1 = ldg8(Vrow + 32 + q * 8);

    f32x4 dkacc[4] = {}, dvacc[4] = {};

    #pragma unroll 1
    for (int i_t = jt; i_t < 16; i_t++) {
      int i0 = i_t * 64;
      __syncthreads();
      stage_tile(QbaseB + (size_t)i0 * E_DIM, E_DIM, Qs, lane, wv);
      stage_tile(GbaseB + (size_t)i0 * E_DIM, E_DIM, Gs, lane, wv);
      stage_tile(QtbaseB + i0, S_LEN, Qts, lane, wv);
      stage_tile(GtbaseB + i0, S_LEN, Gts, lane, wv);
      __syncthreads();
      float mc[4], Dc[4];
      #pragma unroll
      for (int nc = 0; nc < 4; nc++) {
        size_t sid = (size_t)bh * S_LEN + i0 + nc * 16 + fr;
        mc[nc] = mbuf[sid]; Dc[nc] = Dv[sid];
      }
      f32x4 stA[4], dptA[4];
      #pragma unroll
      for (int nc = 0; nc < 4; nc++) {
        bf16x8 bq0 = *tile_at(Qs, nc * 16 + fr, q);
        bf16x8 bq1 = *tile_at(Qs, nc * 16 + fr, q + 4);
        bf16x8 bg0 = *tile_at(Gs, nc * 16 + fr, q);
        bf16x8 bg1 = *tile_at(Gs, nc * 16 + fr, q + 4);
        f32x4 z = {};
        z = __builtin_amdgcn_mfma_f32_16x16x32_bf16(ak0, bq0, z, 0, 0, 0);
        stA[nc] = __builtin_amdgcn_mfma_f32_16x16x32_bf16(ak1, bq1, z, 0, 0, 0);
        f32x4 z2 = {};
        z2 = __builtin_amdgcn_mfma_f32_16x16x32_bf16(av0, bg0, z2, 0, 0, 0);
        dptA[nc] = __builtin_amdgcn_mfma_f32_16x16x32_bf16(av1, bg1, z2, 0, 0, 0);
      }
      #pragma unroll
      for (int nc = 0; nc < 4; nc++)
        #pragma unroll
        for (int r = 0; r < 4; r++) {
          int jrow = j0 + band + q * 4 + r;
          int icol = i0 + nc * 16 + fr;
          float P = 0.f, ds = 0.f;
          if (icol >= jrow) {
            P = exp2f(fmaf(stA[nc][r], C2_C, -mc[nc]));
            ds = P * (dptA[nc][r] - Dc[nc]);   // SC lives in Qt
          }
          PT[band + q * 4 + r][nc * 16 + fr] = f2bu(P);   // wave-private
          dST[band + q * 4 + r][nc * 16 + fr] = f2bu(ds);
        }
      bf16x8 ap0 = *(const bf16x8*)&PT[band + fr][q * 8];
      bf16x8 ap1 = *(const bf16x8*)&PT[band + fr][32 + q * 8];
      bf16x8 ad0 = *(const bf16x8*)&dST[band + fr][q * 8];
      bf16x8 ad1 = *(const bf16x8*)&dST[band + fr][32 + q * 8];
      #pragma unroll
      for (int nc = 0; nc < 4; nc++) {
        bf16x8 bg0 = *tile_at(Gts, nc * 16 + fr, q);
        bf16x8 bg1 = *tile_at(Gts, nc * 16 + fr, q + 4);
        bf16x8 bq0 = *tile_at(Qts, nc * 16 + fr, q);
        bf16x8 bq1 = *tile_at(Qts, nc * 16 + fr, q + 4);
        dvacc[nc] = __builtin_amdgcn_mfma_f32_16x16x32_bf16(ap0, bg0, dvacc[nc], 0, 0, 0);
        dvacc[nc] = __builtin_amdgcn_mfma_f32_16x16x32_bf16(ap1, bg1, dvacc[nc], 0, 0, 0);
        dkacc[nc] = __builtin_amdgcn_mfma_f32_16x16x32_bf16(ad0, bq0, dkacc[nc], 0, 0, 0);
        dkacc[nc] = __builtin_amdgcn_mfma_f32_16x16x32_bf16(ad1, bq1, dkacc[nc], 0, 0, 0);
      }
    }
    #pragma unroll
    for (int nc = 0; nc < 4; nc++)
      #pragma unroll
      for (int r = 0; r < 4; r++) {
        int jrow = j0 + band + q * 4 + r;
        size_t gi = (size_t)(b * S_LEN + jrow) * E_DIM + h * HD + nc * 16 + fr;
        GK[gi] = f2bu(dkacc[nc][r]);
        GV[gi] = f2bu(dvacc[nc][r]);
      }
  }
}

// ---------------- launch ----------------
extern "C" void kernel_launch(void* const* d_in, const int* in_sizes, int n_in,
                              void* d_out, int out_size, void* d_ws, size_t ws_size,
                              hipStream_t stream) {
  const float* T1 = (const float*)d_in[0];
  const float* Wq = (const float*)d_in[1];
  const float* Wk = (const float*)d_in[2];
  const float* Wv = (const float*)d_in[3];
  const float* Wo = (const float*)d_in[4];

  const size_t M2 = 2097152;   // 2048*1024
  const size_t M1 = 1048576;
  float* w = (float*)d_ws;
  float* Xs = w;                       // 8 MB fp32 target
  float* mS = Xs + M2;                 // 64K f32 (stores m')
  float* DvS = mS + 65536;
  ushort_t* u = (ushort_t*)(DvS + 65536);
  ushort_t* W0 = u;          ushort_t* W1 = W0 + M1;  ushort_t* W2 = W1 + M1;
  ushort_t* W3 = W2 + M1;    ushort_t* W4 = W3 + M1;  ushort_t* W5 = W4 + M1;
  ushort_t* Qb = W5 + M1;    ushort_t* Kb = Qb + M2;  ushort_t* Vb = Kb + M2;
  ushort_t* Qt = Vb + M2;    ushort_t* Kt = Qt + M2;  ushort_t* Vt = Kt + M2;
  ushort_t* Gt = Vt + M2;
  ushort_t* Gb = Gt + M2;
  ushort_t* GQb = Gb + M2;   ushort_t* GKb = GQb + M2; ushort_t* GVb = GKb + M2;
  ushort_t* X2b = GVb + M2;
  float* X2 = (float*)d_out;

  // stage-1 aliases (all overwritten before stage-2 uses the slots)
  float* Mf  = (float*)Qb;       // 4 MB
  float* M2f = (float*)Kb;       // 4 MB
  ushort_t* Mb  = Gt;            // 2 MB
  ushort_t* Nb  = Vb;            // 2 MB
  ushort_t* AtB = Qt;            // 2 MB
  ushort_t* T1b = Kt;            // 4 MB

  // iter-1 shortcut aliases (dead before their regions' stage-2 consumers)
  float* Sf  = (float*)GQb;      // 8 MB fp32 scan partials (spans GQb+GKb)
  float* tot = mS;               // 128 KB chunk totals (mS rewritten by fwd of iter 2)
  ushort_t* Sb = GVb;            // 4 MB bf16 scan result

  dim3 pgrid(16, 16);
  dim3 sgrid(16, 16);       // 1024x1024 GEMMs
  dim3 ggrid(16, 32);       // 2048x1024 GEMMs
  dim3 ggrid3(16, 32, 3);   // QKV
  dim3 agrid(BH_CNT, 16);   // attention

  // ---- stage 1 (algebraic): Xs = T * Wo * (3LR·I - 3LR²·M + LR³·M²),  M = WoᵀWo ----
  k_cast<<<(M2 / 4 + 255) / 256, 256, 0, stream>>>(T1, T1b, (int)(M2 / 4));
  prep_w<<<pgrid, 256, 0, stream>>>(Wo, W0, W1);
  // M = W1·W1ᵀ  (fp32 + bf16)
  gemm_mf<4, 1><<<sgrid, 256, 0, stream>>>(W1, nullptr, nullptr, W1, nullptr, nullptr,
                                           Mf, Mb, nullptr, nullptr,
                                           nullptr, nullptr, nullptr, 0.f);
  // M2 = Mb·Mbᵀ (M symmetric)
  gemm_mf<3, 1><<<sgrid, 256, 0, stream>>>(Mb, nullptr, nullptr, Mb, nullptr, nullptr,
                                           M2f, nullptr, nullptr, nullptr,
                                           nullptr, nullptr, nullptr, 0.f);
  k_formN<<<(M1 + 255) / 256, 256, 0, stream>>>(Mf, M2f, Nb);
  // AtB = N·Woᵀ  (symmetric N; this is (Wo·N)ᵀ in [N,K] form)
  gemm_mf<5, 1><<<sgrid, 256, 0, stream>>>(Nb, nullptr, nullptr, W0, nullptr, nullptr,
                                           nullptr, AtB, nullptr, nullptr,
                                           nullptr, nullptr, nullptr, 0.f);
  // stage-2 weights (W0/W1 free after AtB)
  prep_w<<<pgrid, 256, 0, stream>>>(Wq, W0, W3);
  prep_w<<<pgrid, 256, 0, stream>>>(Wk, W1, W4);
  prep_w<<<pgrid, 256, 0, stream>>>(Wv, W2, W5);
  // Xs = T1b·AtBᵀ (fp32)
  gemm_mf<3, 1><<<ggrid, 256, 0, stream>>>(T1b, nullptr, nullptr, AtB, nullptr, nullptr,
                                           Xs, nullptr, nullptr, nullptr,
                                           nullptr, nullptr, nullptr, 0.f);

  // ---- stage 2, iteration 1 (closed form): x=0 => Q=K=V=0, P exactly causal-uniform,
  //      dQ=dK=0, dV = P0^T(-Xs); x1 = LR * (P0^T Xs) * Wv via fp32 suffix scan + one GEMM ----
  k_scan1<<<dim3(E_DIM / 256, 2, 16), 256, 0, stream>>>(Xs, Sf, tot);
  k_scan2<<<dim3(E_DIM / 256, 2, 16), 256, 0, stream>>>(Sf, tot, Sb);
  gemm_mf<6, 1><<<ggrid, 256, 0, stream>>>(Sb, nullptr, nullptr, W5, nullptr, nullptr,
                                           X2, X2b, nullptr, nullptr,
                                           nullptr, nullptr, nullptr, LR_C);

  // ---- stage 2, iterations 2..3 (full PC gradient) ----
  for (int t = 1; t < 3; t++) {
    gemm_mf<0, 1><<<ggrid3, 256, 0, stream>>>(X2b, nullptr, nullptr, W0, W1, W2,
                                              nullptr, Qb, Kb, Vb,
                                              Qt, Kt, Vt, 0.f);
    fwd_fused<<<agrid, 256, 0, stream>>>(Qb, Kb, Vt, Xs, mS, Gb, Gt, DvS);
    bwd_fused<<<agrid, 256, 0, stream>>>(Qb, Kb, Vb, Gb, Qt, Kt, Gt, mS, DvS,
                                         GQb, GKb, GVb);
    gemm_mf<2, 3><<<ggrid, 256, 0, stream>>>(GQb, GKb, GVb, W3, W4, W5,
                                             X2, X2b, nullptr, nullptr,
                                             nullptr, nullptr, nullptr, -LR_C);
  }
}

// Round 7
// 443.184 us; speedup vs baseline: 1.0059x; 1.0059x over previous
//
#include <hip/hip_runtime.h>
#include <hip/hip_bf16.h>
#include <math.h>

// Problem constants (B=2, S=1024, E=1024, H=16, D=64)
#define S_LEN 1024
#define E_DIM 1024
#define NH 16
#define HD 64
#define M_ROWS 2048   // B*S
#define BH_CNT 32     // B*NH

static constexpr float LR_C = 0.01f;
static constexpr float SC_C = 0.125f;                // 1/sqrt(64)
static constexpr float C2_C = 0.125f * 1.44269504f;  // SC * log2(e): log2-domain softmax

typedef unsigned short ushort_t;
typedef __attribute__((ext_vector_type(8))) __bf16 bf16x8;
typedef __attribute__((ext_vector_type(4))) float f32x4;

static __device__ inline ushort_t f2bu(float f) {
  __hip_bfloat16 h = __float2bfloat16(f);
  return *(ushort_t*)&h;
}
static __device__ inline bf16x8 ldg8(const ushort_t* p) { return *(const bf16x8*)p; }

// async global->LDS, 16B per lane; LDS dest = wave-uniform base + lane*16
static __device__ inline void async_cp16(const ushort_t* g, __bf16* lds_wave_base) {
  __builtin_amdgcn_global_load_lds((const __attribute__((address_space(1))) void*)g,
                                   (__attribute__((address_space(3))) void*)lds_wave_base,
                                   16, 0, 0);
}

// ---- 64x64 bf16 tile in unpadded LDS with per-row chunk rotation ----
// element (r,c) lives at ushort offset r*64 + (((c>>3)+r)&7)*8 + (c&7).
// Staged via global_load_lds: wave w, issue t fills slab s=w*2+t (rows 8s..8s+7, 1 KB,
// wave-uniform dest); lane l supplies source chunk c=((l&7)-(l>>3))&7 of row 8s+(l>>3)
// (pre-rotated SOURCE address = m173's swizzle-the-global-side pattern).
// b128 fragment reads hit bank-quad (chunk+row)&7 — same distribution as the old +8 pad.
static __device__ inline void stage_tile(const ushort_t* src, size_t src_stride,
                                         ushort_t* lds, int lane, int wave) {
  int rl = lane >> 3;
  int c = ((lane & 7) - rl) & 7;
  #pragma unroll
  for (int t = 0; t < 2; t++) {
    int s = wave * 2 + t;
    async_cp16(src + (size_t)(s * 8 + rl) * src_stride + c * 8,
               (__bf16*)(lds + s * 512));
  }
}
static __device__ inline const bf16x8* tile_at(const ushort_t* lds, int r, int cchunk) {
  return (const bf16x8*)(lds + r * 64 + (((cchunk + r) & 7) * 8));
}

// ---------------- weight prep: bf16 cast + bf16 transpose, 64x64 tiles ----------------
__global__ __launch_bounds__(256) void prep_w(const float* __restrict__ W,
                                              ushort_t* __restrict__ Wb,
                                              ushort_t* __restrict__ WTb) {
  __shared__ float ts[64][65];
  int bx = blockIdx.x * 64, by = blockIdx.y * 64;
  int t = threadIdx.x;
  int rr = t >> 6, cc = t & 63;
  #pragma unroll
  for (int p = 0; p < 16; p++) {
    int r = p * 4 + rr;
    float v = W[(size_t)(by + r) * E_DIM + bx + cc];
    ts[r][cc] = v;
    Wb[(size_t)(by + r) * E_DIM + bx + cc] = f2bu(v);
  }
  __syncthreads();
  #pragma unroll
  for (int p = 0; p < 16; p++) {
    int r = p * 4 + rr;
    WTb[(size_t)(bx + r) * E_DIM + by + cc] = f2bu(ts[cc][r]);
  }
}

// ---------------- fp32 -> bf16 cast (float4-wide) ----------------
__global__ __launch_bounds__(256) void k_cast(const float* __restrict__ in,
                                              ushort_t* __restrict__ out, int n4) {
  int i = blockIdx.x * 256 + threadIdx.x;
  if (i < n4) {
    float4 v = ((const float4*)in)[i];
    ushort_t p[4] = {f2bu(v.x), f2bu(v.y), f2bu(v.z), f2bu(v.w)};
    *(uint2*)(out + (size_t)i * 4) = *(uint2*)p;
  }
}

// ---------------- N = 3LR*I - 3LR^2*M + LR^3*M2  (bf16 out) ----------------
__global__ __launch_bounds__(256) void k_formN(const float* __restrict__ Mf,
                                               const float* __restrict__ M2f,
                                               ushort_t* __restrict__ Nb) {
  int idx = blockIdx.x * 256 + threadIdx.x;   // 1M elements
  int i = idx >> 10, j = idx & 1023;
  float v = -3.f * LR_C * LR_C * Mf[idx] + LR_C * LR_C * LR_C * M2f[idx];
  if (i == j) v += 3.f * LR_C;
  Nb[idx] = f2bu(v);
}

// ---------------- iter-1 shortcut: suffix scan S[j] = sum_{i>=j} Xs[i]/(i+1) ----------------
// x=0 => Q=K=V=0 => P is exactly causal-uniform, dQ=dK=0, dV = P0^T(-Xs).
// x1 = LR * (P0^T Xs) * Wv. Two-pass chunked scan over the sequence dim.
__global__ __launch_bounds__(256) void k_scan1(const float* __restrict__ Xs,
                                               float* __restrict__ Sf,
                                               float* __restrict__ tot) {
  int e = blockIdx.x * 256 + threadIdx.x;  // column 0..1023
  int b = blockIdx.y;                      // batch
  int z = blockIdx.z;                      // chunk 0..15 (64 rows each)
  float acc = 0.f;
  for (int i = z * 64 + 63; i >= z * 64; i--) {
    size_t idx = ((size_t)b * S_LEN + i) * E_DIM + e;
    acc = fmaf(Xs[idx], 1.0f / (float)(i + 1), acc);
    Sf[idx] = acc;
  }
  tot[((size_t)b * 16 + z) * E_DIM + e] = acc;
}

__global__ __launch_bounds__(256) void k_scan2(const float* __restrict__ Sf,
                                               const float* __restrict__ tot,
                                               ushort_t* __restrict__ Sb) {
  int e = blockIdx.x * 256 + threadIdx.x;
  int b = blockIdx.y;
  int z = blockIdx.z;
  float off = 0.f;
  for (int c = z + 1; c < 16; c++) off += tot[((size_t)b * 16 + c) * E_DIM + e];
  for (int i = z * 64; i < z * 64 + 64; i++) {
    size_t idx = ((size_t)b * S_LEN + i) * E_DIM + e;
    Sb[idx] = f2bu(Sf[idx] + off);
  }
}

// ---------------- bf16 MFMA GEMM, 64x64 tile, BK=64, ASYNC global_load_lds staging ----------
// Four 4KB half-buffers (16KB LDS); 16 barrier-drains per K=1024.
// k-halves accumulated h0 then h1 = identical order to BK=32 -> bit-identical results.
// MODE 2: Cf += alpha*acc (fp32) and Cb0 = bf16(Cf), NSEG K-segments
// MODE 3: Cf = acc (fp32 only)
// MODE 4: Cf = acc and Cb0 = bf16(acc)
// MODE 5: Cb0 = bf16(acc)
// MODE 6: Cf = alpha*acc (overwrite) and Cb0 = bf16(alpha*acc)
template <int MODE, int NSEG>
__global__ __launch_bounds__(256) void gemm_mf(
    const ushort_t* __restrict__ A0, const ushort_t* __restrict__ A1, const ushort_t* __restrict__ A2,
    const ushort_t* __restrict__ B0, const ushort_t* __restrict__ B1, const ushort_t* __restrict__ B2,
    float* __restrict__ Cf,
    ushort_t* __restrict__ Cb0,
    float alpha) {
  const int K = 1024;
  __shared__ __bf16 As0[64][32];
  __shared__ __bf16 As1[64][32];
  __shared__ __bf16 Bs0[64][32];
  __shared__ __bf16 Bs1[64][32];
  int tid = threadIdx.x;
  int m0 = blockIdx.y * 64, n0 = blockIdx.x * 64;

  int lane = tid & 63, wave = tid >> 6;
  int wrow = wave >> 1, wcol = wave & 1;
  int fr = lane & 15, q = lane >> 4;

  int srow = wave * 16 + (lane >> 2);
  int scg = ((lane & 3) + (srow >> 1)) & 3;
  int scol = scg * 8;
  __bf16* ldsA0 = &As0[wave * 16][0];
  __bf16* ldsA1 = &As1[wave * 16][0];
  __bf16* ldsB0 = &Bs0[wave * 16][0];
  __bf16* ldsB1 = &Bs1[wave * 16][0];

  int rA0 = wrow * 32 + fr, rA1r = rA0 + 16;
  int rB0 = wcol * 32 + fr, rB1r = rB0 + 16;
  int cA0 = ((q - (rA0 >> 1)) & 3) * 8;
  int cA1 = ((q - (rA1r >> 1)) & 3) * 8;
  int cB0 = ((q - (rB0 >> 1)) & 3) * 8;
  int cB1 = ((q - (rB1r >> 1)) & 3) * 8;
  const bf16x8* pa0h0 = (const bf16x8*)&As0[rA0][cA0];
  const bf16x8* pa0h1 = (const bf16x8*)&As1[rA0][cA0];
  const bf16x8* pa1h0 = (const bf16x8*)&As0[rA1r][cA1];
  const bf16x8* pa1h1 = (const bf16x8*)&As1[rA1r][cA1];
  const bf16x8* pb0h0 = (const bf16x8*)&Bs0[rB0][cB0];
  const bf16x8* pb0h1 = (const bf16x8*)&Bs1[rB0][cB0];
  const bf16x8* pb1h0 = (const bf16x8*)&Bs0[rB1r][cB1];
  const bf16x8* pb1h1 = (const bf16x8*)&Bs1[rB1r][cB1];

  f32x4 acc[2][2] = {};

  #pragma unroll 1
  for (int seg = 0; seg < NSEG; seg++) {
    const ushort_t* Aseg = (seg == 0) ? A0 : (seg == 1) ? A1 : A2;
    const ushort_t* Bseg = (seg == 0) ? B0 : (seg == 1) ? B1 : B2;
    const ushort_t* ga = Aseg + (size_t)(m0 + srow) * K + scol;
    const ushort_t* gb = Bseg + (size_t)(n0 + srow) * K + scol;
    #pragma unroll 1
    for (int k0 = 0; k0 < K; k0 += 64) {
      __syncthreads();
      async_cp16(ga + k0, ldsA0);
      async_cp16(ga + k0 + 32, ldsA1);
      async_cp16(gb + k0, ldsB0);
      async_cp16(gb + k0 + 32, ldsB1);
      __syncthreads();
      bf16x8 a00 = *pa0h0, a01 = *pa0h1, a10 = *pa1h0, a11 = *pa1h1;
      bf16x8 b00 = *pb0h0, b01 = *pb0h1, b10 = *pb1h0, b11 = *pb1h1;
      acc[0][0] = __builtin_amdgcn_mfma_f32_16x16x32_bf16(a00, b00, acc[0][0], 0, 0, 0);
      acc[0][1] = __builtin_amdgcn_mfma_f32_16x16x32_bf16(a00, b10, acc[0][1], 0, 0, 0);
      acc[1][0] = __builtin_amdgcn_mfma_f32_16x16x32_bf16(a10, b00, acc[1][0], 0, 0, 0);
      acc[1][1] = __builtin_amdgcn_mfma_f32_16x16x32_bf16(a10, b10, acc[1][1], 0, 0, 0);
      acc[0][0] = __builtin_amdgcn_mfma_f32_16x16x32_bf16(a01, b01, acc[0][0], 0, 0, 0);
      acc[0][1] = __builtin_amdgcn_mfma_f32_16x16x32_bf16(a01, b11, acc[0][1], 0, 0, 0);
      acc[1][0] = __builtin_amdgcn_mfma_f32_16x16x32_bf16(a11, b01, acc[1][0], 0, 0, 0);
      acc[1][1] = __builtin_amdgcn_mfma_f32_16x16x32_bf16(a11, b11, acc[1][1], 0, 0, 0);
    }
  }

  // C/D layout: col = lane&15, row = (lane>>4)*4 + reg
  #pragma unroll
  for (int mi = 0; mi < 2; mi++)
    #pragma unroll
    for (int ni = 0; ni < 2; ni++) {
      int col = n0 + wcol * 32 + ni * 16 + fr;
      int row0 = m0 + wrow * 32 + mi * 16 + q * 4;
      #pragma unroll
      for (int r = 0; r < 4; r++) {
        size_t idx = (size_t)(row0 + r) * E_DIM + col;
        float v = acc[mi][ni][r];
        if (MODE == 2) {
          float nv = Cf[idx] + alpha * v;
          Cf[idx] = nv;
          Cb0[idx] = f2bu(nv);
        } else if (MODE == 3) {
          Cf[idx] = v;
        } else if (MODE == 4) {
          Cf[idx] = v;
          Cb0[idx] = f2bu(v);
        } else if (MODE == 6) {
          float nv = alpha * v;
          Cf[idx] = nv;
          Cb0[idx] = f2bu(nv);
        } else {  // MODE 5
          Cb0[idx] = f2bu(v);
        }
      }
    }
}

// ---------------- merged QKV GEMM: one A-stage feeds 3 B-matrices ----------------
// Replaces gemm_mf<0,1> grid (16,32,3): the 3 z-slices shared A (X2b) but re-staged it
// 3x and did only 8 MFMAs per barrier-pair. Merged: A staged once, 24 MFMAs per
// barrier-pair (3x MFMA:drain ratio), A HBM/L2 traffic 1/3. Per-z accumulation order
// identical to the old kernel -> bit-identical outputs. LDS 32 KB, grid (16,32)=2/CU.
__global__ __launch_bounds__(256) void gemm_qkv(
    const ushort_t* __restrict__ A,
    const ushort_t* __restrict__ B0, const ushort_t* __restrict__ B1, const ushort_t* __restrict__ B2,
    ushort_t* __restrict__ Cb0, ushort_t* __restrict__ Cb1, ushort_t* __restrict__ Cb2,
    ushort_t* __restrict__ Ct0, ushort_t* __restrict__ Ct1, ushort_t* __restrict__ Ct2) {
  const int K = 1024;
  __shared__ __bf16 As[2][64][32];
  __shared__ __bf16 Bs[3][2][64][32];
  int tid = threadIdx.x;
  int m0 = blockIdx.y * 64, n0 = blockIdx.x * 64;

  int lane = tid & 63, wave = tid >> 6;
  int wrow = wave >> 1, wcol = wave & 1;
  int fr = lane & 15, q = lane >> 4;

  int srow = wave * 16 + (lane >> 2);
  int scg = ((lane & 3) + (srow >> 1)) & 3;
  int scol = scg * 8;
  __bf16* ldsA0 = &As[0][wave * 16][0];
  __bf16* ldsA1 = &As[1][wave * 16][0];
  __bf16* ldsB00 = &Bs[0][0][wave * 16][0];
  __bf16* ldsB01 = &Bs[0][1][wave * 16][0];
  __bf16* ldsB10 = &Bs[1][0][wave * 16][0];
  __bf16* ldsB11 = &Bs[1][1][wave * 16][0];
  __bf16* ldsB20 = &Bs[2][0][wave * 16][0];
  __bf16* ldsB21 = &Bs[2][1][wave * 16][0];

  int rA0 = wrow * 32 + fr, rA1r = rA0 + 16;
  int rB0 = wcol * 32 + fr, rB1r = rB0 + 16;
  int cA0 = ((q - (rA0 >> 1)) & 3) * 8;
  int cA1 = ((q - (rA1r >> 1)) & 3) * 8;
  int cB0 = ((q - (rB0 >> 1)) & 3) * 8;
  int cB1 = ((q - (rB1r >> 1)) & 3) * 8;
  const bf16x8* pa0h0 = (const bf16x8*)&As[0][rA0][cA0];
  const bf16x8* pa0h1 = (const bf16x8*)&As[1][rA0][cA0];
  const bf16x8* pa1h0 = (const bf16x8*)&As[0][rA1r][cA1];
  const bf16x8* pa1h1 = (const bf16x8*)&As[1][rA1r][cA1];

  f32x4 acc[3][2][2] = {};

  const ushort_t* ga = A + (size_t)(m0 + srow) * K + scol;
  const ushort_t* gb0 = B0 + (size_t)(n0 + srow) * K + scol;
  const ushort_t* gb1 = B1 + (size_t)(n0 + srow) * K + scol;
  const ushort_t* gb2 = B2 + (size_t)(n0 + srow) * K + scol;

  #pragma unroll 1
  for (int k0 = 0; k0 < K; k0 += 64) {
    __syncthreads();
    async_cp16(ga + k0, ldsA0);
    async_cp16(ga + k0 + 32, ldsA1);
    async_cp16(gb0 + k0, ldsB00);
    async_cp16(gb0 + k0 + 32, ldsB01);
    async_cp16(gb1 + k0, ldsB10);
    async_cp16(gb1 + k0 + 32, ldsB11);
    async_cp16(gb2 + k0, ldsB20);
    async_cp16(gb2 + k0 + 32, ldsB21);
    __syncthreads();
    bf16x8 a00 = *pa0h0, a01 = *pa0h1, a10 = *pa1h0, a11 = *pa1h1;
    #pragma unroll
    for (int z = 0; z < 3; z++) {
      bf16x8 b00 = *(const bf16x8*)&Bs[z][0][rB0][cB0];
      bf16x8 b01 = *(const bf16x8*)&Bs[z][1][rB0][cB0];
      bf16x8 b10 = *(const bf16x8*)&Bs[z][0][rB1r][cB1];
      bf16x8 b11 = *(const bf16x8*)&Bs[z][1][rB1r][cB1];
      acc[z][0][0] = __builtin_amdgcn_mfma_f32_16x16x32_bf16(a00, b00, acc[z][0][0], 0, 0, 0);
      acc[z][0][1] = __builtin_amdgcn_mfma_f32_16x16x32_bf16(a00, b10, acc[z][0][1], 0, 0, 0);
      acc[z][1][0] = __builtin_amdgcn_mfma_f32_16x16x32_bf16(a10, b00, acc[z][1][0], 0, 0, 0);
      acc[z][1][1] = __builtin_amdgcn_mfma_f32_16x16x32_bf16(a10, b10, acc[z][1][1], 0, 0, 0);
      acc[z][0][0] = __builtin_amdgcn_mfma_f32_16x16x32_bf16(a01, b01, acc[z][0][0], 0, 0, 0);
      acc[z][0][1] = __builtin_amdgcn_mfma_f32_16x16x32_bf16(a01, b11, acc[z][0][1], 0, 0, 0);
      acc[z][1][0] = __builtin_amdgcn_mfma_f32_16x16x32_bf16(a11, b01, acc[z][1][0], 0, 0, 0);
      acc[z][1][1] = __builtin_amdgcn_mfma_f32_16x16x32_bf16(a11, b11, acc[z][1][1], 0, 0, 0);
    }
  }

  // C/D layout: col = lane&15, row = (lane>>4)*4 + reg
  #pragma unroll
  for (int z = 0; z < 3; z++) {
    ushort_t* Cbz = (z == 0) ? Cb0 : (z == 1) ? Cb1 : Cb2;
    ushort_t* Ctz = (z == 0) ? Ct0 : (z == 1) ? Ct1 : Ct2;
    float tsc = (z == 2) ? 1.0f : SC_C;   // Qt/Kt carry the 1/sqrt(d) factor
    #pragma unroll
    for (int mi = 0; mi < 2; mi++)
      #pragma unroll
      for (int ni = 0; ni < 2; ni++) {
        int col = n0 + wcol * 32 + ni * 16 + fr;
        int row0 = m0 + wrow * 32 + mi * 16 + q * 4;
        ushort_t pk[4];
        #pragma unroll
        for (int r = 0; r < 4; r++) {
          size_t idx = (size_t)(row0 + r) * E_DIM + col;
          float v = acc[z][mi][ni][r];
          Cbz[idx] = f2bu(v);
          pk[r] = f2bu(v * tsc);
        }
        int hh = col >> 6, dd = col & 63;
        int bb = row0 >> 10, ss = row0 & 1023;
        *(uint2*)(Ctz + ((size_t)((bb * NH + hh) * HD + dd)) * S_LEN + ss) = *(uint2*)pk;
      }
  }
}

// ====================== MFMA attention, LDS-staged ======================

// ---- fused fwd: single-pass flash, log2-domain online softmax; emits m' = m + log2(l),
//      g=O-Xs (bf16 + transposed), Dv. grid (bh=32, y=16), balanced pairing.
//      K/V tiles staged via global_load_lds into chunk-rotated unpadded LDS. ----
__global__ __launch_bounds__(256) void fwd_fused(const ushort_t* __restrict__ Qg,
                                                 const ushort_t* __restrict__ Kg,
                                                 const ushort_t* __restrict__ Vt,
                                                 const float* __restrict__ Xs,
                                                 float* __restrict__ mbuf,
                                                 ushort_t* __restrict__ Gb,
                                                 ushort_t* __restrict__ Gt,
                                                 float* __restrict__ Dv) {
  int bh = blockIdx.x, y = blockIdx.y;
  int it = (y < 8) ? (15 - y) : (y - 8);
  int b = bh >> 4, h = bh & 15;
  int tid = threadIdx.x, lane = tid & 63, wv = tid >> 6;
  int fr = lane & 15, q = lane >> 4;
  int i0 = it * 64, band = wv * 16;
  __shared__ ushort_t Ks[4096];     // [j][d] chunk-rotated
  __shared__ ushort_t Vs[4096];     // [d][j] chunk-rotated
  __shared__ ushort_t Ps[64][72];   // [i][j] wave-private bands (lane-written)

  const ushort_t* Kbase = Kg + (size_t)(b * S_LEN) * E_DIM + h * HD;
  const ushort_t* Vbase = Vt + (size_t)(bh * HD) * S_LEN;

  const ushort_t* Qrow = Qg + (size_t)(b * S_LEN + i0 + band + fr) * E_DIM + h * HD;
  bf16x8 aq0 = ldg8(Qrow + q * 8);
  bf16x8 aq1 = ldg8(Qrow + 32 + q * 8);

  float m[4], l[4];
  #pragma unroll
  for (int r = 0; r < 4; r++) { m[r] = -1e30f; l[r] = 0.f; }
  f32x4 oacc[4] = {};

  #pragma unroll 1
  for (int jt = 0; jt <= it; jt++) {
    int j0 = jt * 64;
    __syncthreads();
    stage_tile(Kbase + (size_t)j0 * E_DIM, E_DIM, Ks, lane, wv);
    stage_tile(Vbase + j0, S_LEN, Vs, lane, wv);
    __syncthreads();
    f32x4 sA[4];
    #pragma unroll
    for (int nc = 0; nc < 4; nc++) {
      bf16x8 bk0 = *tile_at(Ks, nc * 16 + fr, q);
      bf16x8 bk1 = *tile_at(Ks, nc * 16 + fr, q + 4);
      f32x4 z = {};
      z = __builtin_amdgcn_mfma_f32_16x16x32_bf16(aq0, bk0, z, 0, 0, 0);
      sA[nc] = __builtin_amdgcn_mfma_f32_16x16x32_bf16(aq1, bk1, z, 0, 0, 0);
    }
    float sv[4][4];
    #pragma unroll
    for (int nc = 0; nc < 4; nc++)
      #pragma unroll
      for (int r = 0; r < 4; r++) {
        int row = i0 + band + q * 4 + r;
        int col = j0 + nc * 16 + fr;
        sv[nc][r] = (col <= row) ? sA[nc][r] * C2_C : -1e30f;  // log2 domain
      }
    #pragma unroll
    for (int r = 0; r < 4; r++) {
      float mx = fmaxf(fmaxf(sv[0][r], sv[1][r]), fmaxf(sv[2][r], sv[3][r]));
      #pragma unroll
      for (int off = 1; off < 16; off <<= 1) mx = fmaxf(mx, __shfl_xor(mx, off, 64));
      float mn = fmaxf(m[r], mx);
      float alpha = exp2f(m[r] - mn);
      float ps = 0.f;
      #pragma unroll
      for (int nc = 0; nc < 4; nc++) {
        float p = exp2f(sv[nc][r] - mn);
        Ps[band + q * 4 + r][nc * 16 + fr] = f2bu(p);
        ps += p;
      }
      #pragma unroll
      for (int off = 1; off < 16; off <<= 1) ps += __shfl_xor(ps, off, 64);
      l[r] = l[r] * alpha + ps;
      m[r] = mn;
      #pragma unroll
      for (int nc = 0; nc < 4; nc++) oacc[nc][r] *= alpha;
    }
    bf16x8 ap0 = *(const bf16x8*)&Ps[band + fr][q * 8];
    bf16x8 ap1 = *(const bf16x8*)&Ps[band + fr][32 + q * 8];
    #pragma unroll
    for (int nc = 0; nc < 4; nc++) {
      bf16x8 bv0 = *tile_at(Vs, nc * 16 + fr, q);
      bf16x8 bv1 = *tile_at(Vs, nc * 16 + fr, q + 4);
      oacc[nc] = __builtin_amdgcn_mfma_f32_16x16x32_bf16(ap0, bv0, oacc[nc], 0, 0, 0);
      oacc[nc] = __builtin_amdgcn_mfma_f32_16x16x32_bf16(ap1, bv1, oacc[nc], 0, 0, 0);
    }
  }
  // epilogue: g = O - Xs (bf16 normal + transposed), Dv partials
  float linv[4];
  #pragma unroll
  for (int r = 0; r < 4; r++) linv[r] = 1.0f / l[r];
  float dpart[4] = {};
  #pragma unroll
  for (int nc = 0; nc < 4; nc++) {
    ushort_t pg[4];
    #pragma unroll
    for (int r = 0; r < 4; r++) {
      int row = i0 + band + q * 4 + r;
      size_t gi = (size_t)(b * S_LEN + row) * E_DIM + h * HD + nc * 16 + fr;
      float o = oacc[nc][r] * linv[r];
      float g = o - Xs[gi];
      ushort_t bu = f2bu(g);
      Gb[gi] = bu;
      pg[r] = bu;
      dpart[r] += g * o;
    }
    int d = nc * 16 + fr;
    int s0 = i0 + band + q * 4;
    *(uint2*)(Gt + ((size_t)bh * HD + d) * S_LEN + s0) = *(uint2*)pg;
  }
  #pragma unroll
  for (int r = 0; r < 4; r++) {
    #pragma unroll
    for (int off = 1; off < 16; off <<= 1) dpart[r] += __shfl_xor(dpart[r], off, 64);
  }
  if (fr == 0) {
    #pragma unroll
    for (int r = 0; r < 4; r++) {
      size_t sid = (size_t)bh * S_LEN + i0 + band + q * 4 + r;
      mbuf[sid] = m[r] + log2f(l[r]);   // m' folds 1/l into the exponent
      Dv[sid] = dpart[r];
    }
  }
}

// ---- merged backward: block (bh, y): dq for i-tile y (y+1 units) then dk/dv for
//      j-tile y (16-y units) = 17 units/block (perfect balance; round-3 showed splitting
//      costs 5.5x HBM). All staged tiles via global_load_lds into chunk-rotated LDS. ----
__global__ __launch_bounds__(256) void bwd_fused(const ushort_t* __restrict__ Qg,
                                                 const ushort_t* __restrict__ Kg,
                                                 const ushort_t* __restrict__ Vg,
                                                 const ushort_t* __restrict__ Gg,
                                                 const ushort_t* __restrict__ Qt,
                                                 const ushort_t* __restrict__ Kt,
                                                 const ushort_t* __restrict__ Gt,
                                                 const float* __restrict__ mbuf,
                                                 const float* __restrict__ Dv,
                                                 ushort_t* __restrict__ GQ,
                                                 ushort_t* __restrict__ GK,
                                                 ushort_t* __restrict__ GV) {
  int bh = blockIdx.x, y = blockIdx.y;
  int b = bh >> 4, h = bh & 15;
  int tid = threadIdx.x, lane = tid & 63, wv = tid >> 6;
  int fr = lane & 15, q = lane >> 4;
  int band = wv * 16;
  __shared__ ushort_t tA[4][4096];    // staged tiles (chunk-rotated, global_load_lds)
  __shared__ ushort_t tP[2][64][72];  // lane-written P/dS (padded)

  // ================= phase A: dq for i-tile y =================
  {
    ushort_t* Ks = tA[0];           // [j][d]
    ushort_t* Vs = tA[1];           // [j][d]
    ushort_t* Ts = tA[2];           // [d][j] Kt (pre-scaled by SC)
    ushort_t (*dSs)[72] = tP[0];
    int it = y, i0 = it * 64;

    const ushort_t* KbaseA = Kg + (size_t)(b * S_LEN) * E_DIM + h * HD;
    const ushort_t* VbaseA = Vg + (size_t)(b * S_LEN) * E_DIM + h * HD;
    const ushort_t* TbaseA = Kt + (size_t)(bh * HD) * S_LEN;

    const ushort_t* Qrow = Qg + (size_t)(b * S_LEN + i0 + band + fr) * E_DIM + h * HD;
    const ushort_t* Grow = Gg + (size_t)(b * S_LEN + i0 + band + fr) * E_DIM + h * HD;
    bf16x8 aq0 = ldg8(Qrow + q * 8), aq1 = ldg8(Qrow + 32 + q * 8);
    bf16x8 ag0 = ldg8(Grow + q * 8), ag1 = ldg8(Grow + 32 + q * 8);

    float mrow[4], Dr[4];
    #pragma unroll
    for (int r = 0; r < 4; r++) {
      size_t sid = (size_t)bh * S_LEN + i0 + band + q * 4 + r;
      mrow[r] = mbuf[sid]; Dr[r] = Dv[sid];
    }
    f32x4 dqacc[4] = {};

    #pragma unroll 1
    for (int jt = 0; jt <= it; jt++) {
      int j0 = jt * 64;
      __syncthreads();
      stage_tile(KbaseA + (size_t)j0 * E_DIM, E_DIM, Ks, lane, wv);
      stage_tile(VbaseA + (size_t)j0 * E_DIM, E_DIM, Vs, lane, wv);
      stage_tile(TbaseA + j0, S_LEN, Ts, lane, wv);
      __syncthreads();
      f32x4 sA[4], dpA[4];
      #pragma unroll
      for (int nc = 0; nc < 4; nc++) {
        bf16x8 bk0 = *tile_at(Ks, nc * 16 + fr, q);
        bf16x8 bk1 = *tile_at(Ks, nc * 16 + fr, q + 4);
        bf16x8 bv0 = *tile_at(Vs, nc * 16 + fr, q);
        bf16x8 bv1 = *tile_at(Vs, nc * 16 + fr, q + 4);
        f32x4 z = {};
        z = __builtin_amdgcn_mfma_f32_16x16x32_bf16(aq0, bk0, z, 0, 0, 0);
        sA[nc] = __builtin_amdgcn_mfma_f32_16x16x32_bf16(aq1, bk1, z, 0, 0, 0);
        f32x4 z2 = {};
        z2 = __builtin_amdgcn_mfma_f32_16x16x32_bf16(ag0, bv0, z2, 0, 0, 0);
        dpA[nc] = __builtin_amdgcn_mfma_f32_16x16x32_bf16(ag1, bv1, z2, 0, 0, 0);
      }
      #pragma unroll
      for (int nc = 0; nc < 4; nc++)
        #pragma unroll
        for (int r = 0; r < 4; r++) {
          int row = i0 + band + q * 4 + r;
          int col = j0 + nc * 16 + fr;
          float ds = 0.f;
          if (col <= row) {
            float P = exp2f(fmaf(sA[nc][r], C2_C, -mrow[r]));
            ds = P * (dpA[nc][r] - Dr[r]);   // SC lives in Kt
          }
          dSs[band + q * 4 + r][nc * 16 + fr] = f2bu(ds);  // wave-private
        }
      bf16x8 ad0 = *(const bf16x8*)&dSs[band + fr][q * 8];
      bf16x8 ad1 = *(const bf16x8*)&dSs[band + fr][32 + q * 8];
      #pragma unroll
      for (int nc = 0; nc < 4; nc++) {
        bf16x8 bt0 = *tile_at(Ts, nc * 16 + fr, q);
        bf16x8 bt1 = *tile_at(Ts, nc * 16 + fr, q + 4);
        dqacc[nc] = __builtin_amdgcn_mfma_f32_16x16x32_bf16(ad0, bt0, dqacc[nc], 0, 0, 0);
        dqacc[nc] = __builtin_amdgcn_mfma_f32_16x16x32_bf16(ad1, bt1, dqacc[nc], 0, 0, 0);
      }
    }
    #pragma unroll
    for (int nc = 0; nc < 4; nc++)
      #pragma unroll
      for (int r = 0; r < 4; r++) {
        int row = i0 + band + q * 4 + r;
        size_t gi = (size_t)(b * S_LEN + row) * E_DIM + h * HD + nc * 16 + fr;
        GQ[gi] = f2bu(dqacc[nc][r]);
      }
  }

  // ================= phase B: dk/dv for j-tile y =================
  {
    ushort_t* Qs  = tA[0];          // [i][d]
    ushort_t* Gs  = tA[1];          // [i][d]
    ushort_t* Qts = tA[2];          // [d][i] (pre-scaled by SC)
    ushort_t* Gts = tA[3];          // [d][i]
    ushort_t (*PT)[72]  = tP[0];    // [j][i]
    ushort_t (*dST)[72] = tP[1];    // [j][i]
    int jt = y, j0 = jt * 64;

    const ushort_t* QbaseB = Qg + (size_t)(b * S_LEN) * E_DIM + h * HD;
    const ushort_t* GbaseB = Gg + (size_t)(b * S_LEN) * E_DIM + h * HD;
    const ushort_t* QtbaseB = Qt + (size_t)(bh * HD) * S_LEN;
    const ushort_t* GtbaseB = Gt + (size_t)(bh * HD) * S_LEN;

    const ushort_t* Krow = Kg + (size_t)(b * S_LEN + j0 + band + fr) * E_DIM + h * HD;
    const ushort_t* Vrow = Vg + (size_t)(b * S_LEN + j0 + band + fr) * E_DIM + h * HD;
    bf16x8 ak0 = ldg8(Krow + q * 8), ak1 = ldg8(Krow + 32 + q * 8);
    bf16x8 av0 = ldg8(Vrow + q * 8), av1 = ldg8(Vrow + 32 + q * 8);

    f32x4 dkacc[4] = {}, dvacc[4] = {};

    #pragma unroll 1
    for (int i_t = jt; i_t < 16; i_t++) {
      int i0 = i_t * 64;
      __syncthreads();
      stage_tile(QbaseB + (size_t)i0 * E_DIM, E_DIM, Qs, lane, wv);
      stage_tile(GbaseB + (size_t)i0 * E_DIM, E_DIM, Gs, lane, wv);
      stage_tile(QtbaseB + i0, S_LEN, Qts, lane, wv);
      stage_tile(GtbaseB + i0, S_LEN, Gts, lane, wv);
      __syncthreads();
      float mc[4], Dc[4];
      #pragma unroll
      for (int nc = 0; nc < 4; nc++) {
        size_t sid = (size_t)bh * S_LEN + i0 + nc * 16 + fr;
        mc[nc] = mbuf[sid]; Dc[nc] = Dv[sid];
      }
      f32x4 stA[4], dptA[4];
      #pragma unroll
      for (int nc = 0; nc < 4; nc++) {
        bf16x8 bq0 = *tile_at(Qs, nc * 16 + fr, q);
        bf16x8 bq1 = *tile_at(Qs, nc * 16 + fr, q + 4);
        bf16x8 bg0 = *tile_at(Gs, nc * 16 + fr, q);
        bf16x8 bg1 = *tile_at(Gs, nc * 16 + fr, q + 4);
        f32x4 z = {};
        z = __builtin_amdgcn_mfma_f32_16x16x32_bf16(ak0, bq0, z, 0, 0, 0);
        stA[nc] = __builtin_amdgcn_mfma_f32_16x16x32_bf16(ak1, bq1, z, 0, 0, 0);
        f32x4 z2 = {};
        z2 = __builtin_amdgcn_mfma_f32_16x16x32_bf16(av0, bg0, z2, 0, 0, 0);
        dptA[nc] = __builtin_amdgcn_mfma_f32_16x16x32_bf16(av1, bg1, z2, 0, 0, 0);
      }
      #pragma unroll
      for (int nc = 0; nc < 4; nc++)
        #pragma unroll
        for (int r = 0; r < 4; r++) {
          int jrow = j0 + band + q * 4 + r;
          int icol = i0 + nc * 16 + fr;
          float P = 0.f, ds = 0.f;
          if (icol >= jrow) {
            P = exp2f(fmaf(stA[nc][r], C2_C, -mc[nc]));
            ds = P * (dptA[nc][r] - Dc[nc]);   // SC lives in Qt
          }
          PT[band + q * 4 + r][nc * 16 + fr] = f2bu(P);   // wave-private
          dST[band + q * 4 + r][nc * 16 + fr] = f2bu(ds);
        }
      bf16x8 ap0 = *(const bf16x8*)&PT[band + fr][q * 8];
      bf16x8 ap1 = *(const bf16x8*)&PT[band + fr][32 + q * 8];
      bf16x8 ad0 = *(const bf16x8*)&dST[band + fr][q * 8];
      bf16x8 ad1 = *(const bf16x8*)&dST[band + fr][32 + q * 8];
      #pragma unroll
      for (int nc = 0; nc < 4; nc++) {
        bf16x8 bg0 = *tile_at(Gts, nc * 16 + fr, q);
        bf16x8 bg1 = *tile_at(Gts, nc * 16 + fr, q + 4);
        bf16x8 bq0 = *tile_at(Qts, nc * 16 + fr, q);
        bf16x8 bq1 = *tile_at(Qts, nc * 16 + fr, q + 4);
        dvacc[nc] = __builtin_amdgcn_mfma_f32_16x16x32_bf16(ap0, bg0, dvacc[nc], 0, 0, 0);
        dvacc[nc] = __builtin_amdgcn_mfma_f32_16x16x32_bf16(ap1, bg1, dvacc[nc], 0, 0, 0);
        dkacc[nc] = __builtin_amdgcn_mfma_f32_16x16x32_bf16(ad0, bq0, dkacc[nc], 0, 0, 0);
        dkacc[nc] = __builtin_amdgcn_mfma_f32_16x16x32_bf16(ad1, bq1, dkacc[nc], 0, 0, 0);
      }
    }
    #pragma unroll
    for (int nc = 0; nc < 4; nc++)
      #pragma unroll
      for (int r = 0; r < 4; r++) {
        int jrow = j0 + band + q * 4 + r;
        size_t gi = (size_t)(b * S_LEN + jrow) * E_DIM + h * HD + nc * 16 + fr;
        GK[gi] = f2bu(dkacc[nc][r]);
        GV[gi] = f2bu(dvacc[nc][r]);
      }
  }
}

// ---------------- launch ----------------
extern "C" void kernel_launch(void* const* d_in, const int* in_sizes, int n_in,
                              void* d_out, int out_size, void* d_ws, size_t ws_size,
                              hipStream_t stream) {
  const float* T1 = (const float*)d_in[0];
  const float* Wq = (const float*)d_in[1];
  const float* Wk = (const float*)d_in[2];
  const float* Wv = (const float*)d_in[3];
  const float* Wo = (const float*)d_in[4];

  const size_t M2 = 2097152;   // 2048*1024
  const size_t M1 = 1048576;
  float* w = (float*)d_ws;
  float* Xs = w;                       // 8 MB fp32 target
  float* mS = Xs + M2;                 // 64K f32 (stores m')
  float* DvS = mS + 65536;
  ushort_t* u = (ushort_t*)(DvS + 65536);
  ushort_t* W0 = u;          ushort_t* W1 = W0 + M1;  ushort_t* W2 = W1 + M1;
  ushort_t* W3 = W2 + M1;    ushort_t* W4 = W3 + M1;  ushort_t* W5 = W4 + M1;
  ushort_t* Qb = W5 + M1;    ushort_t* Kb = Qb + M2;  ushort_t* Vb = Kb + M2;
  ushort_t* Qt = Vb + M2;    ushort_t* Kt = Qt + M2;  ushort_t* Vt = Kt + M2;
  ushort_t* Gt = Vt + M2;
  ushort_t* Gb = Gt + M2;
  ushort_t* GQb = Gb + M2;   ushort_t* GKb = GQb + M2; ushort_t* GVb = GKb + M2;
  ushort_t* X2b = GVb + M2;
  float* X2 = (float*)d_out;

  // stage-1 aliases (all overwritten before stage-2 uses the slots)
  float* Mf  = (float*)Qb;       // 4 MB
  float* M2f = (float*)Kb;       // 4 MB
  ushort_t* Mb  = Gt;            // 2 MB
  ushort_t* Nb  = Vb;            // 2 MB
  ushort_t* AtB = Qt;            // 2 MB
  ushort_t* T1b = Kt;            // 4 MB

  // iter-1 shortcut aliases (dead before their regions' stage-2 consumers)
  float* Sf  = (float*)GQb;      // 8 MB fp32 scan partials (spans GQb+GKb)
  float* tot = mS;               // 128 KB chunk totals (mS rewritten by fwd of iter 2)
  ushort_t* Sb = GVb;            // 4 MB bf16 scan result

  dim3 pgrid(16, 16);
  dim3 sgrid(16, 16);       // 1024x1024 GEMMs
  dim3 ggrid(16, 32);       // 2048x1024 GEMMs
  dim3 agrid(BH_CNT, 16);   // attention

  // ---- stage 1 (algebraic): Xs = T * Wo * (3LR·I - 3LR²·M + LR³·M²),  M = WoᵀWo ----
  k_cast<<<(M2 / 4 + 255) / 256, 256, 0, stream>>>(T1, T1b, (int)(M2 / 4));
  prep_w<<<pgrid, 256, 0, stream>>>(Wo, W0, W1);
  // M = W1·W1ᵀ  (fp32 + bf16)
  gemm_mf<4, 1><<<sgrid, 256, 0, stream>>>(W1, nullptr, nullptr, W1, nullptr, nullptr,
                                           Mf, Mb, 0.f);
  // M2 = Mb·Mbᵀ (M symmetric)
  gemm_mf<3, 1><<<sgrid, 256, 0, stream>>>(Mb, nullptr, nullptr, Mb, nullptr, nullptr,
                                           M2f, nullptr, 0.f);
  k_formN<<<(M1 + 255) / 256, 256, 0, stream>>>(Mf, M2f, Nb);
  // AtB = N·Woᵀ  (symmetric N; this is (Wo·N)ᵀ in [N,K] form)
  gemm_mf<5, 1><<<sgrid, 256, 0, stream>>>(Nb, nullptr, nullptr, W0, nullptr, nullptr,
                                           nullptr, AtB, 0.f);
  // stage-2 weights (W0/W1 free after AtB)
  prep_w<<<pgrid, 256, 0, stream>>>(Wq, W0, W3);
  prep_w<<<pgrid, 256, 0, stream>>>(Wk, W1, W4);
  prep_w<<<pgrid, 256, 0, stream>>>(Wv, W2, W5);
  // Xs = T1b·AtBᵀ (fp32)
  gemm_mf<3, 1><<<ggrid, 256, 0, stream>>>(T1b, nullptr, nullptr, AtB, nullptr, nullptr,
                                           Xs, nullptr, 0.f);

  // ---- stage 2, iteration 1 (closed form): x=0 => Q=K=V=0, P exactly causal-uniform,
  //      dQ=dK=0, dV = P0^T(-Xs); x1 = LR * (P0^T Xs) * Wv via fp32 suffix scan + one GEMM ----
  k_scan1<<<dim3(E_DIM / 256, 2, 16), 256, 0, stream>>>(Xs, Sf, tot);
  k_scan2<<<dim3(E_DIM / 256, 2, 16), 256, 0, stream>>>(Sf, tot, Sb);
  gemm_mf<6, 1><<<ggrid, 256, 0, stream>>>(Sb, nullptr, nullptr, W5, nullptr, nullptr,
                                           X2, X2b, LR_C);

  // ---- stage 2, iterations 2..3 (full PC gradient) ----
  for (int t = 1; t < 3; t++) {
    gemm_qkv<<<ggrid, 256, 0, stream>>>(X2b, W0, W1, W2,
                                        Qb, Kb, Vb, Qt, Kt, Vt);
    fwd_fused<<<agrid, 256, 0, stream>>>(Qb, Kb, Vt, Xs, mS, Gb, Gt, DvS);
    bwd_fused<<<agrid, 256, 0, stream>>>(Qb, Kb, Vb, Gb, Qt, Kt, Gt, mS, DvS,
                                         GQb, GKb, GVb);
    gemm_mf<2, 3><<<ggrid, 256, 0, stream>>>(GQb, GKb, GVb, W3, W4, W5,
                                             X2, X2b, -LR_C);
  }
}

// Round 8
// 429.440 us; speedup vs baseline: 1.0381x; 1.0320x over previous
//
#include <hip/hip_runtime.h>
#include <hip/hip_bf16.h>
#include <math.h>

// Problem constants (B=2, S=1024, E=1024, H=16, D=64)
#define S_LEN 1024
#define E_DIM 1024
#define NH 16
#define HD 64
#define M_ROWS 2048   // B*S
#define BH_CNT 32     // B*NH

static constexpr float LR_C = 0.01f;
static constexpr float SC_C = 0.125f;                // 1/sqrt(64)
static constexpr float C2_C = 0.125f * 1.44269504f;  // SC * log2(e): log2-domain softmax

typedef unsigned short ushort_t;
typedef __attribute__((ext_vector_type(8))) __bf16 bf16x8;
typedef __attribute__((ext_vector_type(4))) float f32x4;

static __device__ inline ushort_t f2bu(float f) {
  __hip_bfloat16 h = __float2bfloat16(f);
  return *(ushort_t*)&h;
}
static __device__ inline bf16x8 ldg8(const ushort_t* p) { return *(const bf16x8*)p; }

// async global->LDS, 16B per lane; LDS dest = wave-uniform base + lane*16
static __device__ inline void async_cp16(const ushort_t* g, __bf16* lds_wave_base) {
  __builtin_amdgcn_global_load_lds((const __attribute__((address_space(1))) void*)g,
                                   (__attribute__((address_space(3))) void*)lds_wave_base,
                                   16, 0, 0);
}

// ---- 64x64 bf16 tile in unpadded LDS with per-row chunk rotation ----
// element (r,c) lives at ushort offset r*64 + (((c>>3)+r)&7)*8 + (c&7).
// Staged via global_load_lds: wave w, issue t fills slab s=w*2+t (rows 8s..8s+7, 1 KB,
// wave-uniform dest); lane l supplies source chunk c=((l&7)-(l>>3))&7 of row 8s+(l>>3)
// (pre-rotated SOURCE address = m173's swizzle-the-global-side pattern).
// b128 fragment reads hit bank-quad (chunk+row)&7 — same distribution as the old +8 pad.
static __device__ inline void stage_tile(const ushort_t* src, size_t src_stride,
                                         ushort_t* lds, int lane, int wave) {
  int rl = lane >> 3;
  int c = ((lane & 7) - rl) & 7;
  #pragma unroll
  for (int t = 0; t < 2; t++) {
    int s = wave * 2 + t;
    async_cp16(src + (size_t)(s * 8 + rl) * src_stride + c * 8,
               (__bf16*)(lds + s * 512));
  }
}
static __device__ inline const bf16x8* tile_at(const ushort_t* lds, int r, int cchunk) {
  return (const bf16x8*)(lds + r * 64 + (((cchunk + r) & 7) * 8));
}

// ---------------- weight prep: bf16 cast + bf16 transpose, 64x64 tiles ----------------
__global__ __launch_bounds__(256) void prep_w(const float* __restrict__ W,
                                              ushort_t* __restrict__ Wb,
                                              ushort_t* __restrict__ WTb) {
  __shared__ float ts[64][65];
  int bx = blockIdx.x * 64, by = blockIdx.y * 64;
  int t = threadIdx.x;
  int rr = t >> 6, cc = t & 63;
  #pragma unroll
  for (int p = 0; p < 16; p++) {
    int r = p * 4 + rr;
    float v = W[(size_t)(by + r) * E_DIM + bx + cc];
    ts[r][cc] = v;
    Wb[(size_t)(by + r) * E_DIM + bx + cc] = f2bu(v);
  }
  __syncthreads();
  #pragma unroll
  for (int p = 0; p < 16; p++) {
    int r = p * 4 + rr;
    WTb[(size_t)(bx + r) * E_DIM + by + cc] = f2bu(ts[cc][r]);
  }
}

// ---------------- fp32 -> bf16 cast (float4-wide) ----------------
__global__ __launch_bounds__(256) void k_cast(const float* __restrict__ in,
                                              ushort_t* __restrict__ out, int n4) {
  int i = blockIdx.x * 256 + threadIdx.x;
  if (i < n4) {
    float4 v = ((const float4*)in)[i];
    ushort_t p[4] = {f2bu(v.x), f2bu(v.y), f2bu(v.z), f2bu(v.w)};
    *(uint2*)(out + (size_t)i * 4) = *(uint2*)p;
  }
}

// ---------------- N = 3LR*I - 3LR^2*M + LR^3*M2  (bf16 out) ----------------
__global__ __launch_bounds__(256) void k_formN(const float* __restrict__ Mf,
                                               const float* __restrict__ M2f,
                                               ushort_t* __restrict__ Nb) {
  int idx = blockIdx.x * 256 + threadIdx.x;   // 1M elements
  int i = idx >> 10, j = idx & 1023;
  float v = -3.f * LR_C * LR_C * Mf[idx] + LR_C * LR_C * LR_C * M2f[idx];
  if (i == j) v += 3.f * LR_C;
  Nb[idx] = f2bu(v);
}

// ---------------- iter-1 shortcut: suffix scan S[j] = sum_{i>=j} Xs[i]/(i+1) ----------------
// x=0 => Q=K=V=0 => P is exactly causal-uniform, dQ=dK=0, dV = P0^T(-Xs).
// x1 = LR * (P0^T Xs) * Wv. Two-pass chunked scan over the sequence dim.
__global__ __launch_bounds__(256) void k_scan1(const float* __restrict__ Xs,
                                               float* __restrict__ Sf,
                                               float* __restrict__ tot) {
  int e = blockIdx.x * 256 + threadIdx.x;  // column 0..1023
  int b = blockIdx.y;                      // batch
  int z = blockIdx.z;                      // chunk 0..15 (64 rows each)
  float acc = 0.f;
  for (int i = z * 64 + 63; i >= z * 64; i--) {
    size_t idx = ((size_t)b * S_LEN + i) * E_DIM + e;
    acc = fmaf(Xs[idx], 1.0f / (float)(i + 1), acc);
    Sf[idx] = acc;
  }
  tot[((size_t)b * 16 + z) * E_DIM + e] = acc;
}

__global__ __launch_bounds__(256) void k_scan2(const float* __restrict__ Sf,
                                               const float* __restrict__ tot,
                                               ushort_t* __restrict__ Sb) {
  int e = blockIdx.x * 256 + threadIdx.x;
  int b = blockIdx.y;
  int z = blockIdx.z;
  float off = 0.f;
  for (int c = z + 1; c < 16; c++) off += tot[((size_t)b * 16 + c) * E_DIM + e];
  for (int i = z * 64; i < z * 64 + 64; i++) {
    size_t idx = ((size_t)b * S_LEN + i) * E_DIM + e;
    Sb[idx] = f2bu(Sf[idx] + off);
  }
}

// ---------------- bf16 MFMA GEMM, 64x64 tile, BK=64, ASYNC global_load_lds staging ----------
// Four 4KB half-buffers (16KB LDS); 16 barrier-drains per K=1024.
// k-halves accumulated h0 then h1 = identical order to BK=32 -> bit-identical results.
// MODE 3: Cf = acc (fp32 only)
// MODE 4: Cf = acc and Cb0 = bf16(acc)
// MODE 5: Cb0 = bf16(acc)
// MODE 6: Cf = alpha*acc (overwrite) and Cb0 = bf16(alpha*acc)
template <int MODE, int NSEG>
__global__ __launch_bounds__(256) void gemm_mf(
    const ushort_t* __restrict__ A0, const ushort_t* __restrict__ A1, const ushort_t* __restrict__ A2,
    const ushort_t* __restrict__ B0, const ushort_t* __restrict__ B1, const ushort_t* __restrict__ B2,
    float* __restrict__ Cf,
    ushort_t* __restrict__ Cb0,
    float alpha) {
  const int K = 1024;
  __shared__ __bf16 As0[64][32];
  __shared__ __bf16 As1[64][32];
  __shared__ __bf16 Bs0[64][32];
  __shared__ __bf16 Bs1[64][32];
  int tid = threadIdx.x;
  int m0 = blockIdx.y * 64, n0 = blockIdx.x * 64;

  int lane = tid & 63, wave = tid >> 6;
  int wrow = wave >> 1, wcol = wave & 1;
  int fr = lane & 15, q = lane >> 4;

  int srow = wave * 16 + (lane >> 2);
  int scg = ((lane & 3) + (srow >> 1)) & 3;
  int scol = scg * 8;
  __bf16* ldsA0 = &As0[wave * 16][0];
  __bf16* ldsA1 = &As1[wave * 16][0];
  __bf16* ldsB0 = &Bs0[wave * 16][0];
  __bf16* ldsB1 = &Bs1[wave * 16][0];

  int rA0 = wrow * 32 + fr, rA1r = rA0 + 16;
  int rB0 = wcol * 32 + fr, rB1r = rB0 + 16;
  int cA0 = ((q - (rA0 >> 1)) & 3) * 8;
  int cA1 = ((q - (rA1r >> 1)) & 3) * 8;
  int cB0 = ((q - (rB0 >> 1)) & 3) * 8;
  int cB1 = ((q - (rB1r >> 1)) & 3) * 8;
  const bf16x8* pa0h0 = (const bf16x8*)&As0[rA0][cA0];
  const bf16x8* pa0h1 = (const bf16x8*)&As1[rA0][cA0];
  const bf16x8* pa1h0 = (const bf16x8*)&As0[rA1r][cA1];
  const bf16x8* pa1h1 = (const bf16x8*)&As1[rA1r][cA1];
  const bf16x8* pb0h0 = (const bf16x8*)&Bs0[rB0][cB0];
  const bf16x8* pb0h1 = (const bf16x8*)&Bs1[rB0][cB0];
  const bf16x8* pb1h0 = (const bf16x8*)&Bs0[rB1r][cB1];
  const bf16x8* pb1h1 = (const bf16x8*)&Bs1[rB1r][cB1];

  f32x4 acc[2][2] = {};

  #pragma unroll 1
  for (int seg = 0; seg < NSEG; seg++) {
    const ushort_t* Aseg = (seg == 0) ? A0 : (seg == 1) ? A1 : A2;
    const ushort_t* Bseg = (seg == 0) ? B0 : (seg == 1) ? B1 : B2;
    const ushort_t* ga = Aseg + (size_t)(m0 + srow) * K + scol;
    const ushort_t* gb = Bseg + (size_t)(n0 + srow) * K + scol;
    #pragma unroll 1
    for (int k0 = 0; k0 < K; k0 += 64) {
      __syncthreads();
      async_cp16(ga + k0, ldsA0);
      async_cp16(ga + k0 + 32, ldsA1);
      async_cp16(gb + k0, ldsB0);
      async_cp16(gb + k0 + 32, ldsB1);
      __syncthreads();
      bf16x8 a00 = *pa0h0, a01 = *pa0h1, a10 = *pa1h0, a11 = *pa1h1;
      bf16x8 b00 = *pb0h0, b01 = *pb0h1, b10 = *pb1h0, b11 = *pb1h1;
      acc[0][0] = __builtin_amdgcn_mfma_f32_16x16x32_bf16(a00, b00, acc[0][0], 0, 0, 0);
      acc[0][1] = __builtin_amdgcn_mfma_f32_16x16x32_bf16(a00, b10, acc[0][1], 0, 0, 0);
      acc[1][0] = __builtin_amdgcn_mfma_f32_16x16x32_bf16(a10, b00, acc[1][0], 0, 0, 0);
      acc[1][1] = __builtin_amdgcn_mfma_f32_16x16x32_bf16(a10, b10, acc[1][1], 0, 0, 0);
      acc[0][0] = __builtin_amdgcn_mfma_f32_16x16x32_bf16(a01, b01, acc[0][0], 0, 0, 0);
      acc[0][1] = __builtin_amdgcn_mfma_f32_16x16x32_bf16(a01, b11, acc[0][1], 0, 0, 0);
      acc[1][0] = __builtin_amdgcn_mfma_f32_16x16x32_bf16(a11, b01, acc[1][0], 0, 0, 0);
      acc[1][1] = __builtin_amdgcn_mfma_f32_16x16x32_bf16(a11, b11, acc[1][1], 0, 0, 0);
    }
  }

  // C/D layout: col = lane&15, row = (lane>>4)*4 + reg
  #pragma unroll
  for (int mi = 0; mi < 2; mi++)
    #pragma unroll
    for (int ni = 0; ni < 2; ni++) {
      int col = n0 + wcol * 32 + ni * 16 + fr;
      int row0 = m0 + wrow * 32 + mi * 16 + q * 4;
      #pragma unroll
      for (int r = 0; r < 4; r++) {
        size_t idx = (size_t)(row0 + r) * E_DIM + col;
        float v = acc[mi][ni][r];
        if (MODE == 3) {
          Cf[idx] = v;
        } else if (MODE == 4) {
          Cf[idx] = v;
          Cb0[idx] = f2bu(v);
        } else if (MODE == 6) {
          float nv = alpha * v;
          Cf[idx] = nv;
          Cb0[idx] = f2bu(nv);
        } else {  // MODE 5
          Cb0[idx] = f2bu(v);
        }
      }
    }
}

// ---------------- merged QKV GEMM: one A-stage feeds 3 B-matrices ----------------
__global__ __launch_bounds__(256) void gemm_qkv(
    const ushort_t* __restrict__ A,
    const ushort_t* __restrict__ B0, const ushort_t* __restrict__ B1, const ushort_t* __restrict__ B2,
    ushort_t* __restrict__ Cb0, ushort_t* __restrict__ Cb1, ushort_t* __restrict__ Cb2,
    ushort_t* __restrict__ Ct0, ushort_t* __restrict__ Ct1, ushort_t* __restrict__ Ct2) {
  const int K = 1024;
  __shared__ __bf16 As[2][64][32];
  __shared__ __bf16 Bs[3][2][64][32];
  int tid = threadIdx.x;
  int m0 = blockIdx.y * 64, n0 = blockIdx.x * 64;

  int lane = tid & 63, wave = tid >> 6;
  int wrow = wave >> 1, wcol = wave & 1;
  int fr = lane & 15, q = lane >> 4;

  int srow = wave * 16 + (lane >> 2);
  int scg = ((lane & 3) + (srow >> 1)) & 3;
  int scol = scg * 8;
  __bf16* ldsA0 = &As[0][wave * 16][0];
  __bf16* ldsA1 = &As[1][wave * 16][0];
  __bf16* ldsB00 = &Bs[0][0][wave * 16][0];
  __bf16* ldsB01 = &Bs[0][1][wave * 16][0];
  __bf16* ldsB10 = &Bs[1][0][wave * 16][0];
  __bf16* ldsB11 = &Bs[1][1][wave * 16][0];
  __bf16* ldsB20 = &Bs[2][0][wave * 16][0];
  __bf16* ldsB21 = &Bs[2][1][wave * 16][0];

  int rA0 = wrow * 32 + fr, rA1r = rA0 + 16;
  int rB0 = wcol * 32 + fr, rB1r = rB0 + 16;
  int cA0 = ((q - (rA0 >> 1)) & 3) * 8;
  int cA1 = ((q - (rA1r >> 1)) & 3) * 8;
  int cB0 = ((q - (rB0 >> 1)) & 3) * 8;
  int cB1 = ((q - (rB1r >> 1)) & 3) * 8;
  const bf16x8* pa0h0 = (const bf16x8*)&As[0][rA0][cA0];
  const bf16x8* pa0h1 = (const bf16x8*)&As[1][rA0][cA0];
  const bf16x8* pa1h0 = (const bf16x8*)&As[0][rA1r][cA1];
  const bf16x8* pa1h1 = (const bf16x8*)&As[1][rA1r][cA1];

  f32x4 acc[3][2][2] = {};

  const ushort_t* ga = A + (size_t)(m0 + srow) * K + scol;
  const ushort_t* gb0 = B0 + (size_t)(n0 + srow) * K + scol;
  const ushort_t* gb1 = B1 + (size_t)(n0 + srow) * K + scol;
  const ushort_t* gb2 = B2 + (size_t)(n0 + srow) * K + scol;

  #pragma unroll 1
  for (int k0 = 0; k0 < K; k0 += 64) {
    __syncthreads();
    async_cp16(ga + k0, ldsA0);
    async_cp16(ga + k0 + 32, ldsA1);
    async_cp16(gb0 + k0, ldsB00);
    async_cp16(gb0 + k0 + 32, ldsB01);
    async_cp16(gb1 + k0, ldsB10);
    async_cp16(gb1 + k0 + 32, ldsB11);
    async_cp16(gb2 + k0, ldsB20);
    async_cp16(gb2 + k0 + 32, ldsB21);
    __syncthreads();
    bf16x8 a00 = *pa0h0, a01 = *pa0h1, a10 = *pa1h0, a11 = *pa1h1;
    #pragma unroll
    for (int z = 0; z < 3; z++) {
      bf16x8 b00 = *(const bf16x8*)&Bs[z][0][rB0][cB0];
      bf16x8 b01 = *(const bf16x8*)&Bs[z][1][rB0][cB0];
      bf16x8 b10 = *(const bf16x8*)&Bs[z][0][rB1r][cB1];
      bf16x8 b11 = *(const bf16x8*)&Bs[z][1][rB1r][cB1];
      acc[z][0][0] = __builtin_amdgcn_mfma_f32_16x16x32_bf16(a00, b00, acc[z][0][0], 0, 0, 0);
      acc[z][0][1] = __builtin_amdgcn_mfma_f32_16x16x32_bf16(a00, b10, acc[z][0][1], 0, 0, 0);
      acc[z][1][0] = __builtin_amdgcn_mfma_f32_16x16x32_bf16(a10, b00, acc[z][1][0], 0, 0, 0);
      acc[z][1][1] = __builtin_amdgcn_mfma_f32_16x16x32_bf16(a10, b10, acc[z][1][1], 0, 0, 0);
      acc[z][0][0] = __builtin_amdgcn_mfma_f32_16x16x32_bf16(a01, b01, acc[z][0][0], 0, 0, 0);
      acc[z][0][1] = __builtin_amdgcn_mfma_f32_16x16x32_bf16(a01, b11, acc[z][0][1], 0, 0, 0);
      acc[z][1][0] = __builtin_amdgcn_mfma_f32_16x16x32_bf16(a11, b01, acc[z][1][0], 0, 0, 0);
      acc[z][1][1] = __builtin_amdgcn_mfma_f32_16x16x32_bf16(a11, b11, acc[z][1][1], 0, 0, 0);
    }
  }

  // C/D layout: col = lane&15, row = (lane>>4)*4 + reg
  #pragma unroll
  for (int z = 0; z < 3; z++) {
    ushort_t* Cbz = (z == 0) ? Cb0 : (z == 1) ? Cb1 : Cb2;
    ushort_t* Ctz = (z == 0) ? Ct0 : (z == 1) ? Ct1 : Ct2;
    float tsc = (z == 2) ? 1.0f : SC_C;   // Qt/Kt carry the 1/sqrt(d) factor
    #pragma unroll
    for (int mi = 0; mi < 2; mi++)
      #pragma unroll
      for (int ni = 0; ni < 2; ni++) {
        int col = n0 + wcol * 32 + ni * 16 + fr;
        int row0 = m0 + wrow * 32 + mi * 16 + q * 4;
        ushort_t pk[4];
        #pragma unroll
        for (int r = 0; r < 4; r++) {
          size_t idx = (size_t)(row0 + r) * E_DIM + col;
          float v = acc[z][mi][ni][r];
          Cbz[idx] = f2bu(v);
          pk[r] = f2bu(v * tsc);
        }
        int hh = col >> 6, dd = col & 63;
        int bb = row0 >> 10, ss = row0 & 1023;
        *(uint2*)(Ctz + ((size_t)((bb * NH + hh) * HD + dd)) * S_LEN + ss) = *(uint2*)pk;
      }
  }
}

// ---------------- merged accumulation GEMM: X2 += alpha * sum_s(As·Bs^T) ----------------
// Replaces gemm_mf<2,3> (48 barrier-drains, 8 MFMA each) with 16 drains of 24 MFMA.
// Per-seg accumulators are kept separate (per-seg k-order identical to before) and
// summed at the C-write — only the final 3-way add order differs (sub-ulp effect).
__global__ __launch_bounds__(256) void gemm_acc(
    const ushort_t* __restrict__ A0, const ushort_t* __restrict__ A1, const ushort_t* __restrict__ A2,
    const ushort_t* __restrict__ B0, const ushort_t* __restrict__ B1, const ushort_t* __restrict__ B2,
    float* __restrict__ Cf, ushort_t* __restrict__ Cb, float alpha) {
  const int K = 1024;
  __shared__ __bf16 As[3][2][64][32];
  __shared__ __bf16 Bs[3][2][64][32];
  int tid = threadIdx.x;
  int m0 = blockIdx.y * 64, n0 = blockIdx.x * 64;

  int lane = tid & 63, wave = tid >> 6;
  int wrow = wave >> 1, wcol = wave & 1;
  int fr = lane & 15, q = lane >> 4;

  int srow = wave * 16 + (lane >> 2);
  int scg = ((lane & 3) + (srow >> 1)) & 3;
  int scol = scg * 8;

  int rA0 = wrow * 32 + fr, rA1r = rA0 + 16;
  int rB0 = wcol * 32 + fr, rB1r = rB0 + 16;
  int cA0 = ((q - (rA0 >> 1)) & 3) * 8;
  int cA1 = ((q - (rA1r >> 1)) & 3) * 8;
  int cB0 = ((q - (rB0 >> 1)) & 3) * 8;
  int cB1 = ((q - (rB1r >> 1)) & 3) * 8;

  f32x4 acc[3][2][2] = {};

  const ushort_t* ga0 = A0 + (size_t)(m0 + srow) * K + scol;
  const ushort_t* ga1 = A1 + (size_t)(m0 + srow) * K + scol;
  const ushort_t* ga2 = A2 + (size_t)(m0 + srow) * K + scol;
  const ushort_t* gb0 = B0 + (size_t)(n0 + srow) * K + scol;
  const ushort_t* gb1 = B1 + (size_t)(n0 + srow) * K + scol;
  const ushort_t* gb2 = B2 + (size_t)(n0 + srow) * K + scol;

  #pragma unroll 1
  for (int k0 = 0; k0 < K; k0 += 64) {
    __syncthreads();
    async_cp16(ga0 + k0,      &As[0][0][wave * 16][0]);
    async_cp16(ga0 + k0 + 32, &As[0][1][wave * 16][0]);
    async_cp16(ga1 + k0,      &As[1][0][wave * 16][0]);
    async_cp16(ga1 + k0 + 32, &As[1][1][wave * 16][0]);
    async_cp16(ga2 + k0,      &As[2][0][wave * 16][0]);
    async_cp16(ga2 + k0 + 32, &As[2][1][wave * 16][0]);
    async_cp16(gb0 + k0,      &Bs[0][0][wave * 16][0]);
    async_cp16(gb0 + k0 + 32, &Bs[0][1][wave * 16][0]);
    async_cp16(gb1 + k0,      &Bs[1][0][wave * 16][0]);
    async_cp16(gb1 + k0 + 32, &Bs[1][1][wave * 16][0]);
    async_cp16(gb2 + k0,      &Bs[2][0][wave * 16][0]);
    async_cp16(gb2 + k0 + 32, &Bs[2][1][wave * 16][0]);
    __syncthreads();
    #pragma unroll
    for (int z = 0; z < 3; z++) {
      bf16x8 a00 = *(const bf16x8*)&As[z][0][rA0][cA0];
      bf16x8 a01 = *(const bf16x8*)&As[z][1][rA0][cA0];
      bf16x8 a10 = *(const bf16x8*)&As[z][0][rA1r][cA1];
      bf16x8 a11 = *(const bf16x8*)&As[z][1][rA1r][cA1];
      bf16x8 b00 = *(const bf16x8*)&Bs[z][0][rB0][cB0];
      bf16x8 b01 = *(const bf16x8*)&Bs[z][1][rB0][cB0];
      bf16x8 b10 = *(const bf16x8*)&Bs[z][0][rB1r][cB1];
      bf16x8 b11 = *(const bf16x8*)&Bs[z][1][rB1r][cB1];
      acc[z][0][0] = __builtin_amdgcn_mfma_f32_16x16x32_bf16(a00, b00, acc[z][0][0], 0, 0, 0);
      acc[z][0][1] = __builtin_amdgcn_mfma_f32_16x16x32_bf16(a00, b10, acc[z][0][1], 0, 0, 0);
      acc[z][1][0] = __builtin_amdgcn_mfma_f32_16x16x32_bf16(a10, b00, acc[z][1][0], 0, 0, 0);
      acc[z][1][1] = __builtin_amdgcn_mfma_f32_16x16x32_bf16(a10, b10, acc[z][1][1], 0, 0, 0);
      acc[z][0][0] = __builtin_amdgcn_mfma_f32_16x16x32_bf16(a01, b01, acc[z][0][0], 0, 0, 0);
      acc[z][0][1] = __builtin_amdgcn_mfma_f32_16x16x32_bf16(a01, b11, acc[z][0][1], 0, 0, 0);
      acc[z][1][0] = __builtin_amdgcn_mfma_f32_16x16x32_bf16(a11, b01, acc[z][1][0], 0, 0, 0);
      acc[z][1][1] = __builtin_amdgcn_mfma_f32_16x16x32_bf16(a11, b11, acc[z][1][1], 0, 0, 0);
    }
  }

  // C/D layout: col = lane&15, row = (lane>>4)*4 + reg
  #pragma unroll
  for (int mi = 0; mi < 2; mi++)
    #pragma unroll
    for (int ni = 0; ni < 2; ni++) {
      int col = n0 + wcol * 32 + ni * 16 + fr;
      int row0 = m0 + wrow * 32 + mi * 16 + q * 4;
      #pragma unroll
      for (int r = 0; r < 4; r++) {
        size_t idx = (size_t)(row0 + r) * E_DIM + col;
        float v = (acc[0][mi][ni][r] + acc[1][mi][ni][r]) + acc[2][mi][ni][r];
        float nv = Cf[idx] + alpha * v;
        Cf[idx] = nv;
        Cb[idx] = f2bu(nv);
      }
    }
}

// ====================== MFMA attention, LDS-staged ======================

// ---- fused fwd: single-pass flash, log2-domain online softmax; emits m' = m + log2(l),
//      g=O-Xs (bf16 + transposed), Dv. grid (bh=32, y=16), balanced pairing.
//      K/V staged via global_load_lds into chunk-rotated LDS. l is tracked as a
//      per-lane 4-column partial (alpha is row-uniform) and reduced ONCE in the
//      epilogue — removes 16 shfl-adds per K/V tile from the serial chain. ----
__global__ __launch_bounds__(256) void fwd_fused(const ushort_t* __restrict__ Qg,
                                                 const ushort_t* __restrict__ Kg,
                                                 const ushort_t* __restrict__ Vt,
                                                 const float* __restrict__ Xs,
                                                 float* __restrict__ mbuf,
                                                 ushort_t* __restrict__ Gb,
                                                 ushort_t* __restrict__ Gt,
                                                 float* __restrict__ Dv) {
  int bh = blockIdx.x, y = blockIdx.y;
  int it = (y < 8) ? (15 - y) : (y - 8);
  int b = bh >> 4, h = bh & 15;
  int tid = threadIdx.x, lane = tid & 63, wv = tid >> 6;
  int fr = lane & 15, q = lane >> 4;
  int i0 = it * 64, band = wv * 16;
  __shared__ ushort_t Ks[4096];     // [j][d] chunk-rotated
  __shared__ ushort_t Vs[4096];     // [d][j] chunk-rotated
  __shared__ ushort_t Ps[64][72];   // [i][j] wave-private bands (lane-written)

  const ushort_t* Kbase = Kg + (size_t)(b * S_LEN) * E_DIM + h * HD;
  const ushort_t* Vbase = Vt + (size_t)(bh * HD) * S_LEN;

  const ushort_t* Qrow = Qg + (size_t)(b * S_LEN + i0 + band + fr) * E_DIM + h * HD;
  bf16x8 aq0 = ldg8(Qrow + q * 8);
  bf16x8 aq1 = ldg8(Qrow + 32 + q * 8);

  float m[4], l[4];
  #pragma unroll
  for (int r = 0; r < 4; r++) { m[r] = -1e30f; l[r] = 0.f; }
  f32x4 oacc[4] = {};

  #pragma unroll 1
  for (int jt = 0; jt <= it; jt++) {
    int j0 = jt * 64;
    __syncthreads();
    stage_tile(Kbase + (size_t)j0 * E_DIM, E_DIM, Ks, lane, wv);
    stage_tile(Vbase + j0, S_LEN, Vs, lane, wv);
    __syncthreads();
    f32x4 sA[4];
    #pragma unroll
    for (int nc = 0; nc < 4; nc++) {
      bf16x8 bk0 = *tile_at(Ks, nc * 16 + fr, q);
      bf16x8 bk1 = *tile_at(Ks, nc * 16 + fr, q + 4);
      f32x4 z = {};
      z = __builtin_amdgcn_mfma_f32_16x16x32_bf16(aq0, bk0, z, 0, 0, 0);
      sA[nc] = __builtin_amdgcn_mfma_f32_16x16x32_bf16(aq1, bk1, z, 0, 0, 0);
    }
    float sv[4][4];
    #pragma unroll
    for (int nc = 0; nc < 4; nc++)
      #pragma unroll
      for (int r = 0; r < 4; r++) {
        int row = i0 + band + q * 4 + r;
        int col = j0 + nc * 16 + fr;
        sv[nc][r] = (col <= row) ? sA[nc][r] * C2_C : -1e30f;  // log2 domain
      }
    #pragma unroll
    for (int r = 0; r < 4; r++) {
      float mx = fmaxf(fmaxf(sv[0][r], sv[1][r]), fmaxf(sv[2][r], sv[3][r]));
      #pragma unroll
      for (int off = 1; off < 16; off <<= 1) mx = fmaxf(mx, __shfl_xor(mx, off, 64));
      float mn = fmaxf(m[r], mx);
      float alpha = exp2f(m[r] - mn);
      float ps = 0.f;
      #pragma unroll
      for (int nc = 0; nc < 4; nc++) {
        float p = exp2f(sv[nc][r] - mn);
        Ps[band + q * 4 + r][nc * 16 + fr] = f2bu(p);
        ps += p;
      }
      l[r] = l[r] * alpha + ps;   // per-lane partial (this lane's 4 columns)
      m[r] = mn;
      #pragma unroll
      for (int nc = 0; nc < 4; nc++) oacc[nc][r] *= alpha;
    }
    bf16x8 ap0 = *(const bf16x8*)&Ps[band + fr][q * 8];
    bf16x8 ap1 = *(const bf16x8*)&Ps[band + fr][32 + q * 8];
    #pragma unroll
    for (int nc = 0; nc < 4; nc++) {
      bf16x8 bv0 = *tile_at(Vs, nc * 16 + fr, q);
      bf16x8 bv1 = *tile_at(Vs, nc * 16 + fr, q + 4);
      oacc[nc] = __builtin_amdgcn_mfma_f32_16x16x32_bf16(ap0, bv0, oacc[nc], 0, 0, 0);
      oacc[nc] = __builtin_amdgcn_mfma_f32_16x16x32_bf16(ap1, bv1, oacc[nc], 0, 0, 0);
    }
  }
  // epilogue: finish the deferred l reduction (alpha chains were row-uniform, so the
  // 16-lane sum of partials equals the old per-tile-reduced l up to association)
  #pragma unroll
  for (int r = 0; r < 4; r++) {
    #pragma unroll
    for (int off = 1; off < 16; off <<= 1) l[r] += __shfl_xor(l[r], off, 64);
  }
  // g = O - Xs (bf16 normal + transposed), Dv partials
  float linv[4];
  #pragma unroll
  for (int r = 0; r < 4; r++) linv[r] = 1.0f / l[r];
  float dpart[4] = {};
  #pragma unroll
  for (int nc = 0; nc < 4; nc++) {
    ushort_t pg[4];
    #pragma unroll
    for (int r = 0; r < 4; r++) {
      int row = i0 + band + q * 4 + r;
      size_t gi = (size_t)(b * S_LEN + row) * E_DIM + h * HD + nc * 16 + fr;
      float o = oacc[nc][r] * linv[r];
      float g = o - Xs[gi];
      ushort_t bu = f2bu(g);
      Gb[gi] = bu;
      pg[r] = bu;
      dpart[r] += g * o;
    }
    int d = nc * 16 + fr;
    int s0 = i0 + band + q * 4;
    *(uint2*)(Gt + ((size_t)bh * HD + d) * S_LEN + s0) = *(uint2*)pg;
  }
  #pragma unroll
  for (int r = 0; r < 4; r++) {
    #pragma unroll
    for (int off = 1; off < 16; off <<= 1) dpart[r] += __shfl_xor(dpart[r], off, 64);
  }
  if (fr == 0) {
    #pragma unroll
    for (int r = 0; r < 4; r++) {
      size_t sid = (size_t)bh * S_LEN + i0 + band + q * 4 + r;
      mbuf[sid] = m[r] + log2f(l[r]);   // m' folds 1/l into the exponent
      Dv[sid] = dpart[r];
    }
  }
}

// ---- merged backward: block (bh, y): dq for i-tile y (y+1 units) then dk/dv for
//      j-tile y (16-y units) = 17 units/block (perfect balance; round-3 showed splitting
//      costs 5.5x HBM). All staged tiles via global_load_lds into chunk-rotated LDS. ----
__global__ __launch_bounds__(256) void bwd_fused(const ushort_t* __restrict__ Qg,
                                                 const ushort_t* __restrict__ Kg,
                                                 const ushort_t* __restrict__ Vg,
                                                 const ushort_t* __restrict__ Gg,
                                                 const ushort_t* __restrict__ Qt,
                                                 const ushort_t* __restrict__ Kt,
                                                 const ushort_t* __restrict__ Gt,
                                                 const float* __restrict__ mbuf,
                                                 const float* __restrict__ Dv,
                                                 ushort_t* __restrict__ GQ,
                                                 ushort_t* __restrict__ GK,
                                                 ushort_t* __restrict__ GV) {
  int bh = blockIdx.x, y = blockIdx.y;
  int b = bh >> 4, h = bh & 15;
  int tid = threadIdx.x, lane = tid & 63, wv = tid >> 6;
  int fr = lane & 15, q = lane >> 4;
  int band = wv * 16;
  __shared__ ushort_t tA[4][4096];    // staged tiles (chunk-rotated, global_load_lds)
  __shared__ ushort_t tP[2][64][72];  // lane-written P/dS (padded)

  // ================= phase A: dq for i-tile y =================
  {
    ushort_t* Ks = tA[0];           // [j][d]
    ushort_t* Vs = tA[1];           // [j][d]
    ushort_t* Ts = tA[2];           // [d][j] Kt (pre-scaled by SC)
    ushort_t (*dSs)[72] = tP[0];
    int it = y, i0 = it * 64;

    const ushort_t* KbaseA = Kg + (size_t)(b * S_LEN) * E_DIM + h * HD;
    const ushort_t* VbaseA = Vg + (size_t)(b * S_LEN) * E_DIM + h * HD;
    const ushort_t* TbaseA = Kt + (size_t)(bh * HD) * S_LEN;

    const ushort_t* Qrow = Qg + (size_t)(b * S_LEN + i0 + band + fr) * E_DIM + h * HD;
    const ushort_t* Grow = Gg + (size_t)(b * S_LEN + i0 + band + fr) * E_DIM + h * HD;
    bf16x8 aq0 = ldg8(Qrow + q * 8), aq1 = ldg8(Qrow + 32 + q * 8);
    bf16x8 ag0 = ldg8(Grow + q * 8), ag1 = ldg8(Grow + 32 + q * 8);

    float mrow[4], Dr[4];
    #pragma unroll
    for (int r = 0; r < 4; r++) {
      size_t sid = (size_t)bh * S_LEN + i0 + band + q * 4 + r;
      mrow[r] = mbuf[sid]; Dr[r] = Dv[sid];
    }
    f32x4 dqacc[4] = {};

    #pragma unroll 1
    for (int jt = 0; jt <= it; jt++) {
      int j0 = jt * 64;
      __syncthreads();
      stage_tile(KbaseA + (size_t)j0 * E_DIM, E_DIM, Ks, lane, wv);
      stage_tile(VbaseA + (size_t)j0 * E_DIM, E_DIM, Vs, lane, wv);
      stage_tile(TbaseA + j0, S_LEN, Ts, lane, wv);
      __syncthreads();
      f32x4 sA[4], dpA[4];
      #pragma unroll
      for (int nc = 0; nc < 4; nc++) {
        bf16x8 bk0 = *tile_at(Ks, nc * 16 + fr, q);
        bf16x8 bk1 = *tile_at(Ks, nc * 16 + fr, q + 4);
        bf16x8 bv0 = *tile_at(Vs, nc * 16 + fr, q);
        bf16x8 bv1 = *tile_at(Vs, nc * 16 + fr, q + 4);
        f32x4 z = {};
        z = __builtin_amdgcn_mfma_f32_16x16x32_bf16(aq0, bk0, z, 0, 0, 0);
        sA[nc] = __builtin_amdgcn_mfma_f32_16x16x32_bf16(aq1, bk1, z, 0, 0, 0);
        f32x4 z2 = {};
        z2 = __builtin_amdgcn_mfma_f32_16x16x32_bf16(ag0, bv0, z2, 0, 0, 0);
        dpA[nc] = __builtin_amdgcn_mfma_f32_16x16x32_bf16(ag1, bv1, z2, 0, 0, 0);
      }
      #pragma unroll
      for (int nc = 0; nc < 4; nc++)
        #pragma unroll
        for (int r = 0; r < 4; r++) {
          int row = i0 + band + q * 4 + r;
          int col = j0 + nc * 16 + fr;
          float ds = 0.f;
          if (col <= row) {
            float P = exp2f(fmaf(sA[nc][r], C2_C, -mrow[r]));
            ds = P * (dpA[nc][r] - Dr[r]);   // SC lives in Kt
          }
          dSs[band + q * 4 + r][nc * 16 + fr] = f2bu(ds);  // wave-private
        }
      bf16x8 ad0 = *(const bf16x8*)&dSs[band + fr][q * 8];
      bf16x8 ad1 = *(const bf16x8*)&dSs[band + fr][32 + q * 8];
      #pragma unroll
      for (int nc = 0; nc < 4; nc++) {
        bf16x8 bt0 = *tile_at(Ts, nc * 16 + fr, q);
        bf16x8 bt1 = *tile_at(Ts, nc * 16 + fr, q + 4);
        dqacc[nc] = __builtin_amdgcn_mfma_f32_16x16x32_bf16(ad0, bt0, dqacc[nc], 0, 0, 0);
        dqacc[nc] = __builtin_amdgcn_mfma_f32_16x16x32_bf16(ad1, bt1, dqacc[nc], 0, 0, 0);
      }
    }
    #pragma unroll
    for (int nc = 0; nc < 4; nc++)
      #pragma unroll
      for (int r = 0; r < 4; r++) {
        int row = i0 + band + q * 4 + r;
        size_t gi = (size_t)(b * S_LEN + row) * E_DIM + h * HD + nc * 16 + fr;
        GQ[gi] = f2bu(dqacc[nc][r]);
      }
  }

  // ================= phase B: dk/dv for j-tile y =================
  {
    ushort_t* Qs  = tA[0];          // [i][d]
    ushort_t* Gs  = tA[1];          // [i][d]
    ushort_t* Qts = tA[2];          // [d][i] (pre-scaled by SC)
    ushort_t* Gts = tA[3];          // [d][i]
    ushort_t (*PT)[72]  = tP[0];    // [j][i]
    ushort_t (*dST)[72] = tP[1];    // [j][i]
    int jt = y, j0 = jt * 64;

    const ushort_t* QbaseB = Qg + (size_t)(b * S_LEN) * E_DIM + h * HD;
    const ushort_t* GbaseB = Gg + (size_t)(b * S_LEN) * E_DIM + h * HD;
    const ushort_t* QtbaseB = Qt + (size_t)(bh * HD) * S_LEN;
    const ushort_t* GtbaseB = Gt + (size_t)(bh * HD) * S_LEN;

    const ushort_t* Krow = Kg + (size_t)(b * S_LEN + j0 + band + fr) * E_DIM + h * HD;
    const ushort_t* Vrow = Vg + (size_t)(b * S_LEN + j0 + band + fr) * E_DIM + h * HD;
    bf16x8 ak0 = ldg8(Krow + q * 8), ak1 = ldg8(Krow + 32 + q * 8);
    bf16x8 av0 = ldg8(Vrow + q * 8), av1 = ldg8(Vrow + 32 + q * 8);

    f32x4 dkacc[4] = {}, dvacc[4] = {};

    #pragma unroll 1
    for (int i_t = jt; i_t < 16; i_t++) {
      int i0 = i_t * 64;
      __syncthreads();
      stage_tile(QbaseB + (size_t)i0 * E_DIM, E_DIM, Qs, lane, wv);
      stage_tile(GbaseB + (size_t)i0 * E_DIM, E_DIM, Gs, lane, wv);
      stage_tile(QtbaseB + i0, S_LEN, Qts, lane, wv);
      stage_tile(GtbaseB + i0, S_LEN, Gts, lane, wv);
      __syncthreads();
      float mc[4], Dc[4];
      #pragma unroll
      for (int nc = 0; nc < 4; nc++) {
        size_t sid = (size_t)bh * S_LEN + i0 + nc * 16 + fr;
        mc[nc] = mbuf[sid]; Dc[nc] = Dv[sid];
      }
      f32x4 stA[4], dptA[4];
      #pragma unroll
      for (int nc = 0; nc < 4; nc++) {
        bf16x8 bq0 = *tile_at(Qs, nc * 16 + fr, q);
        bf16x8 bq1 = *tile_at(Qs, nc * 16 + fr, q + 4);
        bf16x8 bg0 = *tile_at(Gs, nc * 16 + fr, q);
        bf16x8 bg1 = *tile_at(Gs, nc * 16 + fr, q + 4);
        f32x4 z = {};
        z = __builtin_amdgcn_mfma_f32_16x16x32_bf16(ak0, bq0, z, 0, 0, 0);
        stA[nc] = __builtin_amdgcn_mfma_f32_16x16x32_bf16(ak1, bq1, z, 0, 0, 0);
        f32x4 z2 = {};
        z2 = __builtin_amdgcn_mfma_f32_16x16x32_bf16(av0, bg0, z2, 0, 0, 0);
        dptA[nc] = __builtin_amdgcn_mfma_f32_16x16x32_bf16(av1, bg1, z2, 0, 0, 0);
      }
      #pragma unroll
      for (int nc = 0; nc < 4; nc++)
        #pragma unroll
        for (int r = 0; r < 4; r++) {
          int jrow = j0 + band + q * 4 + r;
          int icol = i0 + nc * 16 + fr;
          float P = 0.f, ds = 0.f;
          if (icol >= jrow) {
            P = exp2f(fmaf(stA[nc][r], C2_C, -mc[nc]));
            ds = P * (dptA[nc][r] - Dc[nc]);   // SC lives in Qt
          }
          PT[band + q * 4 + r][nc * 16 + fr] = f2bu(P);   // wave-private
          dST[band + q * 4 + r][nc * 16 + fr] = f2bu(ds);
        }
      bf16x8 ap0 = *(const bf16x8*)&PT[band + fr][q * 8];
      bf16x8 ap1 = *(const bf16x8*)&PT[band + fr][32 + q * 8];
      bf16x8 ad0 = *(const bf16x8*)&dST[band + fr][q * 8];
      bf16x8 ad1 = *(const bf16x8*)&dST[band + fr][32 + q * 8];
      #pragma unroll
      for (int nc = 0; nc < 4; nc++) {
        bf16x8 bg0 = *tile_at(Gts, nc * 16 + fr, q);
        bf16x8 bg1 = *tile_at(Gts, nc * 16 + fr, q + 4);
        bf16x8 bq0 = *tile_at(Qts, nc * 16 + fr, q);
        bf16x8 bq1 = *tile_at(Qts, nc * 16 + fr, q + 4);
        dvacc[nc] = __builtin_amdgcn_mfma_f32_16x16x32_bf16(ap0, bg0, dvacc[nc], 0, 0, 0);
        dvacc[nc] = __builtin_amdgcn_mfma_f32_16x16x32_bf16(ap1, bg1, dvacc[nc], 0, 0, 0);
        dkacc[nc] = __builtin_amdgcn_mfma_f32_16x16x32_bf16(ad0, bq0, dkacc[nc], 0, 0, 0);
        dkacc[nc] = __builtin_amdgcn_mfma_f32_16x16x32_bf16(ad1, bq1, dkacc[nc], 0, 0, 0);
      }
    }
    #pragma unroll
    for (int nc = 0; nc < 4; nc++)
      #pragma unroll
      for (int r = 0; r < 4; r++) {
        int jrow = j0 + band + q * 4 + r;
        size_t gi = (size_t)(b * S_LEN + jrow) * E_DIM + h * HD + nc * 16 + fr;
        GK[gi] = f2bu(dkacc[nc][r]);
        GV[gi] = f2bu(dvacc[nc][r]);
      }
  }
}

// ---------------- launch ----------------
extern "C" void kernel_launch(void* const* d_in, const int* in_sizes, int n_in,
                              void* d_out, int out_size, void* d_ws, size_t ws_size,
                              hipStream_t stream) {
  const float* T1 = (const float*)d_in[0];
  const float* Wq = (const float*)d_in[1];
  const float* Wk = (const float*)d_in[2];
  const float* Wv = (const float*)d_in[3];
  const float* Wo = (const float*)d_in[4];

  const size_t M2 = 2097152;   // 2048*1024
  const size_t M1 = 1048576;
  float* w = (float*)d_ws;
  float* Xs = w;                       // 8 MB fp32 target
  float* mS = Xs + M2;                 // 64K f32 (stores m')
  float* DvS = mS + 65536;
  ushort_t* u = (ushort_t*)(DvS + 65536);
  ushort_t* W0 = u;          ushort_t* W1 = W0 + M1;  ushort_t* W2 = W1 + M1;
  ushort_t* W3 = W2 + M1;    ushort_t* W4 = W3 + M1;  ushort_t* W5 = W4 + M1;
  ushort_t* Qb = W5 + M1;    ushort_t* Kb = Qb + M2;  ushort_t* Vb = Kb + M2;
  ushort_t* Qt = Vb + M2;    ushort_t* Kt = Qt + M2;  ushort_t* Vt = Kt + M2;
  ushort_t* Gt = Vt + M2;
  ushort_t* Gb = Gt + M2;
  ushort_t* GQb = Gb + M2;   ushort_t* GKb = GQb + M2; ushort_t* GVb = GKb + M2;
  ushort_t* X2b = GVb + M2;
  float* X2 = (float*)d_out;

  // stage-1 aliases (all overwritten before stage-2 uses the slots)
  float* Mf  = (float*)Qb;       // 4 MB
  float* M2f = (float*)Kb;       // 4 MB
  ushort_t* Mb  = Gt;            // 2 MB
  ushort_t* Nb  = Vb;            // 2 MB
  ushort_t* AtB = Qt;            // 2 MB
  ushort_t* T1b = Kt;            // 4 MB

  // iter-1 shortcut aliases (dead before their regions' stage-2 consumers)
  float* Sf  = (float*)GQb;      // 8 MB fp32 scan partials (spans GQb+GKb)
  float* tot = mS;               // 128 KB chunk totals (mS rewritten by fwd of iter 2)
  ushort_t* Sb = GVb;            // 4 MB bf16 scan result

  dim3 pgrid(16, 16);
  dim3 sgrid(16, 16);       // 1024x1024 GEMMs
  dim3 ggrid(16, 32);       // 2048x1024 GEMMs
  dim3 agrid(BH_CNT, 16);   // attention

  // ---- stage 1 (algebraic): Xs = T * Wo * (3LR·I - 3LR²·M + LR³·M²),  M = WoᵀWo ----
  k_cast<<<(M2 / 4 + 255) / 256, 256, 0, stream>>>(T1, T1b, (int)(M2 / 4));
  prep_w<<<pgrid, 256, 0, stream>>>(Wo, W0, W1);
  // M = W1·W1ᵀ  (fp32 + bf16)
  gemm_mf<4, 1><<<sgrid, 256, 0, stream>>>(W1, nullptr, nullptr, W1, nullptr, nullptr,
                                           Mf, Mb, 0.f);
  // M2 = Mb·Mbᵀ (M symmetric)
  gemm_mf<3, 1><<<sgrid, 256, 0, stream>>>(Mb, nullptr, nullptr, Mb, nullptr, nullptr,
                                           M2f, nullptr, 0.f);
  k_formN<<<(M1 + 255) / 256, 256, 0, stream>>>(Mf, M2f, Nb);
  // AtB = N·Woᵀ  (symmetric N; this is (Wo·N)ᵀ in [N,K] form)
  gemm_mf<5, 1><<<sgrid, 256, 0, stream>>>(Nb, nullptr, nullptr, W0, nullptr, nullptr,
                                           nullptr, AtB, 0.f);
  // stage-2 weights (W0/W1 free after AtB)
  prep_w<<<pgrid, 256, 0, stream>>>(Wq, W0, W3);
  prep_w<<<pgrid, 256, 0, stream>>>(Wk, W1, W4);
  prep_w<<<pgrid, 256, 0, stream>>>(Wv, W2, W5);
  // Xs = T1b·AtBᵀ (fp32)
  gemm_mf<3, 1><<<ggrid, 256, 0, stream>>>(T1b, nullptr, nullptr, AtB, nullptr, nullptr,
                                           Xs, nullptr, 0.f);

  // ---- stage 2, iteration 1 (closed form): x=0 => Q=K=V=0, P exactly causal-uniform,
  //      dQ=dK=0, dV = P0^T(-Xs); x1 = LR * (P0^T Xs) * Wv via fp32 suffix scan + one GEMM ----
  k_scan1<<<dim3(E_DIM / 256, 2, 16), 256, 0, stream>>>(Xs, Sf, tot);
  k_scan2<<<dim3(E_DIM / 256, 2, 16), 256, 0, stream>>>(Sf, tot, Sb);
  gemm_mf<6, 1><<<ggrid, 256, 0, stream>>>(Sb, nullptr, nullptr, W5, nullptr, nullptr,
                                           X2, X2b, LR_C);

  // ---- stage 2, iterations 2..3 (full PC gradient) ----
  for (int t = 1; t < 3; t++) {
    gemm_qkv<<<ggrid, 256, 0, stream>>>(X2b, W0, W1, W2,
                                        Qb, Kb, Vb, Qt, Kt, Vt);
    fwd_fused<<<agrid, 256, 0, stream>>>(Qb, Kb, Vt, Xs, mS, Gb, Gt, DvS);
    bwd_fused<<<agrid, 256, 0, stream>>>(Qb, Kb, Vb, Gb, Qt, Kt, Gt, mS, DvS,
                                         GQb, GKb, GVb);
    gemm_acc<<<ggrid, 256, 0, stream>>>(GQb, GKb, GVb, W3, W4, W5,
                                        X2, X2b, -LR_C);
  }
}

// Round 9
// 426.749 us; speedup vs baseline: 1.0447x; 1.0063x over previous
//
#include <hip/hip_runtime.h>
#include <hip/hip_bf16.h>
#include <math.h>

// Problem constants (B=2, S=1024, E=1024, H=16, D=64)
#define S_LEN 1024
#define E_DIM 1024
#define NH 16
#define HD 64
#define M_ROWS 2048   // B*S
#define BH_CNT 32     // B*NH

static constexpr float LR_C = 0.01f;
static constexpr float SC_C = 0.125f;                // 1/sqrt(64)
static constexpr float C2_C = 0.125f * 1.44269504f;  // SC * log2(e): log2-domain softmax

typedef unsigned short ushort_t;
typedef __attribute__((ext_vector_type(8))) __bf16 bf16x8;
typedef __attribute__((ext_vector_type(4))) float f32x4;

static __device__ inline ushort_t f2bu(float f) {
  __hip_bfloat16 h = __float2bfloat16(f);
  return *(ushort_t*)&h;
}
static __device__ inline bf16x8 ldg8(const ushort_t* p) { return *(const bf16x8*)p; }

// async global->LDS, 16B per lane; LDS dest = wave-uniform base + lane*16
static __device__ inline void async_cp16(const ushort_t* g, __bf16* lds_wave_base) {
  __builtin_amdgcn_global_load_lds((const __attribute__((address_space(1))) void*)g,
                                   (__attribute__((address_space(3))) void*)lds_wave_base,
                                   16, 0, 0);
}

// ---- 64x64 bf16 tile in unpadded LDS with per-row chunk rotation ----
// element (r,c) lives at ushort offset r*64 + (((c>>3)+r)&7)*8 + (c&7).
// Staged via global_load_lds: wave w, issue t fills slab s=w*2+t (rows 8s..8s+7, 1 KB,
// wave-uniform dest); lane l supplies source chunk c=((l&7)-(l>>3))&7 of row 8s+(l>>3)
// (pre-rotated SOURCE address = m173's swizzle-the-global-side pattern).
// b128 fragment reads hit bank-quad (chunk+row)&7 — same distribution as the old +8 pad.
static __device__ inline void stage_tile(const ushort_t* src, size_t src_stride,
                                         ushort_t* lds, int lane, int wave) {
  int rl = lane >> 3;
  int c = ((lane & 7) - rl) & 7;
  #pragma unroll
  for (int t = 0; t < 2; t++) {
    int s = wave * 2 + t;
    async_cp16(src + (size_t)(s * 8 + rl) * src_stride + c * 8,
               (__bf16*)(lds + s * 512));
  }
}
static __device__ inline const bf16x8* tile_at(const ushort_t* lds, int r, int cchunk) {
  return (const bf16x8*)(lds + r * 64 + (((cchunk + r) & 7) * 8));
}

// ---------------- weight prep: bf16 cast + bf16 transpose, 64x64 tiles ----------------
__global__ __launch_bounds__(256) void prep_w(const float* __restrict__ W,
                                              ushort_t* __restrict__ Wb,
                                              ushort_t* __restrict__ WTb) {
  __shared__ float ts[64][65];
  int bx = blockIdx.x * 64, by = blockIdx.y * 64;
  int t = threadIdx.x;
  int rr = t >> 6, cc = t & 63;
  #pragma unroll
  for (int p = 0; p < 16; p++) {
    int r = p * 4 + rr;
    float v = W[(size_t)(by + r) * E_DIM + bx + cc];
    ts[r][cc] = v;
    Wb[(size_t)(by + r) * E_DIM + bx + cc] = f2bu(v);
  }
  __syncthreads();
  #pragma unroll
  for (int p = 0; p < 16; p++) {
    int r = p * 4 + rr;
    WTb[(size_t)(bx + r) * E_DIM + by + cc] = f2bu(ts[cc][r]);
  }
}

// ---------------- fp32 -> bf16 cast (float4-wide) ----------------
__global__ __launch_bounds__(256) void k_cast(const float* __restrict__ in,
                                              ushort_t* __restrict__ out, int n4) {
  int i = blockIdx.x * 256 + threadIdx.x;
  if (i < n4) {
    float4 v = ((const float4*)in)[i];
    ushort_t p[4] = {f2bu(v.x), f2bu(v.y), f2bu(v.z), f2bu(v.w)};
    *(uint2*)(out + (size_t)i * 4) = *(uint2*)p;
  }
}

// ---------------- N = 3LR*I - 3LR^2*M + LR^3*M2  (bf16 out) ----------------
__global__ __launch_bounds__(256) void k_formN(const float* __restrict__ Mf,
                                               const float* __restrict__ M2f,
                                               ushort_t* __restrict__ Nb) {
  int idx = blockIdx.x * 256 + threadIdx.x;   // 1M elements
  int i = idx >> 10, j = idx & 1023;
  float v = -3.f * LR_C * LR_C * Mf[idx] + LR_C * LR_C * LR_C * M2f[idx];
  if (i == j) v += 3.f * LR_C;
  Nb[idx] = f2bu(v);
}

// ---------------- iter-1 shortcut: suffix scan S[j] = sum_{i>=j} Xs[i]/(i+1) ----------------
// x=0 => Q=K=V=0 => P is exactly causal-uniform, dQ=dK=0, dV = P0^T(-Xs).
// x1 = LR * (P0^T Xs) * Wv. Two-pass chunked scan over the sequence dim.
__global__ __launch_bounds__(256) void k_scan1(const float* __restrict__ Xs,
                                               float* __restrict__ Sf,
                                               float* __restrict__ tot) {
  int e = blockIdx.x * 256 + threadIdx.x;  // column 0..1023
  int b = blockIdx.y;                      // batch
  int z = blockIdx.z;                      // chunk 0..15 (64 rows each)
  float acc = 0.f;
  for (int i = z * 64 + 63; i >= z * 64; i--) {
    size_t idx = ((size_t)b * S_LEN + i) * E_DIM + e;
    acc = fmaf(Xs[idx], 1.0f / (float)(i + 1), acc);
    Sf[idx] = acc;
  }
  tot[((size_t)b * 16 + z) * E_DIM + e] = acc;
}

__global__ __launch_bounds__(256) void k_scan2(const float* __restrict__ Sf,
                                               const float* __restrict__ tot,
                                               ushort_t* __restrict__ Sb) {
  int e = blockIdx.x * 256 + threadIdx.x;
  int b = blockIdx.y;
  int z = blockIdx.z;
  float off = 0.f;
  for (int c = z + 1; c < 16; c++) off += tot[((size_t)b * 16 + c) * E_DIM + e];
  for (int i = z * 64; i < z * 64 + 64; i++) {
    size_t idx = ((size_t)b * S_LEN + i) * E_DIM + e;
    Sb[idx] = f2bu(Sf[idx] + off);
  }
}

// ---------------- bf16 MFMA GEMM, 64x64 tile, BK=64, ASYNC global_load_lds staging ----------
// Four 4KB half-buffers (16KB LDS); 16 barrier-drains per K=1024.
// k-halves accumulated h0 then h1 = identical order to BK=32 -> bit-identical results.
// MODE 3: Cf = acc (fp32 only)
// MODE 4: Cf = acc and Cb0 = bf16(acc)
// MODE 5: Cb0 = bf16(acc)
// MODE 6: Cf = alpha*acc (overwrite) and Cb0 = bf16(alpha*acc)
template <int MODE, int NSEG>
__global__ __launch_bounds__(256) void gemm_mf(
    const ushort_t* __restrict__ A0, const ushort_t* __restrict__ A1, const ushort_t* __restrict__ A2,
    const ushort_t* __restrict__ B0, const ushort_t* __restrict__ B1, const ushort_t* __restrict__ B2,
    float* __restrict__ Cf,
    ushort_t* __restrict__ Cb0,
    float alpha) {
  const int K = 1024;
  __shared__ __bf16 As0[64][32];
  __shared__ __bf16 As1[64][32];
  __shared__ __bf16 Bs0[64][32];
  __shared__ __bf16 Bs1[64][32];
  int tid = threadIdx.x;
  int m0 = blockIdx.y * 64, n0 = blockIdx.x * 64;

  int lane = tid & 63, wave = tid >> 6;
  int wrow = wave >> 1, wcol = wave & 1;
  int fr = lane & 15, q = lane >> 4;

  int srow = wave * 16 + (lane >> 2);
  int scg = ((lane & 3) + (srow >> 1)) & 3;
  int scol = scg * 8;
  __bf16* ldsA0 = &As0[wave * 16][0];
  __bf16* ldsA1 = &As1[wave * 16][0];
  __bf16* ldsB0 = &Bs0[wave * 16][0];
  __bf16* ldsB1 = &Bs1[wave * 16][0];

  int rA0 = wrow * 32 + fr, rA1r = rA0 + 16;
  int rB0 = wcol * 32 + fr, rB1r = rB0 + 16;
  int cA0 = ((q - (rA0 >> 1)) & 3) * 8;
  int cA1 = ((q - (rA1r >> 1)) & 3) * 8;
  int cB0 = ((q - (rB0 >> 1)) & 3) * 8;
  int cB1 = ((q - (rB1r >> 1)) & 3) * 8;
  const bf16x8* pa0h0 = (const bf16x8*)&As0[rA0][cA0];
  const bf16x8* pa0h1 = (const bf16x8*)&As1[rA0][cA0];
  const bf16x8* pa1h0 = (const bf16x8*)&As0[rA1r][cA1];
  const bf16x8* pa1h1 = (const bf16x8*)&As1[rA1r][cA1];
  const bf16x8* pb0h0 = (const bf16x8*)&Bs0[rB0][cB0];
  const bf16x8* pb0h1 = (const bf16x8*)&Bs1[rB0][cB0];
  const bf16x8* pb1h0 = (const bf16x8*)&Bs0[rB1r][cB1];
  const bf16x8* pb1h1 = (const bf16x8*)&Bs1[rB1r][cB1];

  f32x4 acc[2][2] = {};

  #pragma unroll 1
  for (int seg = 0; seg < NSEG; seg++) {
    const ushort_t* Aseg = (seg == 0) ? A0 : (seg == 1) ? A1 : A2;
    const ushort_t* Bseg = (seg == 0) ? B0 : (seg == 1) ? B1 : B2;
    const ushort_t* ga = Aseg + (size_t)(m0 + srow) * K + scol;
    const ushort_t* gb = Bseg + (size_t)(n0 + srow) * K + scol;
    #pragma unroll 1
    for (int k0 = 0; k0 < K; k0 += 64) {
      __syncthreads();
      async_cp16(ga + k0, ldsA0);
      async_cp16(ga + k0 + 32, ldsA1);
      async_cp16(gb + k0, ldsB0);
      async_cp16(gb + k0 + 32, ldsB1);
      __syncthreads();
      bf16x8 a00 = *pa0h0, a01 = *pa0h1, a10 = *pa1h0, a11 = *pa1h1;
      bf16x8 b00 = *pb0h0, b01 = *pb0h1, b10 = *pb1h0, b11 = *pb1h1;
      acc[0][0] = __builtin_amdgcn_mfma_f32_16x16x32_bf16(a00, b00, acc[0][0], 0, 0, 0);
      acc[0][1] = __builtin_amdgcn_mfma_f32_16x16x32_bf16(a00, b10, acc[0][1], 0, 0, 0);
      acc[1][0] = __builtin_amdgcn_mfma_f32_16x16x32_bf16(a10, b00, acc[1][0], 0, 0, 0);
      acc[1][1] = __builtin_amdgcn_mfma_f32_16x16x32_bf16(a10, b10, acc[1][1], 0, 0, 0);
      acc[0][0] = __builtin_amdgcn_mfma_f32_16x16x32_bf16(a01, b01, acc[0][0], 0, 0, 0);
      acc[0][1] = __builtin_amdgcn_mfma_f32_16x16x32_bf16(a01, b11, acc[0][1], 0, 0, 0);
      acc[1][0] = __builtin_amdgcn_mfma_f32_16x16x32_bf16(a11, b01, acc[1][0], 0, 0, 0);
      acc[1][1] = __builtin_amdgcn_mfma_f32_16x16x32_bf16(a11, b11, acc[1][1], 0, 0, 0);
    }
  }

  // C/D layout: col = lane&15, row = (lane>>4)*4 + reg
  #pragma unroll
  for (int mi = 0; mi < 2; mi++)
    #pragma unroll
    for (int ni = 0; ni < 2; ni++) {
      int col = n0 + wcol * 32 + ni * 16 + fr;
      int row0 = m0 + wrow * 32 + mi * 16 + q * 4;
      #pragma unroll
      for (int r = 0; r < 4; r++) {
        size_t idx = (size_t)(row0 + r) * E_DIM + col;
        float v = acc[mi][ni][r];
        if (MODE == 3) {
          Cf[idx] = v;
        } else if (MODE == 4) {
          Cf[idx] = v;
          Cb0[idx] = f2bu(v);
        } else if (MODE == 6) {
          float nv = alpha * v;
          Cf[idx] = nv;
          Cb0[idx] = f2bu(nv);
        } else {  // MODE 5
          Cb0[idx] = f2bu(v);
        }
      }
    }
}

// ---------------- merged QKV GEMM: one A-stage feeds 3 B-matrices ----------------
__global__ __launch_bounds__(256) void gemm_qkv(
    const ushort_t* __restrict__ A,
    const ushort_t* __restrict__ B0, const ushort_t* __restrict__ B1, const ushort_t* __restrict__ B2,
    ushort_t* __restrict__ Cb0, ushort_t* __restrict__ Cb1, ushort_t* __restrict__ Cb2,
    ushort_t* __restrict__ Ct0, ushort_t* __restrict__ Ct1, ushort_t* __restrict__ Ct2) {
  const int K = 1024;
  __shared__ __bf16 As[2][64][32];
  __shared__ __bf16 Bs[3][2][64][32];
  int tid = threadIdx.x;
  int m0 = blockIdx.y * 64, n0 = blockIdx.x * 64;

  int lane = tid & 63, wave = tid >> 6;
  int wrow = wave >> 1, wcol = wave & 1;
  int fr = lane & 15, q = lane >> 4;

  int srow = wave * 16 + (lane >> 2);
  int scg = ((lane & 3) + (srow >> 1)) & 3;
  int scol = scg * 8;
  __bf16* ldsA0 = &As[0][wave * 16][0];
  __bf16* ldsA1 = &As[1][wave * 16][0];
  __bf16* ldsB00 = &Bs[0][0][wave * 16][0];
  __bf16* ldsB01 = &Bs[0][1][wave * 16][0];
  __bf16* ldsB10 = &Bs[1][0][wave * 16][0];
  __bf16* ldsB11 = &Bs[1][1][wave * 16][0];
  __bf16* ldsB20 = &Bs[2][0][wave * 16][0];
  __bf16* ldsB21 = &Bs[2][1][wave * 16][0];

  int rA0 = wrow * 32 + fr, rA1r = rA0 + 16;
  int rB0 = wcol * 32 + fr, rB1r = rB0 + 16;
  int cA0 = ((q - (rA0 >> 1)) & 3) * 8;
  int cA1 = ((q - (rA1r >> 1)) & 3) * 8;
  int cB0 = ((q - (rB0 >> 1)) & 3) * 8;
  int cB1 = ((q - (rB1r >> 1)) & 3) * 8;
  const bf16x8* pa0h0 = (const bf16x8*)&As[0][rA0][cA0];
  const bf16x8* pa0h1 = (const bf16x8*)&As[1][rA0][cA0];
  const bf16x8* pa1h0 = (const bf16x8*)&As[0][rA1r][cA1];
  const bf16x8* pa1h1 = (const bf16x8*)&As[1][rA1r][cA1];

  f32x4 acc[3][2][2] = {};

  const ushort_t* ga = A + (size_t)(m0 + srow) * K + scol;
  const ushort_t* gb0 = B0 + (size_t)(n0 + srow) * K + scol;
  const ushort_t* gb1 = B1 + (size_t)(n0 + srow) * K + scol;
  const ushort_t* gb2 = B2 + (size_t)(n0 + srow) * K + scol;

  #pragma unroll 1
  for (int k0 = 0; k0 < K; k0 += 64) {
    __syncthreads();
    async_cp16(ga + k0, ldsA0);
    async_cp16(ga + k0 + 32, ldsA1);
    async_cp16(gb0 + k0, ldsB00);
    async_cp16(gb0 + k0 + 32, ldsB01);
    async_cp16(gb1 + k0, ldsB10);
    async_cp16(gb1 + k0 + 32, ldsB11);
    async_cp16(gb2 + k0, ldsB20);
    async_cp16(gb2 + k0 + 32, ldsB21);
    __syncthreads();
    bf16x8 a00 = *pa0h0, a01 = *pa0h1, a10 = *pa1h0, a11 = *pa1h1;
    #pragma unroll
    for (int z = 0; z < 3; z++) {
      bf16x8 b00 = *(const bf16x8*)&Bs[z][0][rB0][cB0];
      bf16x8 b01 = *(const bf16x8*)&Bs[z][1][rB0][cB0];
      bf16x8 b10 = *(const bf16x8*)&Bs[z][0][rB1r][cB1];
      bf16x8 b11 = *(const bf16x8*)&Bs[z][1][rB1r][cB1];
      acc[z][0][0] = __builtin_amdgcn_mfma_f32_16x16x32_bf16(a00, b00, acc[z][0][0], 0, 0, 0);
      acc[z][0][1] = __builtin_amdgcn_mfma_f32_16x16x32_bf16(a00, b10, acc[z][0][1], 0, 0, 0);
      acc[z][1][0] = __builtin_amdgcn_mfma_f32_16x16x32_bf16(a10, b00, acc[z][1][0], 0, 0, 0);
      acc[z][1][1] = __builtin_amdgcn_mfma_f32_16x16x32_bf16(a10, b10, acc[z][1][1], 0, 0, 0);
      acc[z][0][0] = __builtin_amdgcn_mfma_f32_16x16x32_bf16(a01, b01, acc[z][0][0], 0, 0, 0);
      acc[z][0][1] = __builtin_amdgcn_mfma_f32_16x16x32_bf16(a01, b11, acc[z][0][1], 0, 0, 0);
      acc[z][1][0] = __builtin_amdgcn_mfma_f32_16x16x32_bf16(a11, b01, acc[z][1][0], 0, 0, 0);
      acc[z][1][1] = __builtin_amdgcn_mfma_f32_16x16x32_bf16(a11, b11, acc[z][1][1], 0, 0, 0);
    }
  }

  // C/D layout: col = lane&15, row = (lane>>4)*4 + reg
  #pragma unroll
  for (int z = 0; z < 3; z++) {
    ushort_t* Cbz = (z == 0) ? Cb0 : (z == 1) ? Cb1 : Cb2;
    ushort_t* Ctz = (z == 0) ? Ct0 : (z == 1) ? Ct1 : Ct2;
    float tsc = (z == 2) ? 1.0f : SC_C;   // Qt/Kt carry the 1/sqrt(d) factor
    #pragma unroll
    for (int mi = 0; mi < 2; mi++)
      #pragma unroll
      for (int ni = 0; ni < 2; ni++) {
        int col = n0 + wcol * 32 + ni * 16 + fr;
        int row0 = m0 + wrow * 32 + mi * 16 + q * 4;
        ushort_t pk[4];
        #pragma unroll
        for (int r = 0; r < 4; r++) {
          size_t idx = (size_t)(row0 + r) * E_DIM + col;
          float v = acc[z][mi][ni][r];
          Cbz[idx] = f2bu(v);
          pk[r] = f2bu(v * tsc);
        }
        int hh = col >> 6, dd = col & 63;
        int bb = row0 >> 10, ss = row0 & 1023;
        *(uint2*)(Ctz + ((size_t)((bb * NH + hh) * HD + dd)) * S_LEN + ss) = *(uint2*)pk;
      }
  }
}

// ---------------- merged accumulation GEMM: X2 += alpha * sum_s(As·Bs^T) ----------------
__global__ __launch_bounds__(256) void gemm_acc(
    const ushort_t* __restrict__ A0, const ushort_t* __restrict__ A1, const ushort_t* __restrict__ A2,
    const ushort_t* __restrict__ B0, const ushort_t* __restrict__ B1, const ushort_t* __restrict__ B2,
    float* __restrict__ Cf, ushort_t* __restrict__ Cb, float alpha) {
  const int K = 1024;
  __shared__ __bf16 As[3][2][64][32];
  __shared__ __bf16 Bs[3][2][64][32];
  int tid = threadIdx.x;
  int m0 = blockIdx.y * 64, n0 = blockIdx.x * 64;

  int lane = tid & 63, wave = tid >> 6;
  int wrow = wave >> 1, wcol = wave & 1;
  int fr = lane & 15, q = lane >> 4;

  int srow = wave * 16 + (lane >> 2);
  int scg = ((lane & 3) + (srow >> 1)) & 3;
  int scol = scg * 8;

  int rA0 = wrow * 32 + fr, rA1r = rA0 + 16;
  int rB0 = wcol * 32 + fr, rB1r = rB0 + 16;
  int cA0 = ((q - (rA0 >> 1)) & 3) * 8;
  int cA1 = ((q - (rA1r >> 1)) & 3) * 8;
  int cB0 = ((q - (rB0 >> 1)) & 3) * 8;
  int cB1 = ((q - (rB1r >> 1)) & 3) * 8;

  f32x4 acc[3][2][2] = {};

  const ushort_t* ga0 = A0 + (size_t)(m0 + srow) * K + scol;
  const ushort_t* ga1 = A1 + (size_t)(m0 + srow) * K + scol;
  const ushort_t* ga2 = A2 + (size_t)(m0 + srow) * K + scol;
  const ushort_t* gb0 = B0 + (size_t)(n0 + srow) * K + scol;
  const ushort_t* gb1 = B1 + (size_t)(n0 + srow) * K + scol;
  const ushort_t* gb2 = B2 + (size_t)(n0 + srow) * K + scol;

  #pragma unroll 1
  for (int k0 = 0; k0 < K; k0 += 64) {
    __syncthreads();
    async_cp16(ga0 + k0,      &As[0][0][wave * 16][0]);
    async_cp16(ga0 + k0 + 32, &As[0][1][wave * 16][0]);
    async_cp16(ga1 + k0,      &As[1][0][wave * 16][0]);
    async_cp16(ga1 + k0 + 32, &As[1][1][wave * 16][0]);
    async_cp16(ga2 + k0,      &As[2][0][wave * 16][0]);
    async_cp16(ga2 + k0 + 32, &As[2][1][wave * 16][0]);
    async_cp16(gb0 + k0,      &Bs[0][0][wave * 16][0]);
    async_cp16(gb0 + k0 + 32, &Bs[0][1][wave * 16][0]);
    async_cp16(gb1 + k0,      &Bs[1][0][wave * 16][0]);
    async_cp16(gb1 + k0 + 32, &Bs[1][1][wave * 16][0]);
    async_cp16(gb2 + k0,      &Bs[2][0][wave * 16][0]);
    async_cp16(gb2 + k0 + 32, &Bs[2][1][wave * 16][0]);
    __syncthreads();
    #pragma unroll
    for (int z = 0; z < 3; z++) {
      bf16x8 a00 = *(const bf16x8*)&As[z][0][rA0][cA0];
      bf16x8 a01 = *(const bf16x8*)&As[z][1][rA0][cA0];
      bf16x8 a10 = *(const bf16x8*)&As[z][0][rA1r][cA1];
      bf16x8 a11 = *(const bf16x8*)&As[z][1][rA1r][cA1];
      bf16x8 b00 = *(const bf16x8*)&Bs[z][0][rB0][cB0];
      bf16x8 b01 = *(const bf16x8*)&Bs[z][1][rB0][cB0];
      bf16x8 b10 = *(const bf16x8*)&Bs[z][0][rB1r][cB1];
      bf16x8 b11 = *(const bf16x8*)&Bs[z][1][rB1r][cB1];
      acc[z][0][0] = __builtin_amdgcn_mfma_f32_16x16x32_bf16(a00, b00, acc[z][0][0], 0, 0, 0);
      acc[z][0][1] = __builtin_amdgcn_mfma_f32_16x16x32_bf16(a00, b10, acc[z][0][1], 0, 0, 0);
      acc[z][1][0] = __builtin_amdgcn_mfma_f32_16x16x32_bf16(a10, b00, acc[z][1][0], 0, 0, 0);
      acc[z][1][1] = __builtin_amdgcn_mfma_f32_16x16x32_bf16(a10, b10, acc[z][1][1], 0, 0, 0);
      acc[z][0][0] = __builtin_amdgcn_mfma_f32_16x16x32_bf16(a01, b01, acc[z][0][0], 0, 0, 0);
      acc[z][0][1] = __builtin_amdgcn_mfma_f32_16x16x32_bf16(a01, b11, acc[z][0][1], 0, 0, 0);
      acc[z][1][0] = __builtin_amdgcn_mfma_f32_16x16x32_bf16(a11, b01, acc[z][1][0], 0, 0, 0);
      acc[z][1][1] = __builtin_amdgcn_mfma_f32_16x16x32_bf16(a11, b11, acc[z][1][1], 0, 0, 0);
    }
  }

  // C/D layout: col = lane&15, row = (lane>>4)*4 + reg
  #pragma unroll
  for (int mi = 0; mi < 2; mi++)
    #pragma unroll
    for (int ni = 0; ni < 2; ni++) {
      int col = n0 + wcol * 32 + ni * 16 + fr;
      int row0 = m0 + wrow * 32 + mi * 16 + q * 4;
      #pragma unroll
      for (int r = 0; r < 4; r++) {
        size_t idx = (size_t)(row0 + r) * E_DIM + col;
        float v = (acc[0][mi][ni][r] + acc[1][mi][ni][r]) + acc[2][mi][ni][r];
        float nv = Cf[idx] + alpha * v;
        Cf[idx] = nv;
        Cb[idx] = f2bu(nv);
      }
    }
}

// ====================== MFMA attention, LDS-staged ======================

// ---- fused fwd: single-pass flash, log2-domain online softmax; emits m' = m + log2(l),
//      g=O-Xs (bf16 + transposed), Dv. grid (bh=32, y=16), balanced pairing.
//      DOUBLE-BUFFERED staging + single barrier per K/V tile: tile t+1's
//      global_load_lds issues right after the barrier, so the next barrier's
//      vmcnt drain waits on loads that had a full compute phase to land. ----
__global__ __launch_bounds__(256) void fwd_fused(const ushort_t* __restrict__ Qg,
                                                 const ushort_t* __restrict__ Kg,
                                                 const ushort_t* __restrict__ Vt,
                                                 const float* __restrict__ Xs,
                                                 float* __restrict__ mbuf,
                                                 ushort_t* __restrict__ Gb,
                                                 ushort_t* __restrict__ Gt,
                                                 float* __restrict__ Dv) {
  int bh = blockIdx.x, y = blockIdx.y;
  int it = (y < 8) ? (15 - y) : (y - 8);
  int b = bh >> 4, h = bh & 15;
  int tid = threadIdx.x, lane = tid & 63, wv = tid >> 6;
  int fr = lane & 15, q = lane >> 4;
  int i0 = it * 64, band = wv * 16;
  __shared__ ushort_t Ksb[2][4096];  // [j][d] chunk-rotated, double-buffered
  __shared__ ushort_t Vsb[2][4096];  // [d][j] chunk-rotated, double-buffered
  __shared__ ushort_t Ps[64][72];    // [i][j] wave-private bands (lane-written)

  const ushort_t* Kbase = Kg + (size_t)(b * S_LEN) * E_DIM + h * HD;
  const ushort_t* Vbase = Vt + (size_t)(bh * HD) * S_LEN;

  const ushort_t* Qrow = Qg + (size_t)(b * S_LEN + i0 + band + fr) * E_DIM + h * HD;
  bf16x8 aq0 = ldg8(Qrow + q * 8);
  bf16x8 aq1 = ldg8(Qrow + 32 + q * 8);

  float m[4], l[4];
  #pragma unroll
  for (int r = 0; r < 4; r++) { m[r] = -1e30f; l[r] = 0.f; }
  f32x4 oacc[4] = {};

  // prologue: stage tile jt=0 into buffer 0
  stage_tile(Kbase, E_DIM, Ksb[0], lane, wv);
  stage_tile(Vbase, S_LEN, Vsb[0], lane, wv);

  #pragma unroll 1
  for (int jt = 0; jt <= it; jt++) {
    int j0 = jt * 64;
    int cur = jt & 1;
    __syncthreads();   // vmcnt drain: tile jt staged; all reads of buf cur^1 done
    if (jt < it) {
      int j0n = j0 + 64;
      stage_tile(Kbase + (size_t)j0n * E_DIM, E_DIM, Ksb[cur ^ 1], lane, wv);
      stage_tile(Vbase + j0n, S_LEN, Vsb[cur ^ 1], lane, wv);
    }
    const ushort_t* Ks = Ksb[cur];
    const ushort_t* Vs = Vsb[cur];
    f32x4 sA[4];
    #pragma unroll
    for (int nc = 0; nc < 4; nc++) {
      bf16x8 bk0 = *tile_at(Ks, nc * 16 + fr, q);
      bf16x8 bk1 = *tile_at(Ks, nc * 16 + fr, q + 4);
      f32x4 z = {};
      z = __builtin_amdgcn_mfma_f32_16x16x32_bf16(aq0, bk0, z, 0, 0, 0);
      sA[nc] = __builtin_amdgcn_mfma_f32_16x16x32_bf16(aq1, bk1, z, 0, 0, 0);
    }
    float sv[4][4];
    #pragma unroll
    for (int nc = 0; nc < 4; nc++)
      #pragma unroll
      for (int r = 0; r < 4; r++) {
        int row = i0 + band + q * 4 + r;
        int col = j0 + nc * 16 + fr;
        sv[nc][r] = (col <= row) ? sA[nc][r] * C2_C : -1e30f;  // log2 domain
      }
    #pragma unroll
    for (int r = 0; r < 4; r++) {
      float mx = fmaxf(fmaxf(sv[0][r], sv[1][r]), fmaxf(sv[2][r], sv[3][r]));
      #pragma unroll
      for (int off = 1; off < 16; off <<= 1) mx = fmaxf(mx, __shfl_xor(mx, off, 64));
      float mn = fmaxf(m[r], mx);
      float alpha = exp2f(m[r] - mn);
      float ps = 0.f;
      #pragma unroll
      for (int nc = 0; nc < 4; nc++) {
        float p = exp2f(sv[nc][r] - mn);
        Ps[band + q * 4 + r][nc * 16 + fr] = f2bu(p);
        ps += p;
      }
      l[r] = l[r] * alpha + ps;   // per-lane partial (this lane's 4 columns)
      m[r] = mn;
      #pragma unroll
      for (int nc = 0; nc < 4; nc++) oacc[nc][r] *= alpha;
    }
    bf16x8 ap0 = *(const bf16x8*)&Ps[band + fr][q * 8];
    bf16x8 ap1 = *(const bf16x8*)&Ps[band + fr][32 + q * 8];
    #pragma unroll
    for (int nc = 0; nc < 4; nc++) {
      bf16x8 bv0 = *tile_at(Vs, nc * 16 + fr, q);
      bf16x8 bv1 = *tile_at(Vs, nc * 16 + fr, q + 4);
      oacc[nc] = __builtin_amdgcn_mfma_f32_16x16x32_bf16(ap0, bv0, oacc[nc], 0, 0, 0);
      oacc[nc] = __builtin_amdgcn_mfma_f32_16x16x32_bf16(ap1, bv1, oacc[nc], 0, 0, 0);
    }
  }
  // epilogue: finish the deferred l reduction
  #pragma unroll
  for (int r = 0; r < 4; r++) {
    #pragma unroll
    for (int off = 1; off < 16; off <<= 1) l[r] += __shfl_xor(l[r], off, 64);
  }
  // g = O - Xs (bf16 normal + transposed), Dv partials
  float linv[4];
  #pragma unroll
  for (int r = 0; r < 4; r++) linv[r] = 1.0f / l[r];
  float dpart[4] = {};
  #pragma unroll
  for (int nc = 0; nc < 4; nc++) {
    ushort_t pg[4];
    #pragma unroll
    for (int r = 0; r < 4; r++) {
      int row = i0 + band + q * 4 + r;
      size_t gi = (size_t)(b * S_LEN + row) * E_DIM + h * HD + nc * 16 + fr;
      float o = oacc[nc][r] * linv[r];
      float g = o - Xs[gi];
      ushort_t bu = f2bu(g);
      Gb[gi] = bu;
      pg[r] = bu;
      dpart[r] += g * o;
    }
    int d = nc * 16 + fr;
    int s0 = i0 + band + q * 4;
    *(uint2*)(Gt + ((size_t)bh * HD + d) * S_LEN + s0) = *(uint2*)pg;
  }
  #pragma unroll
  for (int r = 0; r < 4; r++) {
    #pragma unroll
    for (int off = 1; off < 16; off <<= 1) dpart[r] += __shfl_xor(dpart[r], off, 64);
  }
  if (fr == 0) {
    #pragma unroll
    for (int r = 0; r < 4; r++) {
      size_t sid = (size_t)bh * S_LEN + i0 + band + q * 4 + r;
      mbuf[sid] = m[r] + log2f(l[r]);   // m' folds 1/l into the exponent
      Dv[sid] = dpart[r];
    }
  }
}

// ---- merged backward: block (bh, y): dq for i-tile y then dk/dv for j-tile y
//      (17 units/block, perfect balance; splitting costs 5.5x HBM — round 3).
//      DOUBLE-BUFFERED staging, ONE barrier per tile iteration (prefetch-ahead);
//      phase B shares a single lane-written buffer for P then dS (wave-private
//      overwrite, verified round 1). LDS = 64 KB tiles + 9 KB P = 74.75 KB
//      (>64 KB OK on gfx950 — 160 KB/workgroup; 2 blocks/CU preserved). ----
__global__ __launch_bounds__(256) void bwd_fused(const ushort_t* __restrict__ Qg,
                                                 const ushort_t* __restrict__ Kg,
                                                 const ushort_t* __restrict__ Vg,
                                                 const ushort_t* __restrict__ Gg,
                                                 const ushort_t* __restrict__ Qt,
                                                 const ushort_t* __restrict__ Kt,
                                                 const ushort_t* __restrict__ Gt,
                                                 const float* __restrict__ mbuf,
                                                 const float* __restrict__ Dv,
                                                 ushort_t* __restrict__ GQ,
                                                 ushort_t* __restrict__ GK,
                                                 ushort_t* __restrict__ GV) {
  int bh = blockIdx.x, y = blockIdx.y;
  int b = bh >> 4, h = bh & 15;
  int tid = threadIdx.x, lane = tid & 63, wv = tid >> 6;
  int fr = lane & 15, q = lane >> 4;
  int band = wv * 16;
  __shared__ ushort_t tA[8][4096];   // staged tiles, 2 buffers of up to 4 types
  __shared__ ushort_t tP[64][72];    // lane-written P/dS (padded, wave-private rows)

  // ================= phase A: dq for i-tile y =================
  {
    int it = y, i0 = it * 64;

    const ushort_t* KbaseA = Kg + (size_t)(b * S_LEN) * E_DIM + h * HD;
    const ushort_t* VbaseA = Vg + (size_t)(b * S_LEN) * E_DIM + h * HD;
    const ushort_t* TbaseA = Kt + (size_t)(bh * HD) * S_LEN;

    const ushort_t* Qrow = Qg + (size_t)(b * S_LEN + i0 + band + fr) * E_DIM + h * HD;
    const ushort_t* Grow = Gg + (size_t)(b * S_LEN + i0 + band + fr) * E_DIM + h * HD;
    bf16x8 aq0 = ldg8(Qrow + q * 8), aq1 = ldg8(Qrow + 32 + q * 8);
    bf16x8 ag0 = ldg8(Grow + q * 8), ag1 = ldg8(Grow + 32 + q * 8);

    float mrow[4], Dr[4];
    #pragma unroll
    for (int r = 0; r < 4; r++) {
      size_t sid = (size_t)bh * S_LEN + i0 + band + q * 4 + r;
      mrow[r] = mbuf[sid]; Dr[r] = Dv[sid];
    }
    f32x4 dqacc[4] = {};

    // prologue: stage tile jt=0 into buffer 0 (slots 0..2)
    stage_tile(KbaseA, E_DIM, tA[0], lane, wv);
    stage_tile(VbaseA, E_DIM, tA[1], lane, wv);
    stage_tile(TbaseA, S_LEN, tA[2], lane, wv);

    #pragma unroll 1
    for (int jt = 0; jt <= it; jt++) {
      int cur = (jt & 1) * 3;
      __syncthreads();   // tile jt staged; prior reads of the other buffer done
      if (jt < it) {
        int j0n = (jt + 1) * 64;
        int nxt = 3 - cur;
        stage_tile(KbaseA + (size_t)j0n * E_DIM, E_DIM, tA[nxt], lane, wv);
        stage_tile(VbaseA + (size_t)j0n * E_DIM, E_DIM, tA[nxt + 1], lane, wv);
        stage_tile(TbaseA + j0n, S_LEN, tA[nxt + 2], lane, wv);
      }
      const ushort_t* Ks = tA[cur];
      const ushort_t* Vs = tA[cur + 1];
      const ushort_t* Ts = tA[cur + 2];
      int j0 = jt * 64;
      f32x4 sA[4], dpA[4];
      #pragma unroll
      for (int nc = 0; nc < 4; nc++) {
        bf16x8 bk0 = *tile_at(Ks, nc * 16 + fr, q);
        bf16x8 bk1 = *tile_at(Ks, nc * 16 + fr, q + 4);
        bf16x8 bv0 = *tile_at(Vs, nc * 16 + fr, q);
        bf16x8 bv1 = *tile_at(Vs, nc * 16 + fr, q + 4);
        f32x4 z = {};
        z = __builtin_amdgcn_mfma_f32_16x16x32_bf16(aq0, bk0, z, 0, 0, 0);
        sA[nc] = __builtin_amdgcn_mfma_f32_16x16x32_bf16(aq1, bk1, z, 0, 0, 0);
        f32x4 z2 = {};
        z2 = __builtin_amdgcn_mfma_f32_16x16x32_bf16(ag0, bv0, z2, 0, 0, 0);
        dpA[nc] = __builtin_amdgcn_mfma_f32_16x16x32_bf16(ag1, bv1, z2, 0, 0, 0);
      }
      #pragma unroll
      for (int nc = 0; nc < 4; nc++)
        #pragma unroll
        for (int r = 0; r < 4; r++) {
          int row = i0 + band + q * 4 + r;
          int col = j0 + nc * 16 + fr;
          float ds = 0.f;
          if (col <= row) {
            float P = exp2f(fmaf(sA[nc][r], C2_C, -mrow[r]));
            ds = P * (dpA[nc][r] - Dr[r]);   // SC lives in Kt
          }
          tP[band + q * 4 + r][nc * 16 + fr] = f2bu(ds);  // wave-private
        }
      bf16x8 ad0 = *(const bf16x8*)&tP[band + fr][q * 8];
      bf16x8 ad1 = *(const bf16x8*)&tP[band + fr][32 + q * 8];
      #pragma unroll
      for (int nc = 0; nc < 4; nc++) {
        bf16x8 bt0 = *tile_at(Ts, nc * 16 + fr, q);
        bf16x8 bt1 = *tile_at(Ts, nc * 16 + fr, q + 4);
        dqacc[nc] = __builtin_amdgcn_mfma_f32_16x16x32_bf16(ad0, bt0, dqacc[nc], 0, 0, 0);
        dqacc[nc] = __builtin_amdgcn_mfma_f32_16x16x32_bf16(ad1, bt1, dqacc[nc], 0, 0, 0);
      }
    }
    __syncthreads();   // all phase-A tile reads done before phase-B prologue staging
    #pragma unroll
    for (int nc = 0; nc < 4; nc++)
      #pragma unroll
      for (int r = 0; r < 4; r++) {
        int row = i0 + band + q * 4 + r;
        size_t gi = (size_t)(b * S_LEN + row) * E_DIM + h * HD + nc * 16 + fr;
        GQ[gi] = f2bu(dqacc[nc][r]);
      }
  }

  // ================= phase B: dk/dv for j-tile y =================
  {
    int jt = y, j0 = jt * 64;

    const ushort_t* QbaseB = Qg + (size_t)(b * S_LEN) * E_DIM + h * HD;
    const ushort_t* GbaseB = Gg + (size_t)(b * S_LEN) * E_DIM + h * HD;
    const ushort_t* QtbaseB = Qt + (size_t)(bh * HD) * S_LEN;
    const ushort_t* GtbaseB = Gt + (size_t)(bh * HD) * S_LEN;

    const ushort_t* Krow = Kg + (size_t)(b * S_LEN + j0 + band + fr) * E_DIM + h * HD;
    const ushort_t* Vrow = Vg + (size_t)(b * S_LEN + j0 + band + fr) * E_DIM + h * HD;
    bf16x8 ak0 = ldg8(Krow + q * 8), ak1 = ldg8(Krow + 32 + q * 8);
    bf16x8 av0 = ldg8(Vrow + q * 8), av1 = ldg8(Vrow + 32 + q * 8);

    f32x4 dkacc[4] = {}, dvacc[4] = {};

    // prologue: stage tile i_t=jt into buffer 0 (slots 0..3)
    stage_tile(QbaseB + (size_t)j0 * E_DIM, E_DIM, tA[0], lane, wv);
    stage_tile(GbaseB + (size_t)j0 * E_DIM, E_DIM, tA[1], lane, wv);
    stage_tile(QtbaseB + j0, S_LEN, tA[2], lane, wv);
    stage_tile(GtbaseB + j0, S_LEN, tA[3], lane, wv);

    #pragma unroll 1
    for (int i_t = jt; i_t < 16; i_t++) {
      int cur = ((i_t - jt) & 1) * 4;
      __syncthreads();   // tile i_t staged; prior reads of the other buffer done
      if (i_t < 15) {
        int i0n = (i_t + 1) * 64;
        int nxt = 4 - cur;
        stage_tile(QbaseB + (size_t)i0n * E_DIM, E_DIM, tA[nxt], lane, wv);
        stage_tile(GbaseB + (size_t)i0n * E_DIM, E_DIM, tA[nxt + 1], lane, wv);
        stage_tile(QtbaseB + i0n, S_LEN, tA[nxt + 2], lane, wv);
        stage_tile(GtbaseB + i0n, S_LEN, tA[nxt + 3], lane, wv);
      }
      const ushort_t* Qs  = tA[cur];
      const ushort_t* Gs  = tA[cur + 1];
      const ushort_t* Qts = tA[cur + 2];
      const ushort_t* Gts = tA[cur + 3];
      int i0 = i_t * 64;
      float mc[4], Dc[4];
      #pragma unroll
      for (int nc = 0; nc < 4; nc++) {
        size_t sid = (size_t)bh * S_LEN + i0 + nc * 16 + fr;
        mc[nc] = mbuf[sid]; Dc[nc] = Dv[sid];
      }
      f32x4 stA[4], dptA[4];
      #pragma unroll
      for (int nc = 0; nc < 4; nc++) {
        bf16x8 bq0 = *tile_at(Qs, nc * 16 + fr, q);
        bf16x8 bq1 = *tile_at(Qs, nc * 16 + fr, q + 4);
        bf16x8 bg0 = *tile_at(Gs, nc * 16 + fr, q);
        bf16x8 bg1 = *tile_at(Gs, nc * 16 + fr, q + 4);
        f32x4 z = {};
        z = __builtin_amdgcn_mfma_f32_16x16x32_bf16(ak0, bq0, z, 0, 0, 0);
        stA[nc] = __builtin_amdgcn_mfma_f32_16x16x32_bf16(ak1, bq1, z, 0, 0, 0);
        f32x4 z2 = {};
        z2 = __builtin_amdgcn_mfma_f32_16x16x32_bf16(av0, bg0, z2, 0, 0, 0);
        dptA[nc] = __builtin_amdgcn_mfma_f32_16x16x32_bf16(av1, bg1, z2, 0, 0, 0);
      }
      ushort_t dsp[4][4];
      #pragma unroll
      for (int nc = 0; nc < 4; nc++)
        #pragma unroll
        for (int r = 0; r < 4; r++) {
          int jrow = j0 + band + q * 4 + r;
          int icol = i0 + nc * 16 + fr;
          float P = 0.f, ds = 0.f;
          if (icol >= jrow) {
            P = exp2f(fmaf(stA[nc][r], C2_C, -mc[nc]));
            ds = P * (dptA[nc][r] - Dc[nc]);   // SC lives in Qt
          }
          dsp[nc][r] = f2bu(ds);
          tP[band + q * 4 + r][nc * 16 + fr] = f2bu(P);   // wave-private
        }
      bf16x8 ap0 = *(const bf16x8*)&tP[band + fr][q * 8];
      bf16x8 ap1 = *(const bf16x8*)&tP[band + fr][32 + q * 8];
      #pragma unroll
      for (int nc = 0; nc < 4; nc++) {
        bf16x8 bg0 = *tile_at(Gts, nc * 16 + fr, q);
        bf16x8 bg1 = *tile_at(Gts, nc * 16 + fr, q + 4);
        dvacc[nc] = __builtin_amdgcn_mfma_f32_16x16x32_bf16(ap0, bg0, dvacc[nc], 0, 0, 0);
        dvacc[nc] = __builtin_amdgcn_mfma_f32_16x16x32_bf16(ap1, bg1, dvacc[nc], 0, 0, 0);
      }
      // overwrite the P buffer with dS (wave-private rows; per-wave DS ordering
      // guarantees the ap reads above complete first — verified round 1)
      #pragma unroll
      for (int nc = 0; nc < 4; nc++)
        #pragma unroll
        for (int r = 0; r < 4; r++)
          tP[band + q * 4 + r][nc * 16 + fr] = dsp[nc][r];
      bf16x8 ad0 = *(const bf16x8*)&tP[band + fr][q * 8];
      bf16x8 ad1 = *(const bf16x8*)&tP[band + fr][32 + q * 8];
      #pragma unroll
      for (int nc = 0; nc < 4; nc++) {
        bf16x8 bq0 = *tile_at(Qts, nc * 16 + fr, q);
        bf16x8 bq1 = *tile_at(Qts, nc * 16 + fr, q + 4);
        dkacc[nc] = __builtin_amdgcn_mfma_f32_16x16x32_bf16(ad0, bq0, dkacc[nc], 0, 0, 0);
        dkacc[nc] = __builtin_amdgcn_mfma_f32_16x16x32_bf16(ad1, bq1, dkacc[nc], 0, 0, 0);
      }
    }
    #pragma unroll
    for (int nc = 0; nc < 4; nc++)
      #pragma unroll
      for (int r = 0; r < 4; r++) {
        int jrow = j0 + band + q * 4 + r;
        size_t gi = (size_t)(b * S_LEN + jrow) * E_DIM + h * HD + nc * 16 + fr;
        GK[gi] = f2bu(dkacc[nc][r]);
        GV[gi] = f2bu(dvacc[nc][r]);
      }
  }
}

// ---------------- launch ----------------
extern "C" void kernel_launch(void* const* d_in, const int* in_sizes, int n_in,
                              void* d_out, int out_size, void* d_ws, size_t ws_size,
                              hipStream_t stream) {
  const float* T1 = (const float*)d_in[0];
  const float* Wq = (const float*)d_in[1];
  const float* Wk = (const float*)d_in[2];
  const float* Wv = (const float*)d_in[3];
  const float* Wo = (const float*)d_in[4];

  const size_t M2 = 2097152;   // 2048*1024
  const size_t M1 = 1048576;
  float* w = (float*)d_ws;
  float* Xs = w;                       // 8 MB fp32 target
  float* mS = Xs + M2;                 // 64K f32 (stores m')
  float* DvS = mS + 65536;
  ushort_t* u = (ushort_t*)(DvS + 65536);
  ushort_t* W0 = u;          ushort_t* W1 = W0 + M1;  ushort_t* W2 = W1 + M1;
  ushort_t* W3 = W2 + M1;    ushort_t* W4 = W3 + M1;  ushort_t* W5 = W4 + M1;
  ushort_t* Qb = W5 + M1;    ushort_t* Kb = Qb + M2;  ushort_t* Vb = Kb + M2;
  ushort_t* Qt = Vb + M2;    ushort_t* Kt = Qt + M2;  ushort_t* Vt = Kt + M2;
  ushort_t* Gt = Vt + M2;
  ushort_t* Gb = Gt + M2;
  ushort_t* GQb = Gb + M2;   ushort_t* GKb = GQb + M2; ushort_t* GVb = GKb + M2;
  ushort_t* X2b = GVb + M2;
  float* X2 = (float*)d_out;

  // stage-1 aliases (all overwritten before stage-2 uses the slots)
  float* Mf  = (float*)Qb;       // 4 MB
  float* M2f = (float*)Kb;       // 4 MB
  ushort_t* Mb  = Gt;            // 2 MB
  ushort_t* Nb  = Vb;            // 2 MB
  ushort_t* AtB = Qt;            // 2 MB
  ushort_t* T1b = Kt;            // 4 MB

  // iter-1 shortcut aliases (dead before their regions' stage-2 consumers)
  float* Sf  = (float*)GQb;      // 8 MB fp32 scan partials (spans GQb+GKb)
  float* tot = mS;               // 128 KB chunk totals (mS rewritten by fwd of iter 2)
  ushort_t* Sb = GVb;            // 4 MB bf16 scan result

  dim3 pgrid(16, 16);
  dim3 sgrid(16, 16);       // 1024x1024 GEMMs
  dim3 ggrid(16, 32);       // 2048x1024 GEMMs
  dim3 agrid(BH_CNT, 16);   // attention

  // ---- stage 1 (algebraic): Xs = T * Wo * (3LR·I - 3LR²·M + LR³·M²),  M = WoᵀWo ----
  k_cast<<<(M2 / 4 + 255) / 256, 256, 0, stream>>>(T1, T1b, (int)(M2 / 4));
  prep_w<<<pgrid, 256, 0, stream>>>(Wo, W0, W1);
  // M = W1·W1ᵀ  (fp32 + bf16)
  gemm_mf<4, 1><<<sgrid, 256, 0, stream>>>(W1, nullptr, nullptr, W1, nullptr, nullptr,
                                           Mf, Mb, 0.f);
  // M2 = Mb·Mbᵀ (M symmetric)
  gemm_mf<3, 1><<<sgrid, 256, 0, stream>>>(Mb, nullptr, nullptr, Mb, nullptr, nullptr,
                                           M2f, nullptr, 0.f);
  k_formN<<<(M1 + 255) / 256, 256, 0, stream>>>(Mf, M2f, Nb);
  // AtB = N·Woᵀ  (symmetric N; this is (Wo·N)ᵀ in [N,K] form)
  gemm_mf<5, 1><<<sgrid, 256, 0, stream>>>(Nb, nullptr, nullptr, W0, nullptr, nullptr,
                                           nullptr, AtB, 0.f);
  // stage-2 weights (W0/W1 free after AtB)
  prep_w<<<pgrid, 256, 0, stream>>>(Wq, W0, W3);
  prep_w<<<pgrid, 256, 0, stream>>>(Wk, W1, W4);
  prep_w<<<pgrid, 256, 0, stream>>>(Wv, W2, W5);
  // Xs = T1b·AtBᵀ (fp32)
  gemm_mf<3, 1><<<ggrid, 256, 0, stream>>>(T1b, nullptr, nullptr, AtB, nullptr, nullptr,
                                           Xs, nullptr, 0.f);

  // ---- stage 2, iteration 1 (closed form): x=0 => Q=K=V=0, P exactly causal-uniform,
  //      dQ=dK=0, dV = P0^T(-Xs); x1 = LR * (P0^T Xs) * Wv via fp32 suffix scan + one GEMM ----
  k_scan1<<<dim3(E_DIM / 256, 2, 16), 256, 0, stream>>>(Xs, Sf, tot);
  k_scan2<<<dim3(E_DIM / 256, 2, 16), 256, 0, stream>>>(Sf, tot, Sb);
  gemm_mf<6, 1><<<ggrid, 256, 0, stream>>>(Sb, nullptr, nullptr, W5, nullptr, nullptr,
                                           X2, X2b, LR_C);

  // ---- stage 2, iterations 2..3 (full PC gradient) ----
  for (int t = 1; t < 3; t++) {
    gemm_qkv<<<ggrid, 256, 0, stream>>>(X2b, W0, W1, W2,
                                        Qb, Kb, Vb, Qt, Kt, Vt);
    fwd_fused<<<agrid, 256, 0, stream>>>(Qb, Kb, Vt, Xs, mS, Gb, Gt, DvS);
    bwd_fused<<<agrid, 256, 0, stream>>>(Qb, Kb, Vb, Gb, Qt, Kt, Gt, mS, DvS,
                                         GQb, GKb, GVb);
    gemm_acc<<<ggrid, 256, 0, stream>>>(GQb, GKb, GVb, W3, W4, W5,
                                        X2, X2b, -LR_C);
  }
}

// Round 10
// 407.705 us; speedup vs baseline: 1.0935x; 1.0467x over previous
//
#include <hip/hip_runtime.h>
#include <hip/hip_bf16.h>
#include <math.h>

// Problem constants (B=2, S=1024, E=1024, H=16, D=64)
#define S_LEN 1024
#define E_DIM 1024
#define NH 16
#define HD 64
#define M_ROWS 2048   // B*S
#define BH_CNT 32     // B*NH

static constexpr float LR_C = 0.01f;
static constexpr float SC_C = 0.125f;                // 1/sqrt(64)
static constexpr float C2_C = 0.125f * 1.44269504f;  // SC * log2(e): log2-domain softmax

typedef unsigned short ushort_t;
typedef __attribute__((ext_vector_type(8))) __bf16 bf16x8;
typedef __attribute__((ext_vector_type(4))) float f32x4;

static __device__ inline ushort_t f2bu(float f) {
  __hip_bfloat16 h = __float2bfloat16(f);
  return *(ushort_t*)&h;
}
static __device__ inline bf16x8 ldg8(const ushort_t* p) { return *(const bf16x8*)p; }

// async global->LDS, 16B per lane; LDS dest = wave-uniform base + lane*16
static __device__ inline void async_cp16(const ushort_t* g, __bf16* lds_wave_base) {
  __builtin_amdgcn_global_load_lds((const __attribute__((address_space(1))) void*)g,
                                   (__attribute__((address_space(3))) void*)lds_wave_base,
                                   16, 0, 0);
}

// ---- 64x64 bf16 tile in unpadded LDS with per-row chunk rotation ----
// element (r,c) lives at ushort offset r*64 + (((c>>3)+r)&7)*8 + (c&7).
// Staged via global_load_lds: wave w, issue t fills slab s=w*2+t (rows 8s..8s+7, 1 KB,
// wave-uniform dest); lane l supplies source chunk c=((l&7)-(l>>3))&7 of row 8s+(l>>3)
// (pre-rotated SOURCE address = m173's swizzle-the-global-side pattern).
// b128 fragment reads hit bank-quad (chunk+row)&7 — same distribution as the old +8 pad.
static __device__ inline void stage_tile(const ushort_t* src, size_t src_stride,
                                         ushort_t* lds, int lane, int wave) {
  int rl = lane >> 3;
  int c = ((lane & 7) - rl) & 7;
  #pragma unroll
  for (int t = 0; t < 2; t++) {
    int s = wave * 2 + t;
    async_cp16(src + (size_t)(s * 8 + rl) * src_stride + c * 8,
               (__bf16*)(lds + s * 512));
  }
}
static __device__ inline const bf16x8* tile_at(const ushort_t* lds, int r, int cchunk) {
  return (const bf16x8*)(lds + r * 64 + (((cchunk + r) & 7) * 8));
}

// ---------------- weight prep: bf16 cast + bf16 transpose, 64x64 tiles ----------------
__global__ __launch_bounds__(256) void prep_w(const float* __restrict__ W,
                                              ushort_t* __restrict__ Wb,
                                              ushort_t* __restrict__ WTb) {
  __shared__ float ts[64][65];
  int bx = blockIdx.x * 64, by = blockIdx.y * 64;
  int t = threadIdx.x;
  int rr = t >> 6, cc = t & 63;
  #pragma unroll
  for (int p = 0; p < 16; p++) {
    int r = p * 4 + rr;
    float v = W[(size_t)(by + r) * E_DIM + bx + cc];
    ts[r][cc] = v;
    Wb[(size_t)(by + r) * E_DIM + bx + cc] = f2bu(v);
  }
  __syncthreads();
  #pragma unroll
  for (int p = 0; p < 16; p++) {
    int r = p * 4 + rr;
    WTb[(size_t)(bx + r) * E_DIM + by + cc] = f2bu(ts[cc][r]);
  }
}

// ---------------- fp32 -> bf16 cast (float4-wide) ----------------
__global__ __launch_bounds__(256) void k_cast(const float* __restrict__ in,
                                              ushort_t* __restrict__ out, int n4) {
  int i = blockIdx.x * 256 + threadIdx.x;
  if (i < n4) {
    float4 v = ((const float4*)in)[i];
    ushort_t p[4] = {f2bu(v.x), f2bu(v.y), f2bu(v.z), f2bu(v.w)};
    *(uint2*)(out + (size_t)i * 4) = *(uint2*)p;
  }
}

// ---------------- N = 3LR*I - 3LR^2*M + LR^3*M2  (bf16 out) ----------------
__global__ __launch_bounds__(256) void k_formN(const float* __restrict__ Mf,
                                               const float* __restrict__ M2f,
                                               ushort_t* __restrict__ Nb) {
  int idx = blockIdx.x * 256 + threadIdx.x;   // 1M elements
  int i = idx >> 10, j = idx & 1023;
  float v = -3.f * LR_C * LR_C * Mf[idx] + LR_C * LR_C * LR_C * M2f[idx];
  if (i == j) v += 3.f * LR_C;
  Nb[idx] = f2bu(v);
}

// ---------------- iter-1 shortcut: suffix scan S[j] = sum_{i>=j} Xs[i]/(i+1) ----------------
// x=0 => Q=K=V=0 => P is exactly causal-uniform, dQ=dK=0, dV = P0^T(-Xs).
// x1 = LR * (P0^T Xs) * Wv. Two-pass chunked scan over the sequence dim.
__global__ __launch_bounds__(256) void k_scan1(const float* __restrict__ Xs,
                                               float* __restrict__ Sf,
                                               float* __restrict__ tot) {
  int e = blockIdx.x * 256 + threadIdx.x;  // column 0..1023
  int b = blockIdx.y;                      // batch
  int z = blockIdx.z;                      // chunk 0..15 (64 rows each)
  float acc = 0.f;
  for (int i = z * 64 + 63; i >= z * 64; i--) {
    size_t idx = ((size_t)b * S_LEN + i) * E_DIM + e;
    acc = fmaf(Xs[idx], 1.0f / (float)(i + 1), acc);
    Sf[idx] = acc;
  }
  tot[((size_t)b * 16 + z) * E_DIM + e] = acc;
}

__global__ __launch_bounds__(256) void k_scan2(const float* __restrict__ Sf,
                                               const float* __restrict__ tot,
                                               ushort_t* __restrict__ Sb) {
  int e = blockIdx.x * 256 + threadIdx.x;
  int b = blockIdx.y;
  int z = blockIdx.z;
  float off = 0.f;
  for (int c = z + 1; c < 16; c++) off += tot[((size_t)b * 16 + c) * E_DIM + e];
  for (int i = z * 64; i < z * 64 + 64; i++) {
    size_t idx = ((size_t)b * S_LEN + i) * E_DIM + e;
    Sb[idx] = f2bu(Sf[idx] + off);
  }
}

// ---------------- bf16 MFMA GEMM, 64x64 tile, BK=64, ASYNC global_load_lds staging ----------
// MODE 3: Cf = acc (fp32 only)
// MODE 4: Cf = acc and Cb0 = bf16(acc)
// MODE 5: Cb0 = bf16(acc)
// MODE 6: Cf = alpha*acc (overwrite) and Cb0 = bf16(alpha*acc)
template <int MODE, int NSEG>
__global__ __launch_bounds__(256) void gemm_mf(
    const ushort_t* __restrict__ A0, const ushort_t* __restrict__ A1, const ushort_t* __restrict__ A2,
    const ushort_t* __restrict__ B0, const ushort_t* __restrict__ B1, const ushort_t* __restrict__ B2,
    float* __restrict__ Cf,
    ushort_t* __restrict__ Cb0,
    float alpha) {
  const int K = 1024;
  __shared__ __bf16 As0[64][32];
  __shared__ __bf16 As1[64][32];
  __shared__ __bf16 Bs0[64][32];
  __shared__ __bf16 Bs1[64][32];
  int tid = threadIdx.x;
  int m0 = blockIdx.y * 64, n0 = blockIdx.x * 64;

  int lane = tid & 63, wave = tid >> 6;
  int wrow = wave >> 1, wcol = wave & 1;
  int fr = lane & 15, q = lane >> 4;

  int srow = wave * 16 + (lane >> 2);
  int scg = ((lane & 3) + (srow >> 1)) & 3;
  int scol = scg * 8;
  __bf16* ldsA0 = &As0[wave * 16][0];
  __bf16* ldsA1 = &As1[wave * 16][0];
  __bf16* ldsB0 = &Bs0[wave * 16][0];
  __bf16* ldsB1 = &Bs1[wave * 16][0];

  int rA0 = wrow * 32 + fr, rA1r = rA0 + 16;
  int rB0 = wcol * 32 + fr, rB1r = rB0 + 16;
  int cA0 = ((q - (rA0 >> 1)) & 3) * 8;
  int cA1 = ((q - (rA1r >> 1)) & 3) * 8;
  int cB0 = ((q - (rB0 >> 1)) & 3) * 8;
  int cB1 = ((q - (rB1r >> 1)) & 3) * 8;
  const bf16x8* pa0h0 = (const bf16x8*)&As0[rA0][cA0];
  const bf16x8* pa0h1 = (const bf16x8*)&As1[rA0][cA0];
  const bf16x8* pa1h0 = (const bf16x8*)&As0[rA1r][cA1];
  const bf16x8* pa1h1 = (const bf16x8*)&As1[rA1r][cA1];
  const bf16x8* pb0h0 = (const bf16x8*)&Bs0[rB0][cB0];
  const bf16x8* pb0h1 = (const bf16x8*)&Bs1[rB0][cB0];
  const bf16x8* pb1h0 = (const bf16x8*)&Bs0[rB1r][cB1];
  const bf16x8* pb1h1 = (const bf16x8*)&Bs1[rB1r][cB1];

  f32x4 acc[2][2] = {};

  #pragma unroll 1
  for (int seg = 0; seg < NSEG; seg++) {
    const ushort_t* Aseg = (seg == 0) ? A0 : (seg == 1) ? A1 : A2;
    const ushort_t* Bseg = (seg == 0) ? B0 : (seg == 1) ? B1 : B2;
    const ushort_t* ga = Aseg + (size_t)(m0 + srow) * K + scol;
    const ushort_t* gb = Bseg + (size_t)(n0 + srow) * K + scol;
    #pragma unroll 1
    for (int k0 = 0; k0 < K; k0 += 64) {
      __syncthreads();
      async_cp16(ga + k0, ldsA0);
      async_cp16(ga + k0 + 32, ldsA1);
      async_cp16(gb + k0, ldsB0);
      async_cp16(gb + k0 + 32, ldsB1);
      __syncthreads();
      bf16x8 a00 = *pa0h0, a01 = *pa0h1, a10 = *pa1h0, a11 = *pa1h1;
      bf16x8 b00 = *pb0h0, b01 = *pb0h1, b10 = *pb1h0, b11 = *pb1h1;
      acc[0][0] = __builtin_amdgcn_mfma_f32_16x16x32_bf16(a00, b00, acc[0][0], 0, 0, 0);
      acc[0][1] = __builtin_amdgcn_mfma_f32_16x16x32_bf16(a00, b10, acc[0][1], 0, 0, 0);
      acc[1][0] = __builtin_amdgcn_mfma_f32_16x16x32_bf16(a10, b00, acc[1][0], 0, 0, 0);
      acc[1][1] = __builtin_amdgcn_mfma_f32_16x16x32_bf16(a10, b10, acc[1][1], 0, 0, 0);
      acc[0][0] = __builtin_amdgcn_mfma_f32_16x16x32_bf16(a01, b01, acc[0][0], 0, 0, 0);
      acc[0][1] = __builtin_amdgcn_mfma_f32_16x16x32_bf16(a01, b11, acc[0][1], 0, 0, 0);
      acc[1][0] = __builtin_amdgcn_mfma_f32_16x16x32_bf16(a11, b01, acc[1][0], 0, 0, 0);
      acc[1][1] = __builtin_amdgcn_mfma_f32_16x16x32_bf16(a11, b11, acc[1][1], 0, 0, 0);
    }
  }

  // C/D layout: col = lane&15, row = (lane>>4)*4 + reg
  #pragma unroll
  for (int mi = 0; mi < 2; mi++)
    #pragma unroll
    for (int ni = 0; ni < 2; ni++) {
      int col = n0 + wcol * 32 + ni * 16 + fr;
      int row0 = m0 + wrow * 32 + mi * 16 + q * 4;
      #pragma unroll
      for (int r = 0; r < 4; r++) {
        size_t idx = (size_t)(row0 + r) * E_DIM + col;
        float v = acc[mi][ni][r];
        if (MODE == 3) {
          Cf[idx] = v;
        } else if (MODE == 4) {
          Cf[idx] = v;
          Cb0[idx] = f2bu(v);
        } else if (MODE == 6) {
          float nv = alpha * v;
          Cf[idx] = nv;
          Cb0[idx] = f2bu(nv);
        } else {  // MODE 5
          Cb0[idx] = f2bu(v);
        }
      }
    }
}

// ---------------- merged QKV GEMM: one A-stage feeds 3 B-matrices ----------------
__global__ __launch_bounds__(256) void gemm_qkv(
    const ushort_t* __restrict__ A,
    const ushort_t* __restrict__ B0, const ushort_t* __restrict__ B1, const ushort_t* __restrict__ B2,
    ushort_t* __restrict__ Cb0, ushort_t* __restrict__ Cb1, ushort_t* __restrict__ Cb2,
    ushort_t* __restrict__ Ct0, ushort_t* __restrict__ Ct1, ushort_t* __restrict__ Ct2) {
  const int K = 1024;
  __shared__ __bf16 As[2][64][32];
  __shared__ __bf16 Bs[3][2][64][32];
  int tid = threadIdx.x;
  int m0 = blockIdx.y * 64, n0 = blockIdx.x * 64;

  int lane = tid & 63, wave = tid >> 6;
  int wrow = wave >> 1, wcol = wave & 1;
  int fr = lane & 15, q = lane >> 4;

  int srow = wave * 16 + (lane >> 2);
  int scg = ((lane & 3) + (srow >> 1)) & 3;
  int scol = scg * 8;
  __bf16* ldsA0 = &As[0][wave * 16][0];
  __bf16* ldsA1 = &As[1][wave * 16][0];
  __bf16* ldsB00 = &Bs[0][0][wave * 16][0];
  __bf16* ldsB01 = &Bs[0][1][wave * 16][0];
  __bf16* ldsB10 = &Bs[1][0][wave * 16][0];
  __bf16* ldsB11 = &Bs[1][1][wave * 16][0];
  __bf16* ldsB20 = &Bs[2][0][wave * 16][0];
  __bf16* ldsB21 = &Bs[2][1][wave * 16][0];

  int rA0 = wrow * 32 + fr, rA1r = rA0 + 16;
  int rB0 = wcol * 32 + fr, rB1r = rB0 + 16;
  int cA0 = ((q - (rA0 >> 1)) & 3) * 8;
  int cA1 = ((q - (rA1r >> 1)) & 3) * 8;
  int cB0 = ((q - (rB0 >> 1)) & 3) * 8;
  int cB1 = ((q - (rB1r >> 1)) & 3) * 8;
  const bf16x8* pa0h0 = (const bf16x8*)&As[0][rA0][cA0];
  const bf16x8* pa0h1 = (const bf16x8*)&As[1][rA0][cA0];
  const bf16x8* pa1h0 = (const bf16x8*)&As[0][rA1r][cA1];
  const bf16x8* pa1h1 = (const bf16x8*)&As[1][rA1r][cA1];

  f32x4 acc[3][2][2] = {};

  const ushort_t* ga = A + (size_t)(m0 + srow) * K + scol;
  const ushort_t* gb0 = B0 + (size_t)(n0 + srow) * K + scol;
  const ushort_t* gb1 = B1 + (size_t)(n0 + srow) * K + scol;
  const ushort_t* gb2 = B2 + (size_t)(n0 + srow) * K + scol;

  #pragma unroll 1
  for (int k0 = 0; k0 < K; k0 += 64) {
    __syncthreads();
    async_cp16(ga + k0, ldsA0);
    async_cp16(ga + k0 + 32, ldsA1);
    async_cp16(gb0 + k0, ldsB00);
    async_cp16(gb0 + k0 + 32, ldsB01);
    async_cp16(gb1 + k0, ldsB10);
    async_cp16(gb1 + k0 + 32, ldsB11);
    async_cp16(gb2 + k0, ldsB20);
    async_cp16(gb2 + k0 + 32, ldsB21);
    __syncthreads();
    bf16x8 a00 = *pa0h0, a01 = *pa0h1, a10 = *pa1h0, a11 = *pa1h1;
    #pragma unroll
    for (int z = 0; z < 3; z++) {
      bf16x8 b00 = *(const bf16x8*)&Bs[z][0][rB0][cB0];
      bf16x8 b01 = *(const bf16x8*)&Bs[z][1][rB0][cB0];
      bf16x8 b10 = *(const bf16x8*)&Bs[z][0][rB1r][cB1];
      bf16x8 b11 = *(const bf16x8*)&Bs[z][1][rB1r][cB1];
      acc[z][0][0] = __builtin_amdgcn_mfma_f32_16x16x32_bf16(a00, b00, acc[z][0][0], 0, 0, 0);
      acc[z][0][1] = __builtin_amdgcn_mfma_f32_16x16x32_bf16(a00, b10, acc[z][0][1], 0, 0, 0);
      acc[z][1][0] = __builtin_amdgcn_mfma_f32_16x16x32_bf16(a10, b00, acc[z][1][0], 0, 0, 0);
      acc[z][1][1] = __builtin_amdgcn_mfma_f32_16x16x32_bf16(a10, b10, acc[z][1][1], 0, 0, 0);
      acc[z][0][0] = __builtin_amdgcn_mfma_f32_16x16x32_bf16(a01, b01, acc[z][0][0], 0, 0, 0);
      acc[z][0][1] = __builtin_amdgcn_mfma_f32_16x16x32_bf16(a01, b11, acc[z][0][1], 0, 0, 0);
      acc[z][1][0] = __builtin_amdgcn_mfma_f32_16x16x32_bf16(a11, b01, acc[z][1][0], 0, 0, 0);
      acc[z][1][1] = __builtin_amdgcn_mfma_f32_16x16x32_bf16(a11, b11, acc[z][1][1], 0, 0, 0);
    }
  }

  // C/D layout: col = lane&15, row = (lane>>4)*4 + reg
  #pragma unroll
  for (int z = 0; z < 3; z++) {
    ushort_t* Cbz = (z == 0) ? Cb0 : (z == 1) ? Cb1 : Cb2;
    ushort_t* Ctz = (z == 0) ? Ct0 : (z == 1) ? Ct1 : Ct2;
    float tsc = (z == 2) ? 1.0f : SC_C;   // Qt/Kt carry the 1/sqrt(d) factor
    #pragma unroll
    for (int mi = 0; mi < 2; mi++)
      #pragma unroll
      for (int ni = 0; ni < 2; ni++) {
        int col = n0 + wcol * 32 + ni * 16 + fr;
        int row0 = m0 + wrow * 32 + mi * 16 + q * 4;
        ushort_t pk[4];
        #pragma unroll
        for (int r = 0; r < 4; r++) {
          size_t idx = (size_t)(row0 + r) * E_DIM + col;
          float v = acc[z][mi][ni][r];
          Cbz[idx] = f2bu(v);
          pk[r] = f2bu(v * tsc);
        }
        int hh = col >> 6, dd = col & 63;
        int bb = row0 >> 10, ss = row0 & 1023;
        *(uint2*)(Ctz + ((size_t)((bb * NH + hh) * HD + dd)) * S_LEN + ss) = *(uint2*)pk;
      }
  }
}

// ---------------- merged accumulation GEMM: X2 += alpha * sum_s(As·Bs^T) ----------------
__global__ __launch_bounds__(256) void gemm_acc(
    const ushort_t* __restrict__ A0, const ushort_t* __restrict__ A1, const ushort_t* __restrict__ A2,
    const ushort_t* __restrict__ B0, const ushort_t* __restrict__ B1, const ushort_t* __restrict__ B2,
    float* __restrict__ Cf, ushort_t* __restrict__ Cb, float alpha) {
  const int K = 1024;
  __shared__ __bf16 As[3][2][64][32];
  __shared__ __bf16 Bs[3][2][64][32];
  int tid = threadIdx.x;
  int m0 = blockIdx.y * 64, n0 = blockIdx.x * 64;

  int lane = tid & 63, wave = tid >> 6;
  int wrow = wave >> 1, wcol = wave & 1;
  int fr = lane & 15, q = lane >> 4;

  int srow = wave * 16 + (lane >> 2);
  int scg = ((lane & 3) + (srow >> 1)) & 3;
  int scol = scg * 8;

  int rA0 = wrow * 32 + fr, rA1r = rA0 + 16;
  int rB0 = wcol * 32 + fr, rB1r = rB0 + 16;
  int cA0 = ((q - (rA0 >> 1)) & 3) * 8;
  int cA1 = ((q - (rA1r >> 1)) & 3) * 8;
  int cB0 = ((q - (rB0 >> 1)) & 3) * 8;
  int cB1 = ((q - (rB1r >> 1)) & 3) * 8;

  f32x4 acc[3][2][2] = {};

  const ushort_t* ga0 = A0 + (size_t)(m0 + srow) * K + scol;
  const ushort_t* ga1 = A1 + (size_t)(m0 + srow) * K + scol;
  const ushort_t* ga2 = A2 + (size_t)(m0 + srow) * K + scol;
  const ushort_t* gb0 = B0 + (size_t)(n0 + srow) * K + scol;
  const ushort_t* gb1 = B1 + (size_t)(n0 + srow) * K + scol;
  const ushort_t* gb2 = B2 + (size_t)(n0 + srow) * K + scol;

  #pragma unroll 1
  for (int k0 = 0; k0 < K; k0 += 64) {
    __syncthreads();
    async_cp16(ga0 + k0,      &As[0][0][wave * 16][0]);
    async_cp16(ga0 + k0 + 32, &As[0][1][wave * 16][0]);
    async_cp16(ga1 + k0,      &As[1][0][wave * 16][0]);
    async_cp16(ga1 + k0 + 32, &As[1][1][wave * 16][0]);
    async_cp16(ga2 + k0,      &As[2][0][wave * 16][0]);
    async_cp16(ga2 + k0 + 32, &As[2][1][wave * 16][0]);
    async_cp16(gb0 + k0,      &Bs[0][0][wave * 16][0]);
    async_cp16(gb0 + k0 + 32, &Bs[0][1][wave * 16][0]);
    async_cp16(gb1 + k0,      &Bs[1][0][wave * 16][0]);
    async_cp16(gb1 + k0 + 32, &Bs[1][1][wave * 16][0]);
    async_cp16(gb2 + k0,      &Bs[2][0][wave * 16][0]);
    async_cp16(gb2 + k0 + 32, &Bs[2][1][wave * 16][0]);
    __syncthreads();
    #pragma unroll
    for (int z = 0; z < 3; z++) {
      bf16x8 a00 = *(const bf16x8*)&As[z][0][rA0][cA0];
      bf16x8 a01 = *(const bf16x8*)&As[z][1][rA0][cA0];
      bf16x8 a10 = *(const bf16x8*)&As[z][0][rA1r][cA1];
      bf16x8 a11 = *(const bf16x8*)&As[z][1][rA1r][cA1];
      bf16x8 b00 = *(const bf16x8*)&Bs[z][0][rB0][cB0];
      bf16x8 b01 = *(const bf16x8*)&Bs[z][1][rB0][cB0];
      bf16x8 b10 = *(const bf16x8*)&Bs[z][0][rB1r][cB1];
      bf16x8 b11 = *(const bf16x8*)&Bs[z][1][rB1r][cB1];
      acc[z][0][0] = __builtin_amdgcn_mfma_f32_16x16x32_bf16(a00, b00, acc[z][0][0], 0, 0, 0);
      acc[z][0][1] = __builtin_amdgcn_mfma_f32_16x16x32_bf16(a00, b10, acc[z][0][1], 0, 0, 0);
      acc[z][1][0] = __builtin_amdgcn_mfma_f32_16x16x32_bf16(a10, b00, acc[z][1][0], 0, 0, 0);
      acc[z][1][1] = __builtin_amdgcn_mfma_f32_16x16x32_bf16(a10, b10, acc[z][1][1], 0, 0, 0);
      acc[z][0][0] = __builtin_amdgcn_mfma_f32_16x16x32_bf16(a01, b01, acc[z][0][0], 0, 0, 0);
      acc[z][0][1] = __builtin_amdgcn_mfma_f32_16x16x32_bf16(a01, b11, acc[z][0][1], 0, 0, 0);
      acc[z][1][0] = __builtin_amdgcn_mfma_f32_16x16x32_bf16(a11, b01, acc[z][1][0], 0, 0, 0);
      acc[z][1][1] = __builtin_amdgcn_mfma_f32_16x16x32_bf16(a11, b11, acc[z][1][1], 0, 0, 0);
    }
  }

  // C/D layout: col = lane&15, row = (lane>>4)*4 + reg
  #pragma unroll
  for (int mi = 0; mi < 2; mi++)
    #pragma unroll
    for (int ni = 0; ni < 2; ni++) {
      int col = n0 + wcol * 32 + ni * 16 + fr;
      int row0 = m0 + wrow * 32 + mi * 16 + q * 4;
      #pragma unroll
      for (int r = 0; r < 4; r++) {
        size_t idx = (size_t)(row0 + r) * E_DIM + col;
        float v = (acc[0][mi][ni][r] + acc[1][mi][ni][r]) + acc[2][mi][ni][r];
        float nv = Cf[idx] + alpha * v;
        Cf[idx] = nv;
        Cb[idx] = f2bu(nv);
      }
    }
}

// ====================== MFMA attention, LDS-staged ======================

// ---- fused fwd: single-pass flash, log2-domain online softmax; emits m' = m + log2(l),
//      g=O-Xs (bf16 + transposed), Dv. grid (bh=32, y=16), balanced pairing.
//      Double-buffered K/V staging (1 barrier/tile); causal mask evaluated only on
//      the DIAGONAL tile (off-diagonal tiles are provably unmasked). ----
__global__ __launch_bounds__(256) void fwd_fused(const ushort_t* __restrict__ Qg,
                                                 const ushort_t* __restrict__ Kg,
                                                 const ushort_t* __restrict__ Vt,
                                                 const float* __restrict__ Xs,
                                                 float* __restrict__ mbuf,
                                                 ushort_t* __restrict__ Gb,
                                                 ushort_t* __restrict__ Gt,
                                                 float* __restrict__ Dv) {
  int bh = blockIdx.x, y = blockIdx.y;
  int it = (y < 8) ? (15 - y) : (y - 8);
  int b = bh >> 4, h = bh & 15;
  int tid = threadIdx.x, lane = tid & 63, wv = tid >> 6;
  int fr = lane & 15, q = lane >> 4;
  int i0 = it * 64, band = wv * 16;
  __shared__ ushort_t Ksb[2][4096];  // [j][d] chunk-rotated, double-buffered
  __shared__ ushort_t Vsb[2][4096];  // [d][j] chunk-rotated, double-buffered
  __shared__ ushort_t Ps[64][72];    // [i][j] wave-private bands (lane-written)

  const ushort_t* Kbase = Kg + (size_t)(b * S_LEN) * E_DIM + h * HD;
  const ushort_t* Vbase = Vt + (size_t)(bh * HD) * S_LEN;

  const ushort_t* Qrow = Qg + (size_t)(b * S_LEN + i0 + band + fr) * E_DIM + h * HD;
  bf16x8 aq0 = ldg8(Qrow + q * 8);
  bf16x8 aq1 = ldg8(Qrow + 32 + q * 8);

  float m[4], l[4];
  #pragma unroll
  for (int r = 0; r < 4; r++) { m[r] = -1e30f; l[r] = 0.f; }
  f32x4 oacc[4] = {};

  // prologue: stage tile jt=0 into buffer 0
  stage_tile(Kbase, E_DIM, Ksb[0], lane, wv);
  stage_tile(Vbase, S_LEN, Vsb[0], lane, wv);

  #pragma unroll 1
  for (int jt = 0; jt <= it; jt++) {
    int j0 = jt * 64;
    int cur = jt & 1;
    __syncthreads();   // vmcnt drain: tile jt staged; all reads of buf cur^1 done
    if (jt < it) {
      int j0n = j0 + 64;
      stage_tile(Kbase + (size_t)j0n * E_DIM, E_DIM, Ksb[cur ^ 1], lane, wv);
      stage_tile(Vbase + j0n, S_LEN, Vsb[cur ^ 1], lane, wv);
    }
    const ushort_t* Ks = Ksb[cur];
    const ushort_t* Vs = Vsb[cur];
    f32x4 sA[4];
    #pragma unroll
    for (int nc = 0; nc < 4; nc++) {
      bf16x8 bk0 = *tile_at(Ks, nc * 16 + fr, q);
      bf16x8 bk1 = *tile_at(Ks, nc * 16 + fr, q + 4);
      f32x4 z = {};
      z = __builtin_amdgcn_mfma_f32_16x16x32_bf16(aq0, bk0, z, 0, 0, 0);
      sA[nc] = __builtin_amdgcn_mfma_f32_16x16x32_bf16(aq1, bk1, z, 0, 0, 0);
    }
    float sv[4][4];
    if (jt == it) {   // diagonal tile: causal mask needed
      #pragma unroll
      for (int nc = 0; nc < 4; nc++)
        #pragma unroll
        for (int r = 0; r < 4; r++) {
          int row = i0 + band + q * 4 + r;
          int col = j0 + nc * 16 + fr;
          sv[nc][r] = (col <= row) ? sA[nc][r] * C2_C : -1e30f;  // log2 domain
        }
    } else {          // strictly-lower tile: always unmasked
      #pragma unroll
      for (int nc = 0; nc < 4; nc++)
        #pragma unroll
        for (int r = 0; r < 4; r++)
          sv[nc][r] = sA[nc][r] * C2_C;
    }
    #pragma unroll
    for (int r = 0; r < 4; r++) {
      float mx = fmaxf(fmaxf(sv[0][r], sv[1][r]), fmaxf(sv[2][r], sv[3][r]));
      #pragma unroll
      for (int off = 1; off < 16; off <<= 1) mx = fmaxf(mx, __shfl_xor(mx, off, 64));
      float mn = fmaxf(m[r], mx);
      float alpha = exp2f(m[r] - mn);
      float ps = 0.f;
      #pragma unroll
      for (int nc = 0; nc < 4; nc++) {
        float p = exp2f(sv[nc][r] - mn);
        Ps[band + q * 4 + r][nc * 16 + fr] = f2bu(p);
        ps += p;
      }
      l[r] = l[r] * alpha + ps;   // per-lane partial (this lane's 4 columns)
      m[r] = mn;
      #pragma unroll
      for (int nc = 0; nc < 4; nc++) oacc[nc][r] *= alpha;
    }
    bf16x8 ap0 = *(const bf16x8*)&Ps[band + fr][q * 8];
    bf16x8 ap1 = *(const bf16x8*)&Ps[band + fr][32 + q * 8];
    #pragma unroll
    for (int nc = 0; nc < 4; nc++) {
      bf16x8 bv0 = *tile_at(Vs, nc * 16 + fr, q);
      bf16x8 bv1 = *tile_at(Vs, nc * 16 + fr, q + 4);
      oacc[nc] = __builtin_amdgcn_mfma_f32_16x16x32_bf16(ap0, bv0, oacc[nc], 0, 0, 0);
      oacc[nc] = __builtin_amdgcn_mfma_f32_16x16x32_bf16(ap1, bv1, oacc[nc], 0, 0, 0);
    }
  }
  // epilogue: finish the deferred l reduction
  #pragma unroll
  for (int r = 0; r < 4; r++) {
    #pragma unroll
    for (int off = 1; off < 16; off <<= 1) l[r] += __shfl_xor(l[r], off, 64);
  }
  // g = O - Xs (bf16 normal + transposed), Dv partials
  float linv[4];
  #pragma unroll
  for (int r = 0; r < 4; r++) linv[r] = 1.0f / l[r];
  float dpart[4] = {};
  #pragma unroll
  for (int nc = 0; nc < 4; nc++) {
    ushort_t pg[4];
    #pragma unroll
    for (int r = 0; r < 4; r++) {
      int row = i0 + band + q * 4 + r;
      size_t gi = (size_t)(b * S_LEN + row) * E_DIM + h * HD + nc * 16 + fr;
      float o = oacc[nc][r] * linv[r];
      float g = o - Xs[gi];
      ushort_t bu = f2bu(g);
      Gb[gi] = bu;
      pg[r] = bu;
      dpart[r] += g * o;
    }
    int d = nc * 16 + fr;
    int s0 = i0 + band + q * 4;
    *(uint2*)(Gt + ((size_t)bh * HD + d) * S_LEN + s0) = *(uint2*)pg;
  }
  #pragma unroll
  for (int r = 0; r < 4; r++) {
    #pragma unroll
    for (int off = 1; off < 16; off <<= 1) dpart[r] += __shfl_xor(dpart[r], off, 64);
  }
  if (fr == 0) {
    #pragma unroll
    for (int r = 0; r < 4; r++) {
      size_t sid = (size_t)bh * S_LEN + i0 + band + q * 4 + r;
      mbuf[sid] = m[r] + log2f(l[r]);   // m' folds 1/l into the exponent
      Dv[sid] = dpart[r];
    }
  }
}

// ---- merged backward: block (bh, y): dq for i-tile y then dk/dv for j-tile y
//      (17 units/block, perfect balance; splitting costs 5.5x HBM — round 3).
//      Round-7 structure (single-buffered staging, dual PT/dST — round-8's dbuf
//      regressed bwd): 2 barriers/iter. Causal mask only on the DIAGONAL tile. ----
__global__ __launch_bounds__(256) void bwd_fused(const ushort_t* __restrict__ Qg,
                                                 const ushort_t* __restrict__ Kg,
                                                 const ushort_t* __restrict__ Vg,
                                                 const ushort_t* __restrict__ Gg,
                                                 const ushort_t* __restrict__ Qt,
                                                 const ushort_t* __restrict__ Kt,
                                                 const ushort_t* __restrict__ Gt,
                                                 const float* __restrict__ mbuf,
                                                 const float* __restrict__ Dv,
                                                 ushort_t* __restrict__ GQ,
                                                 ushort_t* __restrict__ GK,
                                                 ushort_t* __restrict__ GV) {
  int bh = blockIdx.x, y = blockIdx.y;
  int b = bh >> 4, h = bh & 15;
  int tid = threadIdx.x, lane = tid & 63, wv = tid >> 6;
  int fr = lane & 15, q = lane >> 4;
  int band = wv * 16;
  __shared__ ushort_t tA[4][4096];    // staged tiles (chunk-rotated, global_load_lds)
  __shared__ ushort_t tP[2][64][72];  // lane-written P/dS (padded)

  // ================= phase A: dq for i-tile y =================
  {
    ushort_t* Ks = tA[0];           // [j][d]
    ushort_t* Vs = tA[1];           // [j][d]
    ushort_t* Ts = tA[2];           // [d][j] Kt (pre-scaled by SC)
    ushort_t (*dSs)[72] = tP[0];
    int it = y, i0 = it * 64;

    const ushort_t* KbaseA = Kg + (size_t)(b * S_LEN) * E_DIM + h * HD;
    const ushort_t* VbaseA = Vg + (size_t)(b * S_LEN) * E_DIM + h * HD;
    const ushort_t* TbaseA = Kt + (size_t)(bh * HD) * S_LEN;

    const ushort_t* Qrow = Qg + (size_t)(b * S_LEN + i0 + band + fr) * E_DIM + h * HD;
    const ushort_t* Grow = Gg + (size_t)(b * S_LEN + i0 + band + fr) * E_DIM + h * HD;
    bf16x8 aq0 = ldg8(Qrow + q * 8), aq1 = ldg8(Qrow + 32 + q * 8);
    bf16x8 ag0 = ldg8(Grow + q * 8), ag1 = ldg8(Grow + 32 + q * 8);

    float mrow[4], Dr[4];
    #pragma unroll
    for (int r = 0; r < 4; r++) {
      size_t sid = (size_t)bh * S_LEN + i0 + band + q * 4 + r;
      mrow[r] = mbuf[sid]; Dr[r] = Dv[sid];
    }
    f32x4 dqacc[4] = {};

    #pragma unroll 1
    for (int jt = 0; jt <= it; jt++) {
      int j0 = jt * 64;
      __syncthreads();
      stage_tile(KbaseA + (size_t)j0 * E_DIM, E_DIM, Ks, lane, wv);
      stage_tile(VbaseA + (size_t)j0 * E_DIM, E_DIM, Vs, lane, wv);
      stage_tile(TbaseA + j0, S_LEN, Ts, lane, wv);
      __syncthreads();
      f32x4 sA[4], dpA[4];
      #pragma unroll
      for (int nc = 0; nc < 4; nc++) {
        bf16x8 bk0 = *tile_at(Ks, nc * 16 + fr, q);
        bf16x8 bk1 = *tile_at(Ks, nc * 16 + fr, q + 4);
        bf16x8 bv0 = *tile_at(Vs, nc * 16 + fr, q);
        bf16x8 bv1 = *tile_at(Vs, nc * 16 + fr, q + 4);
        f32x4 z = {};
        z = __builtin_amdgcn_mfma_f32_16x16x32_bf16(aq0, bk0, z, 0, 0, 0);
        sA[nc] = __builtin_amdgcn_mfma_f32_16x16x32_bf16(aq1, bk1, z, 0, 0, 0);
        f32x4 z2 = {};
        z2 = __builtin_amdgcn_mfma_f32_16x16x32_bf16(ag0, bv0, z2, 0, 0, 0);
        dpA[nc] = __builtin_amdgcn_mfma_f32_16x16x32_bf16(ag1, bv1, z2, 0, 0, 0);
      }
      if (jt == it) {   // diagonal tile: causal mask needed
        #pragma unroll
        for (int nc = 0; nc < 4; nc++)
          #pragma unroll
          for (int r = 0; r < 4; r++) {
            int row = i0 + band + q * 4 + r;
            int col = j0 + nc * 16 + fr;
            float ds = 0.f;
            if (col <= row) {
              float P = exp2f(fmaf(sA[nc][r], C2_C, -mrow[r]));
              ds = P * (dpA[nc][r] - Dr[r]);   // SC lives in Kt
            }
            dSs[band + q * 4 + r][nc * 16 + fr] = f2bu(ds);  // wave-private
          }
      } else {          // strictly-lower tile: always unmasked
        #pragma unroll
        for (int nc = 0; nc < 4; nc++)
          #pragma unroll
          for (int r = 0; r < 4; r++) {
            float P = exp2f(fmaf(sA[nc][r], C2_C, -mrow[r]));
            float ds = P * (dpA[nc][r] - Dr[r]);
            dSs[band + q * 4 + r][nc * 16 + fr] = f2bu(ds);
          }
      }
      bf16x8 ad0 = *(const bf16x8*)&dSs[band + fr][q * 8];
      bf16x8 ad1 = *(const bf16x8*)&dSs[band + fr][32 + q * 8];
      #pragma unroll
      for (int nc = 0; nc < 4; nc++) {
        bf16x8 bt0 = *tile_at(Ts, nc * 16 + fr, q);
        bf16x8 bt1 = *tile_at(Ts, nc * 16 + fr, q + 4);
        dqacc[nc] = __builtin_amdgcn_mfma_f32_16x16x32_bf16(ad0, bt0, dqacc[nc], 0, 0, 0);
        dqacc[nc] = __builtin_amdgcn_mfma_f32_16x16x32_bf16(ad1, bt1, dqacc[nc], 0, 0, 0);
      }
    }
    #pragma unroll
    for (int nc = 0; nc < 4; nc++)
      #pragma unroll
      for (int r = 0; r < 4; r++) {
        int row = i0 + band + q * 4 + r;
        size_t gi = (size_t)(b * S_LEN + row) * E_DIM + h * HD + nc * 16 + fr;
        GQ[gi] = f2bu(dqacc[nc][r]);
      }
  }

  // ================= phase B: dk/dv for j-tile y =================
  {
    ushort_t* Qs  = tA[0];          // [i][d]
    ushort_t* Gs  = tA[1];          // [i][d]
    ushort_t* Qts = tA[2];          // [d][i] (pre-scaled by SC)
    ushort_t* Gts = tA[3];          // [d][i]
    ushort_t (*PT)[72]  = tP[0];    // [j][i]
    ushort_t (*dST)[72] = tP[1];    // [j][i]
    int jt = y, j0 = jt * 64;

    const ushort_t* QbaseB = Qg + (size_t)(b * S_LEN) * E_DIM + h * HD;
    const ushort_t* GbaseB = Gg + (size_t)(b * S_LEN) * E_DIM + h * HD;
    const ushort_t* QtbaseB = Qt + (size_t)(bh * HD) * S_LEN;
    const ushort_t* GtbaseB = Gt + (size_t)(bh * HD) * S_LEN;

    const ushort_t* Krow = Kg + (size_t)(b * S_LEN + j0 + band + fr) * E_DIM + h * HD;
    const ushort_t* Vrow = Vg + (size_t)(b * S_LEN + j0 + band + fr) * E_DIM + h * HD;
    bf16x8 ak0 = ldg8(Krow + q * 8), ak1 = ldg8(Krow + 32 + q * 8);
    bf16x8 av0 = ldg8(Vrow + q * 8), av1 = ldg8(Vrow + 32 + q * 8);

    f32x4 dkacc[4] = {}, dvacc[4] = {};

    #pragma unroll 1
    for (int i_t = jt; i_t < 16; i_t++) {
      int i0 = i_t * 64;
      __syncthreads();
      stage_tile(QbaseB + (size_t)i0 * E_DIM, E_DIM, Qs, lane, wv);
      stage_tile(GbaseB + (size_t)i0 * E_DIM, E_DIM, Gs, lane, wv);
      stage_tile(QtbaseB + i0, S_LEN, Qts, lane, wv);
      stage_tile(GtbaseB + i0, S_LEN, Gts, lane, wv);
      __syncthreads();
      float mc[4], Dc[4];
      #pragma unroll
      for (int nc = 0; nc < 4; nc++) {
        size_t sid = (size_t)bh * S_LEN + i0 + nc * 16 + fr;
        mc[nc] = mbuf[sid]; Dc[nc] = Dv[sid];
      }
      f32x4 stA[4], dptA[4];
      #pragma unroll
      for (int nc = 0; nc < 4; nc++) {
        bf16x8 bq0 = *tile_at(Qs, nc * 16 + fr, q);
        bf16x8 bq1 = *tile_at(Qs, nc * 16 + fr, q + 4);
        bf16x8 bg0 = *tile_at(Gs, nc * 16 + fr, q);
        bf16x8 bg1 = *tile_at(Gs, nc * 16 + fr, q + 4);
        f32x4 z = {};
        z = __builtin_amdgcn_mfma_f32_16x16x32_bf16(ak0, bq0, z, 0, 0, 0);
        stA[nc] = __builtin_amdgcn_mfma_f32_16x16x32_bf16(ak1, bq1, z, 0, 0, 0);
        f32x4 z2 = {};
        z2 = __builtin_amdgcn_mfma_f32_16x16x32_bf16(av0, bg0, z2, 0, 0, 0);
        dptA[nc] = __builtin_amdgcn_mfma_f32_16x16x32_bf16(av1, bg1, z2, 0, 0, 0);
      }
      if (i_t == jt) {   // diagonal tile: causal mask needed
        #pragma unroll
        for (int nc = 0; nc < 4; nc++)
          #pragma unroll
          for (int r = 0; r < 4; r++) {
            int jrow = j0 + band + q * 4 + r;
            int icol = i0 + nc * 16 + fr;
            float P = 0.f, ds = 0.f;
            if (icol >= jrow) {
              P = exp2f(fmaf(stA[nc][r], C2_C, -mc[nc]));
              ds = P * (dptA[nc][r] - Dc[nc]);   // SC lives in Qt
            }
            PT[band + q * 4 + r][nc * 16 + fr] = f2bu(P);   // wave-private
            dST[band + q * 4 + r][nc * 16 + fr] = f2bu(ds);
          }
      } else {           // strictly-upper tile: always unmasked
        #pragma unroll
        for (int nc = 0; nc < 4; nc++)
          #pragma unroll
          for (int r = 0; r < 4; r++) {
            float P = exp2f(fmaf(stA[nc][r], C2_C, -mc[nc]));
            float ds = P * (dptA[nc][r] - Dc[nc]);
            PT[band + q * 4 + r][nc * 16 + fr] = f2bu(P);
            dST[band + q * 4 + r][nc * 16 + fr] = f2bu(ds);
          }
      }
      bf16x8 ap0 = *(const bf16x8*)&PT[band + fr][q * 8];
      bf16x8 ap1 = *(const bf16x8*)&PT[band + fr][32 + q * 8];
      bf16x8 ad0 = *(const bf16x8*)&dST[band + fr][q * 8];
      bf16x8 ad1 = *(const bf16x8*)&dST[band + fr][32 + q * 8];
      #pragma unroll
      for (int nc = 0; nc < 4; nc++) {
        bf16x8 bg0 = *tile_at(Gts, nc * 16 + fr, q);
        bf16x8 bg1 = *tile_at(Gts, nc * 16 + fr, q + 4);
        bf16x8 bq0 = *tile_at(Qts, nc * 16 + fr, q);
        bf16x8 bq1 = *tile_at(Qts, nc * 16 + fr, q + 4);
        dvacc[nc] = __builtin_amdgcn_mfma_f32_16x16x32_bf16(ap0, bg0, dvacc[nc], 0, 0, 0);
        dvacc[nc] = __builtin_amdgcn_mfma_f32_16x16x32_bf16(ap1, bg1, dvacc[nc], 0, 0, 0);
        dkacc[nc] = __builtin_amdgcn_mfma_f32_16x16x32_bf16(ad0, bq0, dkacc[nc], 0, 0, 0);
        dkacc[nc] = __builtin_amdgcn_mfma_f32_16x16x32_bf16(ad1, bq1, dkacc[nc], 0, 0, 0);
      }
    }
    #pragma unroll
    for (int nc = 0; nc < 4; nc++)
      #pragma unroll
      for (int r = 0; r < 4; r++) {
        int jrow = j0 + band + q * 4 + r;
        size_t gi = (size_t)(b * S_LEN + jrow) * E_DIM + h * HD + nc * 16 + fr;
        GK[gi] = f2bu(dkacc[nc][r]);
        GV[gi] = f2bu(dvacc[nc][r]);
      }
  }
}

// ---------------- launch ----------------
extern "C" void kernel_launch(void* const* d_in, const int* in_sizes, int n_in,
                              void* d_out, int out_size, void* d_ws, size_t ws_size,
                              hipStream_t stream) {
  const float* T1 = (const float*)d_in[0];
  const float* Wq = (const float*)d_in[1];
  const float* Wk = (const float*)d_in[2];
  const float* Wv = (const float*)d_in[3];
  const float* Wo = (const float*)d_in[4];

  const size_t M2 = 2097152;   // 2048*1024
  const size_t M1 = 1048576;
  float* w = (float*)d_ws;
  float* Xs = w;                       // 8 MB fp32 target
  float* mS = Xs + M2;                 // 64K f32 (stores m')
  float* DvS = mS + 65536;
  ushort_t* u = (ushort_t*)(DvS + 65536);
  ushort_t* W0 = u;          ushort_t* W1 = W0 + M1;  ushort_t* W2 = W1 + M1;
  ushort_t* W3 = W2 + M1;    ushort_t* W4 = W3 + M1;  ushort_t* W5 = W4 + M1;
  ushort_t* Qb = W5 + M1;    ushort_t* Kb = Qb + M2;  ushort_t* Vb = Kb + M2;
  ushort_t* Qt = Vb + M2;    ushort_t* Kt = Qt + M2;  ushort_t* Vt = Kt + M2;
  ushort_t* Gt = Vt + M2;
  ushort_t* Gb = Gt + M2;
  ushort_t* GQb = Gb + M2;   ushort_t* GKb = GQb + M2; ushort_t* GVb = GKb + M2;
  ushort_t* X2b = GVb + M2;
  float* X2 = (float*)d_out;

  // stage-1 aliases (all overwritten before stage-2 uses the slots)
  float* Mf  = (float*)Qb;       // 4 MB
  float* M2f = (float*)Kb;       // 4 MB
  ushort_t* Mb  = Gt;            // 2 MB
  ushort_t* Nb  = Vb;            // 2 MB
  ushort_t* AtB = Qt;            // 2 MB
  ushort_t* T1b = Kt;            // 4 MB

  // iter-1 shortcut aliases (dead before their regions' stage-2 consumers)
  float* Sf  = (float*)GQb;      // 8 MB fp32 scan partials (spans GQb+GKb)
  float* tot = mS;               // 128 KB chunk totals (mS rewritten by fwd of iter 2)
  ushort_t* Sb = GVb;            // 4 MB bf16 scan result

  dim3 pgrid(16, 16);
  dim3 sgrid(16, 16);       // 1024x1024 GEMMs
  dim3 ggrid(16, 32);       // 2048x1024 GEMMs
  dim3 agrid(BH_CNT, 16);   // attention

  // ---- stage 1 (algebraic): Xs = T * Wo * (3LR·I - 3LR²·M + LR³·M²),  M = WoᵀWo ----
  k_cast<<<(M2 / 4 + 255) / 256, 256, 0, stream>>>(T1, T1b, (int)(M2 / 4));
  prep_w<<<pgrid, 256, 0, stream>>>(Wo, W0, W1);
  // M = W1·W1ᵀ  (fp32 + bf16)
  gemm_mf<4, 1><<<sgrid, 256, 0, stream>>>(W1, nullptr, nullptr, W1, nullptr, nullptr,
                                           Mf, Mb, 0.f);
  // M2 = Mb·Mbᵀ (M symmetric)
  gemm_mf<3, 1><<<sgrid, 256, 0, stream>>>(Mb, nullptr, nullptr, Mb, nullptr, nullptr,
                                           M2f, nullptr, 0.f);
  k_formN<<<(M1 + 255) / 256, 256, 0, stream>>>(Mf, M2f, Nb);
  // AtB = N·Woᵀ  (symmetric N; this is (Wo·N)ᵀ in [N,K] form)
  gemm_mf<5, 1><<<sgrid, 256, 0, stream>>>(Nb, nullptr, nullptr, W0, nullptr, nullptr,
                                           nullptr, AtB, 0.f);
  // stage-2 weights (W0/W1 free after AtB)
  prep_w<<<pgrid, 256, 0, stream>>>(Wq, W0, W3);
  prep_w<<<pgrid, 256, 0, stream>>>(Wk, W1, W4);
  prep_w<<<pgrid, 256, 0, stream>>>(Wv, W2, W5);
  // Xs = T1b·AtBᵀ (fp32)
  gemm_mf<3, 1><<<ggrid, 256, 0, stream>>>(T1b, nullptr, nullptr, AtB, nullptr, nullptr,
                                           Xs, nullptr, 0.f);

  // ---- stage 2, iteration 1 (closed form): x=0 => Q=K=V=0, P exactly causal-uniform,
  //      dQ=dK=0, dV = P0^T(-Xs); x1 = LR * (P0^T Xs) * Wv via fp32 suffix scan + one GEMM ----
  k_scan1<<<dim3(E_DIM / 256, 2, 16), 256, 0, stream>>>(Xs, Sf, tot);
  k_scan2<<<dim3(E_DIM / 256, 2, 16), 256, 0, stream>>>(Sf, tot, Sb);
  gemm_mf<6, 1><<<ggrid, 256, 0, stream>>>(Sb, nullptr, nullptr, W5, nullptr, nullptr,
                                           X2, X2b, LR_C);

  // ---- stage 2, iterations 2..3 (full PC gradient) ----
  for (int t = 1; t < 3; t++) {
    gemm_qkv<<<ggrid, 256, 0, stream>>>(X2b, W0, W1, W2,
                                        Qb, Kb, Vb, Qt, Kt, Vt);
    fwd_fused<<<agrid, 256, 0, stream>>>(Qb, Kb, Vt, Xs, mS, Gb, Gt, DvS);
    bwd_fused<<<agrid, 256, 0, stream>>>(Qb, Kb, Vb, Gb, Qt, Kt, Gt, mS, DvS,
                                         GQb, GKb, GVb);
    gemm_acc<<<ggrid, 256, 0, stream>>>(GQb, GKb, GVb, W3, W4, W5,
                                        X2, X2b, -LR_C);
  }
}

// Round 11
// 389.637 us; speedup vs baseline: 1.1442x; 1.0464x over previous
//
#include <hip/hip_runtime.h>
#include <hip/hip_bf16.h>
#include <math.h>

// Problem constants (B=2, S=1024, E=1024, H=16, D=64)
#define S_LEN 1024
#define E_DIM 1024
#define NH 16
#define HD 64
#define M_ROWS 2048   // B*S
#define BH_CNT 32     // B*NH

static constexpr float LR_C = 0.01f;
static constexpr float SC_C = 0.125f;                // 1/sqrt(64)
static constexpr float C2_C = 0.125f * 1.44269504f;  // SC * log2(e): log2-domain softmax

typedef unsigned short ushort_t;
typedef __attribute__((ext_vector_type(8))) __bf16 bf16x8;
typedef __attribute__((ext_vector_type(4))) float f32x4;

static __device__ inline ushort_t f2bu(float f) {
  __hip_bfloat16 h = __float2bfloat16(f);
  return *(ushort_t*)&h;
}
static __device__ inline bf16x8 ldg8(const ushort_t* p) { return *(const bf16x8*)p; }

// async global->LDS, 16B per lane; LDS dest = wave-uniform base + lane*16
static __device__ inline void async_cp16(const ushort_t* g, __bf16* lds_wave_base) {
  __builtin_amdgcn_global_load_lds((const __attribute__((address_space(1))) void*)g,
                                   (__attribute__((address_space(3))) void*)lds_wave_base,
                                   16, 0, 0);
}

// ---- 64x64 bf16 tile in unpadded LDS with per-row chunk rotation ----
// element (r,c) lives at ushort offset r*64 + (((c>>3)+r)&7)*8 + (c&7).
// Staged via global_load_lds: wave w, issue t fills slab s=w*2+t (rows 8s..8s+7, 1 KB,
// wave-uniform dest); lane l supplies source chunk c=((l&7)-(l>>3))&7 of row 8s+(l>>3)
// (pre-rotated SOURCE address = m173's swizzle-the-global-side pattern).
static __device__ inline void stage_tile(const ushort_t* src, size_t src_stride,
                                         ushort_t* lds, int lane, int wave) {
  int rl = lane >> 3;
  int c = ((lane & 7) - rl) & 7;
  #pragma unroll
  for (int t = 0; t < 2; t++) {
    int s = wave * 2 + t;
    async_cp16(src + (size_t)(s * 8 + rl) * src_stride + c * 8,
               (__bf16*)(lds + s * 512));
  }
}
static __device__ inline const bf16x8* tile_at(const ushort_t* lds, int r, int cchunk) {
  return (const bf16x8*)(lds + r * 64 + (((cchunk + r) & 7) * 8));
}

// ---------------- merged weight prep: bf16 cast + bf16 transpose, 4 matrices, z-select ----
__global__ __launch_bounds__(256) void prep_w4(
    const float* __restrict__ Wo, const float* __restrict__ Wq,
    const float* __restrict__ Wk, const float* __restrict__ Wv,
    ushort_t* __restrict__ o0, ushort_t* __restrict__ t0,
    ushort_t* __restrict__ o1, ushort_t* __restrict__ t1,
    ushort_t* __restrict__ o2, ushort_t* __restrict__ t2,
    ushort_t* __restrict__ o3, ushort_t* __restrict__ t3) {
  __shared__ float ts[64][65];
  int z = blockIdx.z;
  const float* W = (z == 0) ? Wo : (z == 1) ? Wq : (z == 2) ? Wk : Wv;
  ushort_t* Wb  = (z == 0) ? o0 : (z == 1) ? o1 : (z == 2) ? o2 : o3;
  ushort_t* WTb = (z == 0) ? t0 : (z == 1) ? t1 : (z == 2) ? t2 : t3;
  int bx = blockIdx.x * 64, by = blockIdx.y * 64;
  int t = threadIdx.x;
  int rr = t >> 6, cc = t & 63;
  #pragma unroll
  for (int p = 0; p < 16; p++) {
    int r = p * 4 + rr;
    float v = W[(size_t)(by + r) * E_DIM + bx + cc];
    ts[r][cc] = v;
    Wb[(size_t)(by + r) * E_DIM + bx + cc] = f2bu(v);
  }
  __syncthreads();
  #pragma unroll
  for (int p = 0; p < 16; p++) {
    int r = p * 4 + rr;
    WTb[(size_t)(bx + r) * E_DIM + by + cc] = f2bu(ts[cc][r]);
  }
}

// ---------------- fp32 -> bf16 cast (float4-wide) ----------------
__global__ __launch_bounds__(256) void k_cast(const float* __restrict__ in,
                                              ushort_t* __restrict__ out, int n4) {
  int i = blockIdx.x * 256 + threadIdx.x;
  if (i < n4) {
    float4 v = ((const float4*)in)[i];
    ushort_t p[4] = {f2bu(v.x), f2bu(v.y), f2bu(v.z), f2bu(v.w)};
    *(uint2*)(out + (size_t)i * 4) = *(uint2*)p;
  }
}

// ---------------- iter-1 shortcut: suffix scan S[j] = sum_{i>=j} Xs[i]/(i+1) ----------------
__global__ __launch_bounds__(256) void k_scan1(const float* __restrict__ Xs,
                                               float* __restrict__ Sf,
                                               float* __restrict__ tot) {
  int e = blockIdx.x * 256 + threadIdx.x;  // column 0..1023
  int b = blockIdx.y;                      // batch
  int z = blockIdx.z;                      // chunk 0..15 (64 rows each)
  float acc = 0.f;
  for (int i = z * 64 + 63; i >= z * 64; i--) {
    size_t idx = ((size_t)b * S_LEN + i) * E_DIM + e;
    acc = fmaf(Xs[idx], 1.0f / (float)(i + 1), acc);
    Sf[idx] = acc;
  }
  tot[((size_t)b * 16 + z) * E_DIM + e] = acc;
}

__global__ __launch_bounds__(256) void k_scan2(const float* __restrict__ Sf,
                                               const float* __restrict__ tot,
                                               ushort_t* __restrict__ Sb) {
  int e = blockIdx.x * 256 + threadIdx.x;
  int b = blockIdx.y;
  int z = blockIdx.z;
  float off = 0.f;
  for (int c = z + 1; c < 16; c++) off += tot[((size_t)b * 16 + c) * E_DIM + e];
  for (int i = z * 64; i < z * 64 + 64; i++) {
    size_t idx = ((size_t)b * S_LEN + i) * E_DIM + e;
    Sb[idx] = f2bu(Sf[idx] + off);
  }
}

// ---------------- bf16 MFMA GEMM, 64x64 tile, BK=64, DOUBLE-BUFFERED async staging -------
// One barrier per K-step (prefetch-ahead; loads have a full compute phase to land).
// k ascending, h0 then h1 — accumulation order identical to before -> bit-identical.
// MODE 3: Cf = acc (fp32 only)
// MODE 4: Cf = acc and Cb0 = bf16(acc)
// MODE 5: Cb0 = bf16(acc)
// MODE 6: Cf = alpha*acc (overwrite) and Cb0 = bf16(alpha*acc)
// MODE 7: Cb0 = bf16(-3LR^2*Cf[idx] + LR^3*acc + (diag? 3LR)) — fused formN epilogue
template <int MODE>
__global__ __launch_bounds__(256) void gemm_mf(
    const ushort_t* __restrict__ A, const ushort_t* __restrict__ B,
    float* __restrict__ Cf, ushort_t* __restrict__ Cb0, float alpha) {
  const int K = 1024;
  __shared__ __bf16 As[2][2][64][32];
  __shared__ __bf16 Bs[2][2][64][32];
  int tid = threadIdx.x;
  int m0 = blockIdx.y * 64, n0 = blockIdx.x * 64;

  int lane = tid & 63, wave = tid >> 6;
  int wrow = wave >> 1, wcol = wave & 1;
  int fr = lane & 15, q = lane >> 4;

  int srow = wave * 16 + (lane >> 2);
  int scg = ((lane & 3) + (srow >> 1)) & 3;
  int scol = scg * 8;

  int rA0 = wrow * 32 + fr, rA1r = rA0 + 16;
  int rB0 = wcol * 32 + fr, rB1r = rB0 + 16;
  int cA0 = ((q - (rA0 >> 1)) & 3) * 8;
  int cA1 = ((q - (rA1r >> 1)) & 3) * 8;
  int cB0 = ((q - (rB0 >> 1)) & 3) * 8;
  int cB1 = ((q - (rB1r >> 1)) & 3) * 8;

  const ushort_t* ga = A + (size_t)(m0 + srow) * K + scol;
  const ushort_t* gb = B + (size_t)(n0 + srow) * K + scol;

  f32x4 acc[2][2] = {};

  // prologue: k0=0 into buffer 0
  async_cp16(ga,      &As[0][0][wave * 16][0]);
  async_cp16(ga + 32, &As[0][1][wave * 16][0]);
  async_cp16(gb,      &Bs[0][0][wave * 16][0]);
  async_cp16(gb + 32, &Bs[0][1][wave * 16][0]);

  #pragma unroll 1
  for (int k0 = 0; k0 < K; k0 += 64) {
    int cur = (k0 >> 6) & 1;
    __syncthreads();   // buf cur staged; prior reads of buf cur^1 done
    if (k0 + 64 < K) {
      int nxt = cur ^ 1;
      async_cp16(ga + k0 + 64, &As[nxt][0][wave * 16][0]);
      async_cp16(ga + k0 + 96, &As[nxt][1][wave * 16][0]);
      async_cp16(gb + k0 + 64, &Bs[nxt][0][wave * 16][0]);
      async_cp16(gb + k0 + 96, &Bs[nxt][1][wave * 16][0]);
    }
    bf16x8 a00 = *(const bf16x8*)&As[cur][0][rA0][cA0];
    bf16x8 a01 = *(const bf16x8*)&As[cur][1][rA0][cA0];
    bf16x8 a10 = *(const bf16x8*)&As[cur][0][rA1r][cA1];
    bf16x8 a11 = *(const bf16x8*)&As[cur][1][rA1r][cA1];
    bf16x8 b00 = *(const bf16x8*)&Bs[cur][0][rB0][cB0];
    bf16x8 b01 = *(const bf16x8*)&Bs[cur][1][rB0][cB0];
    bf16x8 b10 = *(const bf16x8*)&Bs[cur][0][rB1r][cB1];
    bf16x8 b11 = *(const bf16x8*)&Bs[cur][1][rB1r][cB1];
    acc[0][0] = __builtin_amdgcn_mfma_f32_16x16x32_bf16(a00, b00, acc[0][0], 0, 0, 0);
    acc[0][1] = __builtin_amdgcn_mfma_f32_16x16x32_bf16(a00, b10, acc[0][1], 0, 0, 0);
    acc[1][0] = __builtin_amdgcn_mfma_f32_16x16x32_bf16(a10, b00, acc[1][0], 0, 0, 0);
    acc[1][1] = __builtin_amdgcn_mfma_f32_16x16x32_bf16(a10, b10, acc[1][1], 0, 0, 0);
    acc[0][0] = __builtin_amdgcn_mfma_f32_16x16x32_bf16(a01, b01, acc[0][0], 0, 0, 0);
    acc[0][1] = __builtin_amdgcn_mfma_f32_16x16x32_bf16(a01, b11, acc[0][1], 0, 0, 0);
    acc[1][0] = __builtin_amdgcn_mfma_f32_16x16x32_bf16(a11, b01, acc[1][0], 0, 0, 0);
    acc[1][1] = __builtin_amdgcn_mfma_f32_16x16x32_bf16(a11, b11, acc[1][1], 0, 0, 0);
  }

  // C/D layout: col = lane&15, row = (lane>>4)*4 + reg
  #pragma unroll
  for (int mi = 0; mi < 2; mi++)
    #pragma unroll
    for (int ni = 0; ni < 2; ni++) {
      int col = n0 + wcol * 32 + ni * 16 + fr;
      int row0 = m0 + wrow * 32 + mi * 16 + q * 4;
      #pragma unroll
      for (int r = 0; r < 4; r++) {
        size_t idx = (size_t)(row0 + r) * E_DIM + col;
        float v = acc[mi][ni][r];
        if (MODE == 3) {
          Cf[idx] = v;
        } else if (MODE == 4) {
          Cf[idx] = v;
          Cb0[idx] = f2bu(v);
        } else if (MODE == 6) {
          float nv = alpha * v;
          Cf[idx] = nv;
          Cb0[idx] = f2bu(nv);
        } else if (MODE == 7) {
          float nv = -3.f * LR_C * LR_C * Cf[idx] + LR_C * LR_C * LR_C * v;
          if (row0 + r == col) nv += 3.f * LR_C;
          Cb0[idx] = f2bu(nv);
        } else {  // MODE 5
          Cb0[idx] = f2bu(v);
        }
      }
    }
}

// ---------------- merged QKV GEMM: one A-stage feeds 3 B-matrices, double-buffered ------
__global__ __launch_bounds__(256) void gemm_qkv(
    const ushort_t* __restrict__ A,
    const ushort_t* __restrict__ B0, const ushort_t* __restrict__ B1, const ushort_t* __restrict__ B2,
    ushort_t* __restrict__ Cb0, ushort_t* __restrict__ Cb1, ushort_t* __restrict__ Cb2,
    ushort_t* __restrict__ Ct0, ushort_t* __restrict__ Ct1, ushort_t* __restrict__ Ct2) {
  const int K = 1024;
  __shared__ __bf16 As[2][2][64][32];
  __shared__ __bf16 Bs[2][3][2][64][32];
  int tid = threadIdx.x;
  int m0 = blockIdx.y * 64, n0 = blockIdx.x * 64;

  int lane = tid & 63, wave = tid >> 6;
  int wrow = wave >> 1, wcol = wave & 1;
  int fr = lane & 15, q = lane >> 4;

  int srow = wave * 16 + (lane >> 2);
  int scg = ((lane & 3) + (srow >> 1)) & 3;
  int scol = scg * 8;

  int rA0 = wrow * 32 + fr, rA1r = rA0 + 16;
  int rB0 = wcol * 32 + fr, rB1r = rB0 + 16;
  int cA0 = ((q - (rA0 >> 1)) & 3) * 8;
  int cA1 = ((q - (rA1r >> 1)) & 3) * 8;
  int cB0 = ((q - (rB0 >> 1)) & 3) * 8;
  int cB1 = ((q - (rB1r >> 1)) & 3) * 8;

  const ushort_t* ga = A + (size_t)(m0 + srow) * K + scol;
  const ushort_t* gb0 = B0 + (size_t)(n0 + srow) * K + scol;
  const ushort_t* gb1 = B1 + (size_t)(n0 + srow) * K + scol;
  const ushort_t* gb2 = B2 + (size_t)(n0 + srow) * K + scol;

  f32x4 acc[3][2][2] = {};

  // prologue: k0=0 into buffer 0
  async_cp16(ga,       &As[0][0][wave * 16][0]);
  async_cp16(ga + 32,  &As[0][1][wave * 16][0]);
  async_cp16(gb0,      &Bs[0][0][0][wave * 16][0]);
  async_cp16(gb0 + 32, &Bs[0][0][1][wave * 16][0]);
  async_cp16(gb1,      &Bs[0][1][0][wave * 16][0]);
  async_cp16(gb1 + 32, &Bs[0][1][1][wave * 16][0]);
  async_cp16(gb2,      &Bs[0][2][0][wave * 16][0]);
  async_cp16(gb2 + 32, &Bs[0][2][1][wave * 16][0]);

  #pragma unroll 1
  for (int k0 = 0; k0 < K; k0 += 64) {
    int cur = (k0 >> 6) & 1;
    __syncthreads();
    if (k0 + 64 < K) {
      int nxt = cur ^ 1;
      async_cp16(ga + k0 + 64,  &As[nxt][0][wave * 16][0]);
      async_cp16(ga + k0 + 96,  &As[nxt][1][wave * 16][0]);
      async_cp16(gb0 + k0 + 64, &Bs[nxt][0][0][wave * 16][0]);
      async_cp16(gb0 + k0 + 96, &Bs[nxt][0][1][wave * 16][0]);
      async_cp16(gb1 + k0 + 64, &Bs[nxt][1][0][wave * 16][0]);
      async_cp16(gb1 + k0 + 96, &Bs[nxt][1][1][wave * 16][0]);
      async_cp16(gb2 + k0 + 64, &Bs[nxt][2][0][wave * 16][0]);
      async_cp16(gb2 + k0 + 96, &Bs[nxt][2][1][wave * 16][0]);
    }
    bf16x8 a00 = *(const bf16x8*)&As[cur][0][rA0][cA0];
    bf16x8 a01 = *(const bf16x8*)&As[cur][1][rA0][cA0];
    bf16x8 a10 = *(const bf16x8*)&As[cur][0][rA1r][cA1];
    bf16x8 a11 = *(const bf16x8*)&As[cur][1][rA1r][cA1];
    #pragma unroll
    for (int z = 0; z < 3; z++) {
      bf16x8 b00 = *(const bf16x8*)&Bs[cur][z][0][rB0][cB0];
      bf16x8 b01 = *(const bf16x8*)&Bs[cur][z][1][rB0][cB0];
      bf16x8 b10 = *(const bf16x8*)&Bs[cur][z][0][rB1r][cB1];
      bf16x8 b11 = *(const bf16x8*)&Bs[cur][z][1][rB1r][cB1];
      acc[z][0][0] = __builtin_amdgcn_mfma_f32_16x16x32_bf16(a00, b00, acc[z][0][0], 0, 0, 0);
      acc[z][0][1] = __builtin_amdgcn_mfma_f32_16x16x32_bf16(a00, b10, acc[z][0][1], 0, 0, 0);
      acc[z][1][0] = __builtin_amdgcn_mfma_f32_16x16x32_bf16(a10, b00, acc[z][1][0], 0, 0, 0);
      acc[z][1][1] = __builtin_amdgcn_mfma_f32_16x16x32_bf16(a10, b10, acc[z][1][1], 0, 0, 0);
      acc[z][0][0] = __builtin_amdgcn_mfma_f32_16x16x32_bf16(a01, b01, acc[z][0][0], 0, 0, 0);
      acc[z][0][1] = __builtin_amdgcn_mfma_f32_16x16x32_bf16(a01, b11, acc[z][0][1], 0, 0, 0);
      acc[z][1][0] = __builtin_amdgcn_mfma_f32_16x16x32_bf16(a11, b01, acc[z][1][0], 0, 0, 0);
      acc[z][1][1] = __builtin_amdgcn_mfma_f32_16x16x32_bf16(a11, b11, acc[z][1][1], 0, 0, 0);
    }
  }

  // C/D layout: col = lane&15, row = (lane>>4)*4 + reg
  #pragma unroll
  for (int z = 0; z < 3; z++) {
    ushort_t* Cbz = (z == 0) ? Cb0 : (z == 1) ? Cb1 : Cb2;
    ushort_t* Ctz = (z == 0) ? Ct0 : (z == 1) ? Ct1 : Ct2;
    float tsc = (z == 2) ? 1.0f : SC_C;   // Qt/Kt carry the 1/sqrt(d) factor
    #pragma unroll
    for (int mi = 0; mi < 2; mi++)
      #pragma unroll
      for (int ni = 0; ni < 2; ni++) {
        int col = n0 + wcol * 32 + ni * 16 + fr;
        int row0 = m0 + wrow * 32 + mi * 16 + q * 4;
        ushort_t pk[4];
        #pragma unroll
        for (int r = 0; r < 4; r++) {
          size_t idx = (size_t)(row0 + r) * E_DIM + col;
          float v = acc[z][mi][ni][r];
          Cbz[idx] = f2bu(v);
          pk[r] = f2bu(v * tsc);
        }
        int hh = col >> 6, dd = col & 63;
        int bb = row0 >> 10, ss = row0 & 1023;
        *(uint2*)(Ctz + ((size_t)((bb * NH + hh) * HD + dd)) * S_LEN + ss) = *(uint2*)pk;
      }
  }
}

// ---------------- merged accumulation GEMM: X2 += alpha * sum_s(As·Bs^T) ----------------
__global__ __launch_bounds__(256) void gemm_acc(
    const ushort_t* __restrict__ A0, const ushort_t* __restrict__ A1, const ushort_t* __restrict__ A2,
    const ushort_t* __restrict__ B0, const ushort_t* __restrict__ B1, const ushort_t* __restrict__ B2,
    float* __restrict__ Cf, ushort_t* __restrict__ Cb, float alpha) {
  const int K = 1024;
  __shared__ __bf16 As[3][2][64][32];
  __shared__ __bf16 Bs[3][2][64][32];
  int tid = threadIdx.x;
  int m0 = blockIdx.y * 64, n0 = blockIdx.x * 64;

  int lane = tid & 63, wave = tid >> 6;
  int wrow = wave >> 1, wcol = wave & 1;
  int fr = lane & 15, q = lane >> 4;

  int srow = wave * 16 + (lane >> 2);
  int scg = ((lane & 3) + (srow >> 1)) & 3;
  int scol = scg * 8;

  int rA0 = wrow * 32 + fr, rA1r = rA0 + 16;
  int rB0 = wcol * 32 + fr, rB1r = rB0 + 16;
  int cA0 = ((q - (rA0 >> 1)) & 3) * 8;
  int cA1 = ((q - (rA1r >> 1)) & 3) * 8;
  int cB0 = ((q - (rB0 >> 1)) & 3) * 8;
  int cB1 = ((q - (rB1r >> 1)) & 3) * 8;

  f32x4 acc[3][2][2] = {};

  const ushort_t* ga0 = A0 + (size_t)(m0 + srow) * K + scol;
  const ushort_t* ga1 = A1 + (size_t)(m0 + srow) * K + scol;
  const ushort_t* ga2 = A2 + (size_t)(m0 + srow) * K + scol;
  const ushort_t* gb0 = B0 + (size_t)(n0 + srow) * K + scol;
  const ushort_t* gb1 = B1 + (size_t)(n0 + srow) * K + scol;
  const ushort_t* gb2 = B2 + (size_t)(n0 + srow) * K + scol;

  #pragma unroll 1
  for (int k0 = 0; k0 < K; k0 += 64) {
    __syncthreads();
    async_cp16(ga0 + k0,      &As[0][0][wave * 16][0]);
    async_cp16(ga0 + k0 + 32, &As[0][1][wave * 16][0]);
    async_cp16(ga1 + k0,      &As[1][0][wave * 16][0]);
    async_cp16(ga1 + k0 + 32, &As[1][1][wave * 16][0]);
    async_cp16(ga2 + k0,      &As[2][0][wave * 16][0]);
    async_cp16(ga2 + k0 + 32, &As[2][1][wave * 16][0]);
    async_cp16(gb0 + k0,      &Bs[0][0][wave * 16][0]);
    async_cp16(gb0 + k0 + 32, &Bs[0][1][wave * 16][0]);
    async_cp16(gb1 + k0,      &Bs[1][0][wave * 16][0]);
    async_cp16(gb1 + k0 + 32, &Bs[1][1][wave * 16][0]);
    async_cp16(gb2 + k0,      &Bs[2][0][wave * 16][0]);
    async_cp16(gb2 + k0 + 32, &Bs[2][1][wave * 16][0]);
    __syncthreads();
    #pragma unroll
    for (int z = 0; z < 3; z++) {
      bf16x8 a00 = *(const bf16x8*)&As[z][0][rA0][cA0];
      bf16x8 a01 = *(const bf16x8*)&As[z][1][rA0][cA0];
      bf16x8 a10 = *(const bf16x8*)&As[z][0][rA1r][cA1];
      bf16x8 a11 = *(const bf16x8*)&As[z][1][rA1r][cA1];
      bf16x8 b00 = *(const bf16x8*)&Bs[z][0][rB0][cB0];
      bf16x8 b01 = *(const bf16x8*)&Bs[z][1][rB0][cB0];
      bf16x8 b10 = *(const bf16x8*)&Bs[z][0][rB1r][cB1];
      bf16x8 b11 = *(const bf16x8*)&Bs[z][1][rB1r][cB1];
      acc[z][0][0] = __builtin_amdgcn_mfma_f32_16x16x32_bf16(a00, b00, acc[z][0][0], 0, 0, 0);
      acc[z][0][1] = __builtin_amdgcn_mfma_f32_16x16x32_bf16(a00, b10, acc[z][0][1], 0, 0, 0);
      acc[z][1][0] = __builtin_amdgcn_mfma_f32_16x16x32_bf16(a10, b00, acc[z][1][0], 0, 0, 0);
      acc[z][1][1] = __builtin_amdgcn_mfma_f32_16x16x32_bf16(a10, b10, acc[z][1][1], 0, 0, 0);
      acc[z][0][0] = __builtin_amdgcn_mfma_f32_16x16x32_bf16(a01, b01, acc[z][0][0], 0, 0, 0);
      acc[z][0][1] = __builtin_amdgcn_mfma_f32_16x16x32_bf16(a01, b11, acc[z][0][1], 0, 0, 0);
      acc[z][1][0] = __builtin_amdgcn_mfma_f32_16x16x32_bf16(a11, b01, acc[z][1][0], 0, 0, 0);
      acc[z][1][1] = __builtin_amdgcn_mfma_f32_16x16x32_bf16(a11, b11, acc[z][1][1], 0, 0, 0);
    }
  }

  // C/D layout: col = lane&15, row = (lane>>4)*4 + reg
  #pragma unroll
  for (int mi = 0; mi < 2; mi++)
    #pragma unroll
    for (int ni = 0; ni < 2; ni++) {
      int col = n0 + wcol * 32 + ni * 16 + fr;
      int row0 = m0 + wrow * 32 + mi * 16 + q * 4;
      #pragma unroll
      for (int r = 0; r < 4; r++) {
        size_t idx = (size_t)(row0 + r) * E_DIM + col;
        float v = (acc[0][mi][ni][r] + acc[1][mi][ni][r]) + acc[2][mi][ni][r];
        float nv = Cf[idx] + alpha * v;
        Cf[idx] = nv;
        Cb[idx] = f2bu(nv);
      }
    }
}

// ====================== MFMA attention, LDS-staged ======================

// ---- fused fwd: single-pass flash, log2-domain online softmax; emits m' = m + log2(l),
//      g=O-Xs (bf16 + transposed), Dv. Double-buffered K/V staging (1 barrier/tile);
//      causal mask only on the DIAGONAL tile; l deferred to one epilogue reduce. ----
__global__ __launch_bounds__(256) void fwd_fused(const ushort_t* __restrict__ Qg,
                                                 const ushort_t* __restrict__ Kg,
                                                 const ushort_t* __restrict__ Vt,
                                                 const float* __restrict__ Xs,
                                                 float* __restrict__ mbuf,
                                                 ushort_t* __restrict__ Gb,
                                                 ushort_t* __restrict__ Gt,
                                                 float* __restrict__ Dv) {
  int bh = blockIdx.x, y = blockIdx.y;
  int it = (y < 8) ? (15 - y) : (y - 8);
  int b = bh >> 4, h = bh & 15;
  int tid = threadIdx.x, lane = tid & 63, wv = tid >> 6;
  int fr = lane & 15, q = lane >> 4;
  int i0 = it * 64, band = wv * 16;
  __shared__ ushort_t Ksb[2][4096];  // [j][d] chunk-rotated, double-buffered
  __shared__ ushort_t Vsb[2][4096];  // [d][j] chunk-rotated, double-buffered
  __shared__ ushort_t Ps[64][72];    // [i][j] wave-private bands (lane-written)

  const ushort_t* Kbase = Kg + (size_t)(b * S_LEN) * E_DIM + h * HD;
  const ushort_t* Vbase = Vt + (size_t)(bh * HD) * S_LEN;

  const ushort_t* Qrow = Qg + (size_t)(b * S_LEN + i0 + band + fr) * E_DIM + h * HD;
  bf16x8 aq0 = ldg8(Qrow + q * 8);
  bf16x8 aq1 = ldg8(Qrow + 32 + q * 8);

  float m[4], l[4];
  #pragma unroll
  for (int r = 0; r < 4; r++) { m[r] = -1e30f; l[r] = 0.f; }
  f32x4 oacc[4] = {};

  // prologue: stage tile jt=0 into buffer 0
  stage_tile(Kbase, E_DIM, Ksb[0], lane, wv);
  stage_tile(Vbase, S_LEN, Vsb[0], lane, wv);

  #pragma unroll 1
  for (int jt = 0; jt <= it; jt++) {
    int j0 = jt * 64;
    int cur = jt & 1;
    __syncthreads();   // vmcnt drain: tile jt staged; all reads of buf cur^1 done
    if (jt < it) {
      int j0n = j0 + 64;
      stage_tile(Kbase + (size_t)j0n * E_DIM, E_DIM, Ksb[cur ^ 1], lane, wv);
      stage_tile(Vbase + j0n, S_LEN, Vsb[cur ^ 1], lane, wv);
    }
    const ushort_t* Ks = Ksb[cur];
    const ushort_t* Vs = Vsb[cur];
    f32x4 sA[4];
    #pragma unroll
    for (int nc = 0; nc < 4; nc++) {
      bf16x8 bk0 = *tile_at(Ks, nc * 16 + fr, q);
      bf16x8 bk1 = *tile_at(Ks, nc * 16 + fr, q + 4);
      f32x4 z = {};
      z = __builtin_amdgcn_mfma_f32_16x16x32_bf16(aq0, bk0, z, 0, 0, 0);
      sA[nc] = __builtin_amdgcn_mfma_f32_16x16x32_bf16(aq1, bk1, z, 0, 0, 0);
    }
    float sv[4][4];
    if (jt == it) {   // diagonal tile: causal mask needed
      #pragma unroll
      for (int nc = 0; nc < 4; nc++)
        #pragma unroll
        for (int r = 0; r < 4; r++) {
          int row = i0 + band + q * 4 + r;
          int col = j0 + nc * 16 + fr;
          sv[nc][r] = (col <= row) ? sA[nc][r] * C2_C : -1e30f;  // log2 domain
        }
    } else {          // strictly-lower tile: always unmasked
      #pragma unroll
      for (int nc = 0; nc < 4; nc++)
        #pragma unroll
        for (int r = 0; r < 4; r++)
          sv[nc][r] = sA[nc][r] * C2_C;
    }
    #pragma unroll
    for (int r = 0; r < 4; r++) {
      float mx = fmaxf(fmaxf(sv[0][r], sv[1][r]), fmaxf(sv[2][r], sv[3][r]));
      #pragma unroll
      for (int off = 1; off < 16; off <<= 1) mx = fmaxf(mx, __shfl_xor(mx, off, 64));
      float mn = fmaxf(m[r], mx);
      float alpha = exp2f(m[r] - mn);
      float ps = 0.f;
      #pragma unroll
      for (int nc = 0; nc < 4; nc++) {
        float p = exp2f(sv[nc][r] - mn);
        Ps[band + q * 4 + r][nc * 16 + fr] = f2bu(p);
        ps += p;
      }
      l[r] = l[r] * alpha + ps;   // per-lane partial (this lane's 4 columns)
      m[r] = mn;
      #pragma unroll
      for (int nc = 0; nc < 4; nc++) oacc[nc][r] *= alpha;
    }
    bf16x8 ap0 = *(const bf16x8*)&Ps[band + fr][q * 8];
    bf16x8 ap1 = *(const bf16x8*)&Ps[band + fr][32 + q * 8];
    #pragma unroll
    for (int nc = 0; nc < 4; nc++) {
      bf16x8 bv0 = *tile_at(Vs, nc * 16 + fr, q);
      bf16x8 bv1 = *tile_at(Vs, nc * 16 + fr, q + 4);
      oacc[nc] = __builtin_amdgcn_mfma_f32_16x16x32_bf16(ap0, bv0, oacc[nc], 0, 0, 0);
      oacc[nc] = __builtin_amdgcn_mfma_f32_16x16x32_bf16(ap1, bv1, oacc[nc], 0, 0, 0);
    }
  }
  // epilogue: finish the deferred l reduction
  #pragma unroll
  for (int r = 0; r < 4; r++) {
    #pragma unroll
    for (int off = 1; off < 16; off <<= 1) l[r] += __shfl_xor(l[r], off, 64);
  }
  // g = O - Xs (bf16 normal + transposed), Dv partials
  float linv[4];
  #pragma unroll
  for (int r = 0; r < 4; r++) linv[r] = 1.0f / l[r];
  float dpart[4] = {};
  #pragma unroll
  for (int nc = 0; nc < 4; nc++) {
    ushort_t pg[4];
    #pragma unroll
    for (int r = 0; r < 4; r++) {
      int row = i0 + band + q * 4 + r;
      size_t gi = (size_t)(b * S_LEN + row) * E_DIM + h * HD + nc * 16 + fr;
      float o = oacc[nc][r] * linv[r];
      float g = o - Xs[gi];
      ushort_t bu = f2bu(g);
      Gb[gi] = bu;
      pg[r] = bu;
      dpart[r] += g * o;
    }
    int d = nc * 16 + fr;
    int s0 = i0 + band + q * 4;
    *(uint2*)(Gt + ((size_t)bh * HD + d) * S_LEN + s0) = *(uint2*)pg;
  }
  #pragma unroll
  for (int r = 0; r < 4; r++) {
    #pragma unroll
    for (int off = 1; off < 16; off <<= 1) dpart[r] += __shfl_xor(dpart[r], off, 64);
  }
  if (fr == 0) {
    #pragma unroll
    for (int r = 0; r < 4; r++) {
      size_t sid = (size_t)bh * S_LEN + i0 + band + q * 4 + r;
      mbuf[sid] = m[r] + log2f(l[r]);   // m' folds 1/l into the exponent
      Dv[sid] = dpart[r];
    }
  }
}

// ---- merged backward: block (bh, y): dq for i-tile y then dk/dv for j-tile y
//      (17 units/block, perfect balance; splitting costs 5.5x HBM — round 3).
//      Round-7 structure (single-buffered staging, dual PT/dST); causal mask only
//      on the DIAGONAL tile. ----
__global__ __launch_bounds__(256) void bwd_fused(const ushort_t* __restrict__ Qg,
                                                 const ushort_t* __restrict__ Kg,
                                                 const ushort_t* __restrict__ Vg,
                                                 const ushort_t* __restrict__ Gg,
                                                 const ushort_t* __restrict__ Qt,
                                                 const ushort_t* __restrict__ Kt,
                                                 const ushort_t* __restrict__ Gt,
                                                 const float* __restrict__ mbuf,
                                                 const float* __restrict__ Dv,
                                                 ushort_t* __restrict__ GQ,
                                                 ushort_t* __restrict__ GK,
                                                 ushort_t* __restrict__ GV) {
  int bh = blockIdx.x, y = blockIdx.y;
  int b = bh >> 4, h = bh & 15;
  int tid = threadIdx.x, lane = tid & 63, wv = tid >> 6;
  int fr = lane & 15, q = lane >> 4;
  int band = wv * 16;
  __shared__ ushort_t tA[4][4096];    // staged tiles (chunk-rotated, global_load_lds)
  __shared__ ushort_t tP[2][64][72];  // lane-written P/dS (padded)

  // ================= phase A: dq for i-tile y =================
  {
    ushort_t* Ks = tA[0];           // [j][d]
    ushort_t* Vs = tA[1];           // [j][d]
    ushort_t* Ts = tA[2];           // [d][j] Kt (pre-scaled by SC)
    ushort_t (*dSs)[72] = tP[0];
    int it = y, i0 = it * 64;

    const ushort_t* KbaseA = Kg + (size_t)(b * S_LEN) * E_DIM + h * HD;
    const ushort_t* VbaseA = Vg + (size_t)(b * S_LEN) * E_DIM + h * HD;
    const ushort_t* TbaseA = Kt + (size_t)(bh * HD) * S_LEN;

    const ushort_t* Qrow = Qg + (size_t)(b * S_LEN + i0 + band + fr) * E_DIM + h * HD;
    const ushort_t* Grow = Gg + (size_t)(b * S_LEN + i0 + band + fr) * E_DIM + h * HD;
    bf16x8 aq0 = ldg8(Qrow + q * 8), aq1 = ldg8(Qrow + 32 + q * 8);
    bf16x8 ag0 = ldg8(Grow + q * 8), ag1 = ldg8(Grow + 32 + q * 8);

    float mrow[4], Dr[4];
    #pragma unroll
    for (int r = 0; r < 4; r++) {
      size_t sid = (size_t)bh * S_LEN + i0 + band + q * 4 + r;
      mrow[r] = mbuf[sid]; Dr[r] = Dv[sid];
    }
    f32x4 dqacc[4] = {};

    #pragma unroll 1
    for (int jt = 0; jt <= it; jt++) {
      int j0 = jt * 64;
      __syncthreads();
      stage_tile(KbaseA + (size_t)j0 * E_DIM, E_DIM, Ks, lane, wv);
      stage_tile(VbaseA + (size_t)j0 * E_DIM, E_DIM, Vs, lane, wv);
      stage_tile(TbaseA + j0, S_LEN, Ts, lane, wv);
      __syncthreads();
      f32x4 sA[4], dpA[4];
      #pragma unroll
      for (int nc = 0; nc < 4; nc++) {
        bf16x8 bk0 = *tile_at(Ks, nc * 16 + fr, q);
        bf16x8 bk1 = *tile_at(Ks, nc * 16 + fr, q + 4);
        bf16x8 bv0 = *tile_at(Vs, nc * 16 + fr, q);
        bf16x8 bv1 = *tile_at(Vs, nc * 16 + fr, q + 4);
        f32x4 z = {};
        z = __builtin_amdgcn_mfma_f32_16x16x32_bf16(aq0, bk0, z, 0, 0, 0);
        sA[nc] = __builtin_amdgcn_mfma_f32_16x16x32_bf16(aq1, bk1, z, 0, 0, 0);
        f32x4 z2 = {};
        z2 = __builtin_amdgcn_mfma_f32_16x16x32_bf16(ag0, bv0, z2, 0, 0, 0);
        dpA[nc] = __builtin_amdgcn_mfma_f32_16x16x32_bf16(ag1, bv1, z2, 0, 0, 0);
      }
      if (jt == it) {   // diagonal tile: causal mask needed
        #pragma unroll
        for (int nc = 0; nc < 4; nc++)
          #pragma unroll
          for (int r = 0; r < 4; r++) {
            int row = i0 + band + q * 4 + r;
            int col = j0 + nc * 16 + fr;
            float ds = 0.f;
            if (col <= row) {
              float P = exp2f(fmaf(sA[nc][r], C2_C, -mrow[r]));
              ds = P * (dpA[nc][r] - Dr[r]);   // SC lives in Kt
            }
            dSs[band + q * 4 + r][nc * 16 + fr] = f2bu(ds);  // wave-private
          }
      } else {          // strictly-lower tile: always unmasked
        #pragma unroll
        for (int nc = 0; nc < 4; nc++)
          #pragma unroll
          for (int r = 0; r < 4; r++) {
            float P = exp2f(fmaf(sA[nc][r], C2_C, -mrow[r]));
            float ds = P * (dpA[nc][r] - Dr[r]);
            dSs[band + q * 4 + r][nc * 16 + fr] = f2bu(ds);
          }
      }
      bf16x8 ad0 = *(const bf16x8*)&dSs[band + fr][q * 8];
      bf16x8 ad1 = *(const bf16x8*)&dSs[band + fr][32 + q * 8];
      #pragma unroll
      for (int nc = 0; nc < 4; nc++) {
        bf16x8 bt0 = *tile_at(Ts, nc * 16 + fr, q);
        bf16x8 bt1 = *tile_at(Ts, nc * 16 + fr, q + 4);
        dqacc[nc] = __builtin_amdgcn_mfma_f32_16x16x32_bf16(ad0, bt0, dqacc[nc], 0, 0, 0);
        dqacc[nc] = __builtin_amdgcn_mfma_f32_16x16x32_bf16(ad1, bt1, dqacc[nc], 0, 0, 0);
      }
    }
    #pragma unroll
    for (int nc = 0; nc < 4; nc++)
      #pragma unroll
      for (int r = 0; r < 4; r++) {
        int row = i0 + band + q * 4 + r;
        size_t gi = (size_t)(b * S_LEN + row) * E_DIM + h * HD + nc * 16 + fr;
        GQ[gi] = f2bu(dqacc[nc][r]);
      }
  }

  // ================= phase B: dk/dv for j-tile y =================
  {
    ushort_t* Qs  = tA[0];          // [i][d]
    ushort_t* Gs  = tA[1];          // [i][d]
    ushort_t* Qts = tA[2];          // [d][i] (pre-scaled by SC)
    ushort_t* Gts = tA[3];          // [d][i]
    ushort_t (*PT)[72]  = tP[0];    // [j][i]
    ushort_t (*dST)[72] = tP[1];    // [j][i]
    int jt = y, j0 = jt * 64;

    const ushort_t* QbaseB = Qg + (size_t)(b * S_LEN) * E_DIM + h * HD;
    const ushort_t* GbaseB = Gg + (size_t)(b * S_LEN) * E_DIM + h * HD;
    const ushort_t* QtbaseB = Qt + (size_t)(bh * HD) * S_LEN;
    const ushort_t* GtbaseB = Gt + (size_t)(bh * HD) * S_LEN;

    const ushort_t* Krow = Kg + (size_t)(b * S_LEN + j0 + band + fr) * E_DIM + h * HD;
    const ushort_t* Vrow = Vg + (size_t)(b * S_LEN + j0 + band + fr) * E_DIM + h * HD;
    bf16x8 ak0 = ldg8(Krow + q * 8), ak1 = ldg8(Krow + 32 + q * 8);
    bf16x8 av0 = ldg8(Vrow + q * 8), av1 = ldg8(Vrow + 32 + q * 8);

    f32x4 dkacc[4] = {}, dvacc[4] = {};

    #pragma unroll 1
    for (int i_t = jt; i_t < 16; i_t++) {
      int i0 = i_t * 64;
      __syncthreads();
      stage_tile(QbaseB + (size_t)i0 * E_DIM, E_DIM, Qs, lane, wv);
      stage_tile(GbaseB + (size_t)i0 * E_DIM, E_DIM, Gs, lane, wv);
      stage_tile(QtbaseB + i0, S_LEN, Qts, lane, wv);
      stage_tile(GtbaseB + i0, S_LEN, Gts, lane, wv);
      __syncthreads();
      float mc[4], Dc[4];
      #pragma unroll
      for (int nc = 0; nc < 4; nc++) {
        size_t sid = (size_t)bh * S_LEN + i0 + nc * 16 + fr;
        mc[nc] = mbuf[sid]; Dc[nc] = Dv[sid];
      }
      f32x4 stA[4], dptA[4];
      #pragma unroll
      for (int nc = 0; nc < 4; nc++) {
        bf16x8 bq0 = *tile_at(Qs, nc * 16 + fr, q);
        bf16x8 bq1 = *tile_at(Qs, nc * 16 + fr, q + 4);
        bf16x8 bg0 = *tile_at(Gs, nc * 16 + fr, q);
        bf16x8 bg1 = *tile_at(Gs, nc * 16 + fr, q + 4);
        f32x4 z = {};
        z = __builtin_amdgcn_mfma_f32_16x16x32_bf16(ak0, bq0, z, 0, 0, 0);
        stA[nc] = __builtin_amdgcn_mfma_f32_16x16x32_bf16(ak1, bq1, z, 0, 0, 0);
        f32x4 z2 = {};
        z2 = __builtin_amdgcn_mfma_f32_16x16x32_bf16(av0, bg0, z2, 0, 0, 0);
        dptA[nc] = __builtin_amdgcn_mfma_f32_16x16x32_bf16(av1, bg1, z2, 0, 0, 0);
      }
      if (i_t == jt) {   // diagonal tile: causal mask needed
        #pragma unroll
        for (int nc = 0; nc < 4; nc++)
          #pragma unroll
          for (int r = 0; r < 4; r++) {
            int jrow = j0 + band + q * 4 + r;
            int icol = i0 + nc * 16 + fr;
            float P = 0.f, ds = 0.f;
            if (icol >= jrow) {
              P = exp2f(fmaf(stA[nc][r], C2_C, -mc[nc]));
              ds = P * (dptA[nc][r] - Dc[nc]);   // SC lives in Qt
            }
            PT[band + q * 4 + r][nc * 16 + fr] = f2bu(P);   // wave-private
            dST[band + q * 4 + r][nc * 16 + fr] = f2bu(ds);
          }
      } else {           // strictly-upper tile: always unmasked
        #pragma unroll
        for (int nc = 0; nc < 4; nc++)
          #pragma unroll
          for (int r = 0; r < 4; r++) {
            float P = exp2f(fmaf(stA[nc][r], C2_C, -mc[nc]));
            float ds = P * (dptA[nc][r] - Dc[nc]);
            PT[band + q * 4 + r][nc * 16 + fr] = f2bu(P);
            dST[band + q * 4 + r][nc * 16 + fr] = f2bu(ds);
          }
      }
      bf16x8 ap0 = *(const bf16x8*)&PT[band + fr][q * 8];
      bf16x8 ap1 = *(const bf16x8*)&PT[band + fr][32 + q * 8];
      bf16x8 ad0 = *(const bf16x8*)&dST[band + fr][q * 8];
      bf16x8 ad1 = *(const bf16x8*)&dST[band + fr][32 + q * 8];
      #pragma unroll
      for (int nc = 0; nc < 4; nc++) {
        bf16x8 bg0 = *tile_at(Gts, nc * 16 + fr, q);
        bf16x8 bg1 = *tile_at(Gts, nc * 16 + fr, q + 4);
        bf16x8 bq0 = *tile_at(Qts, nc * 16 + fr, q);
        bf16x8 bq1 = *tile_at(Qts, nc * 16 + fr, q + 4);
        dvacc[nc] = __builtin_amdgcn_mfma_f32_16x16x32_bf16(ap0, bg0, dvacc[nc], 0, 0, 0);
        dvacc[nc] = __builtin_amdgcn_mfma_f32_16x16x32_bf16(ap1, bg1, dvacc[nc], 0, 0, 0);
        dkacc[nc] = __builtin_amdgcn_mfma_f32_16x16x32_bf16(ad0, bq0, dkacc[nc], 0, 0, 0);
        dkacc[nc] = __builtin_amdgcn_mfma_f32_16x16x32_bf16(ad1, bq1, dkacc[nc], 0, 0, 0);
      }
    }
    #pragma unroll
    for (int nc = 0; nc < 4; nc++)
      #pragma unroll
      for (int r = 0; r < 4; r++) {
        int jrow = j0 + band + q * 4 + r;
        size_t gi = (size_t)(b * S_LEN + jrow) * E_DIM + h * HD + nc * 16 + fr;
        GK[gi] = f2bu(dkacc[nc][r]);
        GV[gi] = f2bu(dvacc[nc][r]);
      }
  }
}

// ---------------- launch ----------------
extern "C" void kernel_launch(void* const* d_in, const int* in_sizes, int n_in,
                              void* d_out, int out_size, void* d_ws, size_t ws_size,
                              hipStream_t stream) {
  const float* T1 = (const float*)d_in[0];
  const float* Wq = (const float*)d_in[1];
  const float* Wk = (const float*)d_in[2];
  const float* Wv = (const float*)d_in[3];
  const float* Wo = (const float*)d_in[4];

  const size_t M2 = 2097152;   // 2048*1024
  const size_t M1 = 1048576;
  float* w = (float*)d_ws;
  float* Xs = w;                       // 8 MB fp32 target
  float* mS = Xs + M2;                 // 64K f32 (stores m')
  float* DvS = mS + 65536;
  ushort_t* u = (ushort_t*)(DvS + 65536);
  ushort_t* W0 = u;          ushort_t* W1 = W0 + M1;  ushort_t* W2 = W1 + M1;
  ushort_t* W3 = W2 + M1;    ushort_t* W4 = W3 + M1;  ushort_t* W5 = W4 + M1;
  ushort_t* Qb = W5 + M1;    ushort_t* Kb = Qb + M2;  ushort_t* Vb = Kb + M2;
  ushort_t* Qt = Vb + M2;    ushort_t* Kt = Qt + M2;  ushort_t* Vt = Kt + M2;
  ushort_t* Gt = Vt + M2;
  ushort_t* Gb = Gt + M2;
  ushort_t* GQb = Gb + M2;   ushort_t* GKb = GQb + M2; ushort_t* GVb = GKb + M2;
  ushort_t* X2b = GVb + M2;
  float* X2 = (float*)d_out;

  // stage-1 aliases (all consumed before their stage-2 owners write them)
  ushort_t* WoB = Gb;            // bf16 Wo (transient; Gb rewritten by fwd iter 2)
  ushort_t* WoT = Gt;            // bf16 Wo^T (transient; Gt rewritten by fwd iter 2)
  float* Mf  = (float*)Qb;       // 4 MB fp32 M
  ushort_t* Mb  = Vt;            // 2 MB bf16 M (Vt rewritten by qkv iter 2)
  ushort_t* Nb  = Vb;            // 2 MB bf16 N
  ushort_t* AtB = Qt;            // 2 MB
  ushort_t* T1b = Kt;            // 4 MB

  // iter-1 shortcut aliases (dead before their regions' stage-2 consumers)
  float* Sf  = (float*)GQb;      // 8 MB fp32 scan partials (spans GQb+GKb)
  float* tot = mS;               // 128 KB chunk totals (mS rewritten by fwd of iter 2)
  ushort_t* Sb = GVb;            // 4 MB bf16 scan result

  dim3 p4grid(16, 16, 4);
  dim3 sgrid(16, 16);       // 1024x1024 GEMMs
  dim3 ggrid(16, 32);       // 2048x1024 GEMMs
  dim3 agrid(BH_CNT, 16);   // attention

  // ---- stage 1 (algebraic): Xs = T * Wo * (3LR·I - 3LR²·M + LR³·M²),  M = WoᵀWo ----
  prep_w4<<<p4grid, 256, 0, stream>>>(Wo, Wq, Wk, Wv,
                                      WoB, WoT, W0, W3, W1, W4, W2, W5);
  k_cast<<<(M2 / 4 + 255) / 256, 256, 0, stream>>>(T1, T1b, (int)(M2 / 4));
  // M = WoT·WoTᵀ  (fp32 + bf16)
  gemm_mf<4><<<sgrid, 256, 0, stream>>>(WoT, WoT, Mf, Mb, 0.f);
  // fused M2+formN: Nb = bf16(3LR·I - 3LR²·Mf + LR³·(Mb·Mbᵀ))
  gemm_mf<7><<<sgrid, 256, 0, stream>>>(Mb, Mb, Mf, Nb, 0.f);
  // AtB = N·Woᵀ  (symmetric N; this is (Wo·N)ᵀ in [N,K] form)
  gemm_mf<5><<<sgrid, 256, 0, stream>>>(Nb, WoB, nullptr, AtB, 0.f);
  // Xs = T1b·AtBᵀ (fp32)
  gemm_mf<3><<<ggrid, 256, 0, stream>>>(T1b, AtB, Xs, nullptr, 0.f);

  // ---- stage 2, iteration 1 (closed form): x=0 => Q=K=V=0, P exactly causal-uniform,
  //      dQ=dK=0, dV = P0^T(-Xs); x1 = LR * (P0^T Xs) * Wv via fp32 suffix scan + one GEMM ----
  k_scan1<<<dim3(E_DIM / 256, 2, 16), 256, 0, stream>>>(Xs, Sf, tot);
  k_scan2<<<dim3(E_DIM / 256, 2, 16), 256, 0, stream>>>(Sf, tot, Sb);
  gemm_mf<6><<<ggrid, 256, 0, stream>>>(Sb, W5, X2, X2b, LR_C);

  // ---- stage 2, iterations 2..3 (full PC gradient) ----
  for (int t = 1; t < 3; t++) {
    gemm_qkv<<<ggrid, 256, 0, stream>>>(X2b, W0, W1, W2,
                                        Qb, Kb, Vb, Qt, Kt, Vt);
    fwd_fused<<<agrid, 256, 0, stream>>>(Qb, Kb, Vt, Xs, mS, Gb, Gt, DvS);
    bwd_fused<<<agrid, 256, 0, stream>>>(Qb, Kb, Vb, Gb, Qt, Kt, Gt, mS, DvS,
                                         GQb, GKb, GVb);
    gemm_acc<<<ggrid, 256, 0, stream>>>(GQb, GKb, GVb, W3, W4, W5,
                                        X2, X2b, -LR_C);
  }
}